// Round 3
// baseline (3912.992 us; speedup 1.0000x reference)
//
#include <hip/hip_runtime.h>
#include <cstdint>
#include <math.h>

typedef unsigned int u32;
typedef unsigned long long u64;

#define NB    4
#define NPB   512
#define BnN   2048
#define CIN   1024
#define ODEC  256
#define NE    261632      // 512*511 ordered pairs per batch
#define KEDGE 4096
#define CAP   65536
#define TIECAP 2048

// ---------------------------------------------------------------------------
// init: zero/one the accumulators that the harness poisons with 0xAA
// ---------------------------------------------------------------------------
__global__ void init_kernel(float* degw, int* indeg, int* fill, int* ecnt, int* tiecnt) {
    int i = blockIdx.x * 256 + threadIdx.x;
    if (i < 4096) { degw[i] = 1.0f; indeg[i] = 0; fill[i] = 0; }
    if (i < 8)    tiecnt[i] = 0;
    if (i < 2)    ecnt[i]   = 0;
}

// ---------------------------------------------------------------------------
// conv 3x3 SAME, 1024->256, +bias +relu.  Block: 8x8 spatial x 64 och.
// ---------------------------------------------------------------------------
__global__ __launch_bounds__(256) void conv3x3_kernel(
    const float* __restrict__ in, const float* __restrict__ Wd,
    const float* __restrict__ bd, float* __restrict__ out)
{
    __shared__ float inT[8 * 100];   // [ci][10][10]
    __shared__ float wT[64 * 72];    // [o][ci][9]
    const int tile = blockIdx.x;             // 0..35
    const int og   = blockIdx.y;             // 0..3
    const int b    = blockIdx.z;
    const int ty0  = (tile / 6) * 8, tx0 = (tile % 6) * 8;
    const int tid  = threadIdx.x;
    const int to   = tid >> 4;               // 0..15
    const int ts   = tid & 15;
    const int sy   = ts >> 2, sx = ts & 3;

    float acc[4][2][2];
#pragma unroll
    for (int a = 0; a < 4; ++a)
#pragma unroll
        for (int d1 = 0; d1 < 2; ++d1)
#pragma unroll
            for (int d2 = 0; d2 < 2; ++d2) acc[a][d1][d2] = 0.f;

    for (int cc = 0; cc < CIN; cc += 8) {
        for (int idx = tid; idx < 800; idx += 256) {
            int ci = idx / 100; int r = idx - ci * 100;
            int yy = r / 10;    int xx = r - yy * 10;
            int gy = ty0 + yy - 1, gx = tx0 + xx - 1;
            float v = 0.f;
            if ((unsigned)gy < 48u && (unsigned)gx < 48u)
                v = in[((b * CIN + cc + ci) * 48 + gy) * 48 + gx];
            inT[idx] = v;
        }
        for (int idx = tid; idx < 4608; idx += 256) {
            int oi = idx / 72; int r = idx - oi * 72;   // r = ci*9+k
            wT[idx] = Wd[((og * 64 + oi) * CIN + cc) * 9 + r];
        }
        __syncthreads();
#pragma unroll
        for (int ci = 0; ci < 8; ++ci) {
            float iv[4][4];
#pragma unroll
            for (int r = 0; r < 4; ++r)
#pragma unroll
                for (int c2 = 0; c2 < 4; ++c2)
                    iv[r][c2] = inT[ci * 100 + (sy * 2 + r) * 10 + (sx * 2 + c2)];
#pragma unroll
            for (int oi = 0; oi < 4; ++oi) {
                const float* wp = &wT[(to * 4 + oi) * 72 + ci * 9];
                float w0 = wp[0], w1 = wp[1], w2 = wp[2], w3 = wp[3], w4 = wp[4];
                float w5 = wp[5], w6 = wp[6], w7 = wp[7], w8 = wp[8];
#pragma unroll
                for (int dy = 0; dy < 2; ++dy)
#pragma unroll
                    for (int dx = 0; dx < 2; ++dx) {
                        float s = acc[oi][dy][dx];
                        s += iv[dy + 0][dx + 0] * w0 + iv[dy + 0][dx + 1] * w1 + iv[dy + 0][dx + 2] * w2;
                        s += iv[dy + 1][dx + 0] * w3 + iv[dy + 1][dx + 1] * w4 + iv[dy + 1][dx + 2] * w5;
                        s += iv[dy + 2][dx + 0] * w6 + iv[dy + 2][dx + 1] * w7 + iv[dy + 2][dx + 2] * w8;
                        acc[oi][dy][dx] = s;
                    }
            }
        }
        __syncthreads();
    }
#pragma unroll
    for (int oi = 0; oi < 4; ++oi) {
        int o = og * 64 + to * 4 + oi;
        float bias = bd[o];
#pragma unroll
        for (int dy = 0; dy < 2; ++dy)
#pragma unroll
            for (int dx = 0; dx < 2; ++dx) {
                int y = ty0 + sy * 2 + dy, x = tx0 + sx * 2 + dx;
                float v = acc[oi][dy][dx] + bias;
                out[((b * ODEC + o) * 48 + y) * 48 + x] = v > 0.f ? v : 0.f;
            }
    }
}

// ---------------------------------------------------------------------------
// ROI align 2x2: one block per box, one thread per channel. cnn[n][c*4+p]
// ---------------------------------------------------------------------------
__global__ __launch_bounds__(256) void roi_kernel(
    const float* __restrict__ dec, const float* __restrict__ boxes,
    float* __restrict__ cnn)
{
    int n = blockIdx.x; int c = threadIdx.x;
    int b = n >> 9;
    float x1 = boxes[n * 4 + 0], y1 = boxes[n * 4 + 1];
    float x2 = boxes[n * 4 + 2], y2 = boxes[n * 4 + 3];
    float bw = (x2 - x1) * 0.5f, bh = (y2 - y1) * 0.5f;
    float sxv[2] = { x1 + 0.5f * bw, x1 + 1.5f * bw };
    float syv[2] = { y1 + 0.5f * bh, y1 + 1.5f * bh };
    float px[4] = { sxv[0], sxv[1], sxv[0], sxv[1] };
    float py[4] = { syv[0], syv[0], syv[1], syv[1] };
    const float* f = dec + (b * ODEC + c) * 2304;
    float res[4];
#pragma unroll
    for (int p = 0; p < 4; ++p) {
        float yy = fminf(fmaxf(py[p], 0.f), 47.f);
        float xx = fminf(fmaxf(px[p], 0.f), 47.f);
        int y0 = (int)floorf(yy), x0 = (int)floorf(xx);
        int y1i = min(y0 + 1, 47), x1i = min(x0 + 1, 47);
        float wy = yy - (float)y0, wx = xx - (float)x0;
        float f00 = f[y0 * 48 + x0],  f01 = f[y0 * 48 + x1i];
        float f10 = f[y1i * 48 + x0], f11 = f[y1i * 48 + x1i];
        res[p] = f00 * (1.f - wy) * (1.f - wx) + f01 * (1.f - wy) * wx
               + f10 * wy * (1.f - wx) + f11 * wy * wx;
    }
    float4 o4 = make_float4(res[0], res[1], res[2], res[3]);
    *(float4*)&cnn[n * 1024 + c * 4] = o4;
}

// ---------------------------------------------------------------------------
// box geometric features bf[n][4]
// ---------------------------------------------------------------------------
__global__ void mkbf_kernel(const float* __restrict__ boxes, float* __restrict__ bf) {
    int n = blockIdx.x * 256 + threadIdx.x;
    if (n >= BnN) return;
    float x1 = boxes[n * 4 + 0], y1 = boxes[n * 4 + 1];
    float x2 = boxes[n * 4 + 2], y2 = boxes[n * 4 + 3];
    bf[n * 4 + 0] = ((x1 + x2) * 0.5f) / 48.f;
    bf[n * 4 + 1] = ((y1 + y2) * 0.5f) / 48.f;
    bf[n * 4 + 2] = (x2 - x1) / 48.f;
    bf[n * 4 + 3] = (y2 - y1) / 48.f;
}

// ---------------------------------------------------------------------------
// generic tiled fp32 GEMM: C = act(A@B + bias). 64x64 tile, 4x4 per thread.
// ACT: 0 none, 1 relu, 2 leaky(0.01)
// ---------------------------------------------------------------------------
template <int ACT>
__global__ __launch_bounds__(256) void gemm_kernel(
    const float* __restrict__ A, const float* __restrict__ B,
    const float* __restrict__ bias, float* __restrict__ C,
    int M, int N, int K, int ldA, int ldB, int ldC)
{
    __shared__ float As[16][64];
    __shared__ float Bs[16][64];
    const int m0 = blockIdx.y * 64, n0 = blockIdx.x * 64;
    const int tid = threadIdx.x;
    const int ma = tid >> 2, ka = (tid & 3) * 4;
    const int kb = tid >> 4, nb = (tid & 15) * 4;
    const int ty = tid >> 4, tx = tid & 15;
    float acc[4][4] = {};
    for (int kk = 0; kk < K; kk += 16) {
        float a0 = 0.f, a1 = 0.f, a2 = 0.f, a3 = 0.f;
        if (m0 + ma < M) {
            const float* ap = A + (size_t)(m0 + ma) * ldA + kk + ka;
            if (kk + ka + 0 < K) a0 = ap[0];
            if (kk + ka + 1 < K) a1 = ap[1];
            if (kk + ka + 2 < K) a2 = ap[2];
            if (kk + ka + 3 < K) a3 = ap[3];
        }
        As[ka + 0][ma] = a0; As[ka + 1][ma] = a1; As[ka + 2][ma] = a2; As[ka + 3][ma] = a3;
        float4 bv = make_float4(0.f, 0.f, 0.f, 0.f);
        if (kk + kb < K) {
            const float* bp = B + (size_t)(kk + kb) * ldB + n0 + nb;
            if (n0 + nb + 0 < N) bv.x = bp[0];
            if (n0 + nb + 1 < N) bv.y = bp[1];
            if (n0 + nb + 2 < N) bv.z = bp[2];
            if (n0 + nb + 3 < N) bv.w = bp[3];
        }
        *(float4*)&Bs[kb][nb] = bv;
        __syncthreads();
#pragma unroll
        for (int k = 0; k < 16; ++k) {
            float4 av4 = *(const float4*)&As[k][ty * 4];
            float4 bv4 = *(const float4*)&Bs[k][tx * 4];
            float aarr[4] = { av4.x, av4.y, av4.z, av4.w };
            float barr[4] = { bv4.x, bv4.y, bv4.z, bv4.w };
#pragma unroll
            for (int i = 0; i < 4; ++i)
#pragma unroll
                for (int j = 0; j < 4; ++j) acc[i][j] += aarr[i] * barr[j];
        }
        __syncthreads();
    }
#pragma unroll
    for (int i = 0; i < 4; ++i) {
        int m = m0 + ty * 4 + i;
        if (m >= M) continue;
#pragma unroll
        for (int j = 0; j < 4; ++j) {
            int n = n0 + tx * 4 + j;
            if (n >= N) continue;
            float v = acc[i][j] + (bias ? bias[n] : 0.f);
            if (ACT == 1) v = fmaxf(v, 0.f);
            if (ACT == 2) v = (v >= 0.f) ? v : 0.01f * v;
            C[(size_t)m * ldC + n] = v;
        }
    }
}

// ---------------------------------------------------------------------------
// E0: per-batch centers (fp32, exact replica of reference op order)
//     + table extents (fp32 max-reduce)
// ---------------------------------------------------------------------------
__global__ __launch_bounds__(512) void e0_kernel(
    const float* __restrict__ boxes, const float* __restrict__ scales,
    const float* __restrict__ pdls, const float* __restrict__ pdts,
    float* __restrict__ cxA, float* __restrict__ cyA, float* __restrict__ tb)
{
    __shared__ float sw[512], sh[512];
    int b = blockIdx.x, n = threadIdx.x;
    float pdl = pdls[b], pdt = pdts[b], sc = scales[b];
    const float* bx = boxes + (size_t)(b * 512 + n) * 4;
    float o0 = (bx[0] - pdl) / sc;
    float o1 = (bx[1] - pdt) / sc;
    float o2 = (bx[2] - pdl) / sc;
    float o3 = (bx[3] - pdt) / sc;
    cxA[b * 512 + n] = (o0 + o2) * 0.5f;
    cyA[b * 512 + n] = (o1 + o3) * 0.5f;
    sw[n] = fmaxf(o0, o2); sh[n] = fmaxf(o1, o3);
    __syncthreads();
    for (int s = 256; s > 0; s >>= 1) {
        if (n < s) { sw[n] = fmaxf(sw[n], sw[n + s]); sh[n] = fmaxf(sh[n], sh[n + s]); }
        __syncthreads();
    }
    if (n == 0) { tb[b * 2 + 0] = sw[0]; tb[b * 2 + 1] = sh[0]; }
}

// ---------------------------------------------------------------------------
// Ranking key: the reference top_k's key is attr = exp(-q) (fp32), DESCENDING,
// ties broken by pair index. exp collapses adjacent q near the boundary
// (dw_ulps ~ dq_ulps * q, q* < 1), so ranking by q is WRONG within collapsed
// groups. Key = ~bits(w) ascending == w descending (positive floats are
// bit-monotone). w computed correctly-rounded: f32(exp64(-q32)).
// ---------------------------------------------------------------------------
__device__ __forceinline__ float q_val(const float* sv, float tbv, int e) {
    int i = e / 511; int jj = e - i * 511; int j = jj + (jj >= i ? 1 : 0);
    float diff = sv[i] - sv[j];
    float u = (diff * 5.0f) / tbv;
    return u * u;
}
__device__ __forceinline__ u32 key_bits(const float* sv, float tbv, int e) {
    float q = q_val(sv, tbv, e);
    float w = (float)exp(-(double)q);
    return ~__float_as_uint(w);
}

// ---------------------------------------------------------------------------
// E2: 32-bit radix select of K-th smallest key (== K-th largest w).
// one block per selection (sel = b*2 + type). Ties resolved later by index.
// ---------------------------------------------------------------------------
__global__ __launch_bounds__(1024) void select_kernel(
    const float* __restrict__ cxA, const float* __restrict__ cyA,
    const float* __restrict__ tb,
    u32* __restrict__ candA, u32* __restrict__ candB,
    u32* __restrict__ kstar, int* __restrict__ rstar)
{
    const int sel = blockIdx.x;
    const int b = sel >> 1, t = sel & 1;
    const int tid = threadIdx.x;
    const int wv = tid >> 6;
    __shared__ float sv[512];
    __shared__ u32 h[16][256];
    __shared__ u32 tot[256];
    __shared__ int s_digit, s_need, s_cnt;
    __shared__ float s_tb;
    if (tid < 512) sv[tid] = (t == 0) ? cyA[b * 512 + tid] : cxA[b * 512 + tid];
    if (tid == 0) s_tb = tb[b * 2 + (t == 0 ? 1 : 0)];
    __syncthreads();
    const float tbv = s_tb;
    int need = KEDGE;
    u32 prefix = 0;

    // ---- byte 3 (full array) ----
    for (int x = tid; x < 16 * 256; x += 1024) ((u32*)h)[x] = 0;
    __syncthreads();
    for (int e = tid; e < NE; e += 1024) {
        u32 kb2 = key_bits(sv, tbv, e);
        atomicAdd(&h[wv][(int)(kb2 >> 24)], 1u);
    }
    __syncthreads();
    if (tid < 256) { u32 s = 0; for (int w = 0; w < 16; ++w) s += h[w][tid]; tot[tid] = s; }
    __syncthreads();
    if (tid == 0) {
        u32 cum = 0; int d = 255;
        for (int bb = 0; bb < 256; ++bb) { if (cum + tot[bb] >= (u32)need) { d = bb; break; } cum += tot[bb]; }
        s_digit = d; s_need = need - (int)cum;
    }
    __syncthreads();
    prefix |= ((u32)s_digit) << 24; need = s_need;
    __syncthreads();

    // ---- byte 2 (full array, filtered) ----
    for (int x = tid; x < 16 * 256; x += 1024) ((u32*)h)[x] = 0;
    __syncthreads();
    for (int e = tid; e < NE; e += 1024) {
        u32 kb2 = key_bits(sv, tbv, e);
        if ((kb2 >> 24) == (prefix >> 24)) atomicAdd(&h[wv][(int)((kb2 >> 16) & 0xFF)], 1u);
    }
    __syncthreads();
    if (tid < 256) { u32 s = 0; for (int w = 0; w < 16; ++w) s += h[w][tid]; tot[tid] = s; }
    __syncthreads();
    if (tid == 0) {
        u32 cum = 0; int d = 255;
        for (int bb = 0; bb < 256; ++bb) { if (cum + tot[bb] >= (u32)need) { d = bb; break; } cum += tot[bb]; }
        s_digit = d; s_need = need - (int)cum;
    }
    __syncthreads();
    prefix |= ((u32)s_digit) << 16; need = s_need;
    if (tid == 0) s_cnt = 0;
    __syncthreads();

    // ---- compact top-16-bit matches ----
    u32* cA = candA + (size_t)sel * CAP;
    u32* cB = candB + (size_t)sel * CAP;
    for (int e = tid; e < NE; e += 1024) {
        u32 kb2 = key_bits(sv, tbv, e);
        if ((kb2 >> 16) == (prefix >> 16)) {
            int pos = atomicAdd(&s_cnt, 1);
            if (pos < CAP) cA[pos] = kb2;
        }
    }
    __syncthreads();
    int C = min(s_cnt, CAP);
    u32* cur = cA; u32* nxt = cB;

    // ---- bytes 1..0 over candidates ----
    for (int shift = 8; shift >= 0; shift -= 8) {
        __syncthreads();
        for (int x = tid; x < 16 * 256; x += 1024) ((u32*)h)[x] = 0;
        __syncthreads();
        for (int k = tid; k < C; k += 1024)
            atomicAdd(&h[wv][(int)((cur[k] >> shift) & 0xFF)], 1u);
        __syncthreads();
        if (tid < 256) { u32 s = 0; for (int w = 0; w < 16; ++w) s += h[w][tid]; tot[tid] = s; }
        __syncthreads();
        if (tid == 0) {
            u32 cum = 0; int d = 255;
            for (int bb = 0; bb < 256; ++bb) { if (cum + tot[bb] >= (u32)need) { d = bb; break; } cum += tot[bb]; }
            s_digit = d; s_need = need - (int)cum;
            s_cnt = 0;
        }
        __syncthreads();
        int dig = s_digit;
        prefix |= ((u32)dig) << shift; need = s_need;
        for (int k = tid; k < C; k += 1024) {
            u32 kb2 = cur[k];
            if ((int)((kb2 >> shift) & 0xFF) == dig) {
                int pos = atomicAdd(&s_cnt, 1);
                if (pos < CAP) nxt[pos] = kb2;
            }
        }
        __syncthreads();
        C = min(s_cnt, CAP);
        u32* tmp = cur; cur = nxt; nxt = tmp;
    }
    if (tid == 0) { kstar[sel] = prefix; rstar[sel] = need; }
}

// ---------------------------------------------------------------------------
// E3: emit edges with key < k*; queue ties (key == k*)
// ---------------------------------------------------------------------------
__device__ __forceinline__ void emit_edge(int t, int src, int dst, float w,
    int* es, int* ed, float* ew, int* ecnt, int* indeg, float* degw)
{
    int slot = atomicAdd(&ecnt[t], 1);
    es[t * 16384 + slot] = src;
    ed[t * 16384 + slot] = dst;
    ew[t * 16384 + slot] = w;
    atomicAdd(&indeg[t * 2048 + dst], 1);
    atomicAdd(&degw[t * 2048 + dst], w);
}

__global__ void e3_kernel(
    const float* __restrict__ cxA, const float* __restrict__ cyA,
    const float* __restrict__ tb, const u32* __restrict__ kstar,
    int* __restrict__ tiebuf, int* __restrict__ tiecnt,
    int* __restrict__ es, int* __restrict__ ed, float* __restrict__ ew,
    int* __restrict__ ecnt, int* __restrict__ indeg, float* __restrict__ degw)
{
    int idx = blockIdx.x * 256 + threadIdx.x;
    if (idx >= 8 * NE) return;
    int sel = idx / NE; int e = idx - sel * NE;
    int b = sel >> 1, t = sel & 1;
    const float* v = (t == 0) ? cyA : cxA;
    float tbv = tb[b * 2 + (t == 0 ? 1 : 0)];
    int i = e / 511; int jj = e - i * 511; int j = jj + (jj >= i ? 1 : 0);
    float diff = v[b * 512 + i] - v[b * 512 + j];
    float u = (diff * 5.0f) / tbv;
    float q = u * u;
    float w = (float)exp(-(double)q);
    u32 kb2 = ~__float_as_uint(w);
    u32 ks = kstar[sel];
    if (kb2 < ks) {
        emit_edge(t, b * 512 + i, b * 512 + j, w, es, ed, ew, ecnt, indeg, degw);
    } else if (kb2 == ks) {
        int p = atomicAdd(&tiecnt[sel], 1);
        if (p < TIECAP) tiebuf[sel * TIECAP + p] = e;
    }
}

// E3b: resolve ties by smallest pair-index (lax.top_k semantics)
__global__ void e3b_kernel(
    const u32* __restrict__ kstar, const int* __restrict__ rstar,
    const int* __restrict__ tiebuf, const int* __restrict__ tiecnt,
    int* __restrict__ es, int* __restrict__ ed, float* __restrict__ ew,
    int* __restrict__ ecnt, int* __restrict__ indeg, float* __restrict__ degw)
{
    int sel = blockIdx.x;
    int b = sel >> 1, t = sel & 1;
    int m = min(tiecnt[sel], TIECAP);
    int r = rstar[sel];
    float w = __uint_as_float(~kstar[sel]);
    for (int k = threadIdx.x; k < m; k += blockDim.x) {
        int e = tiebuf[sel * TIECAP + k];
        int rank = 0;
        for (int l = 0; l < m; ++l) rank += (tiebuf[sel * TIECAP + l] < e) ? 1 : 0;
        if (rank < r) {
            int i = e / 511; int jj = e - i * 511; int j = jj + (jj >= i ? 1 : 0);
            emit_edge(t, b * 512 + i, b * 512 + j, w, es, ed, ew, ecnt, indeg, degw);
        }
    }
}

__global__ void e4_kernel(const float* __restrict__ degw, float* __restrict__ dis) {
    int i = blockIdx.x * 256 + threadIdx.x;
    if (i < 4096) dis[i] = 1.0f / sqrtf(degw[i]);
}

// E5: exclusive scan of indeg (2048 per type), one block per type
__global__ __launch_bounds__(1024) void scan_kernel(const int* __restrict__ indeg, int* __restrict__ offs) {
    __shared__ int bufA[2048], bufB[2048];
    int t = blockIdx.x, tid = threadIdx.x;
    bufA[tid] = indeg[t * 2048 + tid];
    bufA[tid + 1024] = indeg[t * 2048 + tid + 1024];
    __syncthreads();
    int* src = bufA; int* dst = bufB;
    for (int st = 1; st < 2048; st <<= 1) {
        dst[tid] = src[tid] + (tid >= st ? src[tid - st] : 0);
        int k1 = tid + 1024;
        dst[k1] = src[k1] + (k1 >= st ? src[k1 - st] : 0);
        __syncthreads();
        int* tmp = src; src = dst; dst = tmp;
    }
    offs[t * 2048 + tid] = (tid == 0) ? 0 : src[tid - 1];
    offs[t * 2048 + tid + 1024] = src[tid + 1023];
}

__global__ void fill_kernel(const int* __restrict__ ed, const int* __restrict__ offs,
                            int* __restrict__ fill, int* __restrict__ csr) {
    int idx = blockIdx.x * 256 + threadIdx.x;
    if (idx >= 32768) return;
    int t = idx >> 14, e = idx & 16383;
    int d = ed[t * 16384 + e];
    int pos = offs[t * 2048 + d] + atomicAdd(&fill[t * 2048 + d], 1);
    csr[t * 16384 + pos] = e;
}

// E7: GCN aggregate per (type, dst-node): relu(sum norm*xw[src] + self + bias)
__global__ __launch_bounds__(256) void gcn_agg_kernel(
    const float* __restrict__ xw_row, const float* __restrict__ xw_col,
    const float* __restrict__ b_row, const float* __restrict__ b_col,
    const int* __restrict__ es, const float* __restrict__ ew,
    const int* __restrict__ csr, const int* __restrict__ offs,
    const int* __restrict__ indeg, const float* __restrict__ dis,
    float* __restrict__ feat_row, float* __restrict__ feat_col)
{
    int d = blockIdx.x; int t = blockIdx.y;
    const float* xw = t ? xw_col : xw_row;
    const float* bg = t ? b_col : b_row;
    float* out = t ? feat_col : feat_row;
    int f0 = threadIdx.x, f1 = threadIdx.x + 256;
    float dd = dis[t * 2048 + d];
    float a0 = dd * dd * xw[(size_t)d * 512 + f0];
    float a1 = dd * dd * xw[(size_t)d * 512 + f1];
    int st = offs[t * 2048 + d], cnt = indeg[t * 2048 + d];
    for (int k = 0; k < cnt; ++k) {
        int e = csr[t * 16384 + st + k];
        int s = es[t * 16384 + e];
        float w = ew[t * 16384 + e];
        float coef = dis[t * 2048 + s] * w * dd;
        a0 += coef * xw[(size_t)s * 512 + f0];
        a1 += coef * xw[(size_t)s * 512 + f1];
    }
    a0 += bg[f0]; a1 += bg[f1];
    out[(size_t)d * 512 + f0] = fmaxf(a0, 0.f);
    out[(size_t)d * 512 + f1] = fmaxf(a1, 0.f);
}

// ---------------------------------------------------------------------------
extern "C" void kernel_launch(void* const* d_in, const int* in_sizes, int n_in,
                              void* d_out, int out_size, void* d_ws, size_t ws_size,
                              hipStream_t stream)
{
    const float* x      = (const float*)d_in[0];
    const float* boxes  = (const float*)d_in[1];
    const float* scales = (const float*)d_in[2];
    const float* pdls   = (const float*)d_in[3];
    const float* pdts   = (const float*)d_in[4];
    const float* W_dec  = (const float*)d_in[5];
    const float* b_dec  = (const float*)d_in[6];
    const float* W_box  = (const float*)d_in[7];
    const float* b_box  = (const float*)d_in[8];
    const float* W_cnn  = (const float*)d_in[9];
    const float* b_cnn  = (const float*)d_in[10];
    const float* W_grow = (const float*)d_in[11];
    const float* b_grow = (const float*)d_in[12];
    const float* W_gcol = (const float*)d_in[13];
    const float* b_gcol = (const float*)d_in[14];
    const float* W_rcls = (const float*)d_in[15];
    const float* b_rcls = (const float*)d_in[16];
    const float* W_ccls = (const float*)d_in[17];
    const float* b_ccls = (const float*)d_in[18];

    char* ws = (char*)d_ws;
    size_t off = 0;
    auto alloc = [&](size_t bytes) -> void* {
        void* p = ws + off;
        off = (off + bytes + 255) & ~(size_t)255;
        return p;
    };
    float* dec    = (float*)alloc((size_t)2359296 * 4);   // (4,256,48,48)
    float* fusion = (float*)alloc((size_t)1572864 * 4);   // (2048,768)
    float* cnn    = (float*)alloc((size_t)2097152 * 4);   // (2048,1024)
    float* xw     = (float*)alloc((size_t)2097152 * 4);   // xw_row|xw_col (2048,512)x2
    u32*   cand   = (u32*)  alloc((size_t)16 * CAP * 4);  // radix candidates A|B
    float* feats  = (float*)alloc((size_t)2097152 * 4);   // feat_row|feat_col
    float* bf     = (float*)alloc((size_t)8192 * 4);
    float* cxA    = (float*)alloc((size_t)2048 * 4);
    float* cyA    = (float*)alloc((size_t)2048 * 4);
    float* tbA    = (float*)alloc((size_t)8 * 4);
    u32*  kstar   = (u32*)  alloc((size_t)8 * 4);
    int*  rstar   = (int*)  alloc((size_t)8 * 4);
    int*  tiebuf  = (int*)  alloc((size_t)8 * TIECAP * 4);
    int*  tiecnt  = (int*)  alloc((size_t)8 * 4);
    int*  es      = (int*)  alloc((size_t)2 * 16384 * 4);
    int*  ed      = (int*)  alloc((size_t)2 * 16384 * 4);
    float* ewt    = (float*)alloc((size_t)2 * 16384 * 4);
    int*  ecnt    = (int*)  alloc((size_t)64);
    int*  indeg   = (int*)  alloc((size_t)4096 * 4);
    float* degw   = (float*)alloc((size_t)4096 * 4);
    float* dis    = (float*)alloc((size_t)4096 * 4);
    int*  offsA   = (int*)  alloc((size_t)4096 * 4);
    int*  fillA   = (int*)  alloc((size_t)4096 * 4);
    int*  csr     = (int*)  alloc((size_t)2 * 16384 * 4);

    float* out = (float*)d_out;

    init_kernel<<<16, 256, 0, stream>>>(degw, indeg, fillA, ecnt, tiecnt);
    conv3x3_kernel<<<dim3(36, 4, 4), 256, 0, stream>>>(x, W_dec, b_dec, dec);
    roi_kernel<<<2048, 256, 0, stream>>>(dec, boxes, cnn);
    mkbf_kernel<<<8, 256, 0, stream>>>(boxes, bf);
    // fusion = [relu(bf@W_box+b) | relu(cnn@W_cnn+b)]
    gemm_kernel<1><<<dim3(4, 32), 256, 0, stream>>>(bf, W_box, b_box, fusion, 2048, 256, 4, 4, 256, 768);
    gemm_kernel<1><<<dim3(8, 32), 256, 0, stream>>>(cnn, W_cnn, b_cnn, fusion + 256, 2048, 512, 1024, 1024, 512, 768);
    // edge selection
    e0_kernel<<<4, 512, 0, stream>>>(boxes, scales, pdls, pdts, cxA, cyA, tbA);
    select_kernel<<<8, 1024, 0, stream>>>(cxA, cyA, tbA, cand, cand + (size_t)8 * CAP, kstar, rstar);
    e3_kernel<<<8176, 256, 0, stream>>>(cxA, cyA, tbA, kstar, tiebuf, tiecnt, es, ed, ewt, ecnt, indeg, degw);
    e3b_kernel<<<8, 256, 0, stream>>>(kstar, rstar, tiebuf, tiecnt, es, ed, ewt, ecnt, indeg, degw);
    e4_kernel<<<16, 256, 0, stream>>>(degw, dis);
    scan_kernel<<<2, 1024, 0, stream>>>(indeg, offsA);
    fill_kernel<<<128, 256, 0, stream>>>(ed, offsA, fillA, csr);
    // xw = fusion @ W_g{row,col}  (no bias/act; bias applied after aggregation)
    gemm_kernel<0><<<dim3(8, 32), 256, 0, stream>>>(fusion, W_grow, nullptr, xw, 2048, 512, 768, 768, 512, 512);
    gemm_kernel<0><<<dim3(8, 32), 256, 0, stream>>>(fusion, W_gcol, nullptr, xw + 1048576, 2048, 512, 768, 768, 512, 512);
    gcn_agg_kernel<<<dim3(2048, 2), 256, 0, stream>>>(xw, xw + 1048576, b_grow, b_gcol,
                                                      es, ewt, csr, offsA, indeg, dis,
                                                      feats, feats + 1048576);
    // classifier heads (leaky relu 0.01)
    gemm_kernel<2><<<dim3(4, 32), 256, 0, stream>>>(feats, W_rcls, b_rcls, out, 2048, 228, 512, 512, 228, 228);
    gemm_kernel<2><<<dim3(2, 32), 256, 0, stream>>>(feats + 1048576, W_ccls, b_ccls, out + (size_t)2048 * 228,
                                                    2048, 116, 512, 512, 116, 116);
}

// Round 4
// 2171.839 us; speedup vs baseline: 1.8017x; 1.8017x over previous
//
#include <hip/hip_runtime.h>
#include <cstdint>
#include <math.h>

typedef unsigned int u32;
typedef unsigned long long u64;
typedef unsigned short ushort;

typedef __attribute__((ext_vector_type(8))) short bf16x8;
typedef __attribute__((ext_vector_type(4))) float f32x4;

#define NB    4
#define NPB   512
#define BnN   2048
#define CIN   1024
#define ODEC  256
#define NE    261632      // 512*511 ordered pairs per batch
#define KEDGE 4096
#define CAP   65536
#define TIECAP 2048

// ---------------------------------------------------------------------------
// init: zero/one the accumulators that the harness poisons with 0xAA
// ---------------------------------------------------------------------------
__global__ void init_kernel(float* degw, int* indeg, int* fill, int* ecnt, int* tiecnt) {
    int i = blockIdx.x * 256 + threadIdx.x;
    if (i < 4096) { degw[i] = 1.0f; indeg[i] = 0; fill[i] = 0; }
    if (i < 8)    tiecnt[i] = 0;
    if (i < 2)    ecnt[i]   = 0;
}

// ---------------------------------------------------------------------------
// bf16 split helpers (RNE)
// ---------------------------------------------------------------------------
__device__ __forceinline__ ushort bf16_rne(float v) {
    u32 b = __float_as_uint(v);
    return (ushort)((b + 0x7FFFu + ((b >> 16) & 1u)) >> 16);
}
__device__ __forceinline__ float bf16_to_f(ushort h) {
    return __uint_as_float(((u32)h) << 16);
}

// split+transpose input: NCHW fp32 -> NHWC bf16 hi/lo
// grid (16 chgrp, 48 y, 4 b), block 256
__global__ __launch_bounds__(256) void split_x_kernel(
    const float* __restrict__ in, ushort* __restrict__ xh, ushort* __restrict__ xl)
{
    __shared__ ushort shh[64][49];
    __shared__ ushort shl[64][49];
    int cg = blockIdx.x, y = blockIdx.y, b = blockIdx.z;
    int tid = threadIdx.x;
    for (int i = tid; i < 64 * 48; i += 256) {
        int cl = i / 48, x = i - cl * 48;
        float v = in[(((size_t)b * 1024 + cg * 64 + cl) * 48 + y) * 48 + x];
        ushort hb = bf16_rne(v);
        float lo = v - bf16_to_f(hb);
        shh[cl][x] = hb; shl[cl][x] = bf16_rne(lo);
    }
    __syncthreads();
    for (int i = tid; i < 64 * 48; i += 256) {
        int x = i / 64, cl = i - x * 64;
        size_t o = ((size_t)(b * 48 + y) * 48 + x) * 1024 + cg * 64 + cl;
        xh[o] = shh[cl][x]; xl[o] = shl[cl][x];
    }
}

// split weights: [o][ch][3][3] fp32 -> [o][tap][ch] bf16 hi/lo
// grid (9 tap, 256 o), block 256
__global__ __launch_bounds__(256) void split_w_kernel(
    const float* __restrict__ W, ushort* __restrict__ wh, ushort* __restrict__ wl)
{
    int tap = blockIdx.x, o = blockIdx.y;
    for (int ch = threadIdx.x; ch < 1024; ch += 256) {
        float v = W[((size_t)o * 1024 + ch) * 9 + tap];
        ushort hb = bf16_rne(v);
        float lo = v - bf16_to_f(hb);
        size_t idx = ((size_t)o * 9 + tap) * 1024 + ch;
        wh[idx] = hb; wl[idx] = bf16_rne(lo);
    }
}

// ---------------------------------------------------------------------------
// conv 3x3 SAME, 1024->256, +bias +relu, via implicit-GEMM MFMA bf16x3.
// Block: 128 thr (2 waves). Wave computes 16 och x 48 px (one output row).
// grid (48 y, 8 og[32 och], 4 b). K-chunks of 32 ch; 9 taps; 3 n-tiles.
// LDS blocked [tap/row][quad][och/col][8ch] so every ds_read_b128 is
// 16B-aligned and bank-uniform (8 dwords/bank = the b128 floor).
// ---------------------------------------------------------------------------
__global__ __launch_bounds__(128) void conv_mfma_kernel(
    const ushort* __restrict__ xh, const ushort* __restrict__ xl,
    const ushort* __restrict__ wh, const ushort* __restrict__ wl,
    const float* __restrict__ bd, float* __restrict__ dec)
{
    __shared__ ushort wS[2][9][4][32][8];   // 36.9 KB
    __shared__ ushort xS[2][3][4][50][8];   // 19.2 KB
    const int y  = blockIdx.x;
    const int og = blockIdx.y;
    const int b  = blockIdx.z;
    const int tid = threadIdx.x;
    const int wv = tid >> 6;
    const int ln = tid & 63;
    const int n  = ln & 15;        // A: och-in-tile ; B: pixel-in-tile ; D: col
    const int q  = ln >> 4;        // k-quad

    f32x4 acc[3];
#pragma unroll
    for (int t = 0; t < 3; ++t) acc[t] = (f32x4){0.f, 0.f, 0.f, 0.f};

    for (int cc = 0; cc < 1024; cc += 32) {
        // ---- stage weights: 2304 x 16B groups ----
        for (int g = tid; g < 2304; g += 128) {
            int hl = g / 1152; int r = g - hl * 1152;
            int tap = r >> 7; int r2 = r & 127;
            int qq = r2 >> 5; int oc = r2 & 31;
            const ushort* src = (hl ? wl : wh) +
                (((size_t)(og * 32 + oc) * 9 + tap) * 1024 + cc + qq * 8);
            uint4 v = *(const uint4*)src;
            *(uint4*)&wS[hl][tap][qq][oc][0] = v;
        }
        // ---- stage input: 1200 x 16B groups (rows y-1..y+1, cols -1..48) ----
        for (int g = tid; g < 1200; g += 128) {
            int hl = g / 600; int r = g - hl * 600;
            int row = r / 200; int r2 = r - row * 200;
            int qq = r2 / 50; int c = r2 - qq * 50;
            int gy = y + row - 1, gx = c - 1;
            uint4 v = make_uint4(0u, 0u, 0u, 0u);
            if ((unsigned)gy < 48u && (unsigned)gx < 48u)
                v = *(const uint4*)((hl ? xl : xh) +
                    (((size_t)(b * 48 + gy) * 48 + gx) * 1024 + cc + qq * 8));
            *(uint4*)&xS[hl][row][qq][c][0] = v;
        }
        __syncthreads();

#pragma unroll
        for (int tap = 0; tap < 9; ++tap) {
            const int dy = tap / 3, dx = tap % 3;
            bf16x8 ah = *(const bf16x8*)&wS[0][tap][q][wv * 16 + n][0];
            bf16x8 al = *(const bf16x8*)&wS[1][tap][q][wv * 16 + n][0];
#pragma unroll
            for (int nt = 0; nt < 3; ++nt) {
                int col = nt * 16 + n + dx;
                bf16x8 bh = *(const bf16x8*)&xS[0][dy][q][col][0];
                bf16x8 bl = *(const bf16x8*)&xS[1][dy][q][col][0];
                acc[nt] = __builtin_amdgcn_mfma_f32_16x16x32_bf16(ah, bh, acc[nt], 0, 0, 0);
                acc[nt] = __builtin_amdgcn_mfma_f32_16x16x32_bf16(ah, bl, acc[nt], 0, 0, 0);
                acc[nt] = __builtin_amdgcn_mfma_f32_16x16x32_bf16(al, bh, acc[nt], 0, 0, 0);
            }
        }
        __syncthreads();
    }

    // ---- epilogue: D col = ln&15 (pixel), row = q*4+r (och) ----
#pragma unroll
    for (int nt = 0; nt < 3; ++nt) {
        int xcol = nt * 16 + n;
#pragma unroll
        for (int r = 0; r < 4; ++r) {
            int och = og * 32 + wv * 16 + q * 4 + r;
            float v = acc[nt][r] + bd[och];
            dec[(((size_t)b * 256 + och) * 48 + y) * 48 + xcol] = v > 0.f ? v : 0.f;
        }
    }
}

// ---------------------------------------------------------------------------
// ROI align 2x2: one block per box, one thread per channel. cnn[n][c*4+p]
// ---------------------------------------------------------------------------
__global__ __launch_bounds__(256) void roi_kernel(
    const float* __restrict__ dec, const float* __restrict__ boxes,
    float* __restrict__ cnn)
{
    int n = blockIdx.x; int c = threadIdx.x;
    int b = n >> 9;
    float x1 = boxes[n * 4 + 0], y1 = boxes[n * 4 + 1];
    float x2 = boxes[n * 4 + 2], y2 = boxes[n * 4 + 3];
    float bw = (x2 - x1) * 0.5f, bh = (y2 - y1) * 0.5f;
    float sxv[2] = { x1 + 0.5f * bw, x1 + 1.5f * bw };
    float syv[2] = { y1 + 0.5f * bh, y1 + 1.5f * bh };
    float px[4] = { sxv[0], sxv[1], sxv[0], sxv[1] };
    float py[4] = { syv[0], syv[0], syv[1], syv[1] };
    const float* f = dec + (b * ODEC + c) * 2304;
    float res[4];
#pragma unroll
    for (int p = 0; p < 4; ++p) {
        float yy = fminf(fmaxf(py[p], 0.f), 47.f);
        float xx = fminf(fmaxf(px[p], 0.f), 47.f);
        int y0 = (int)floorf(yy), x0 = (int)floorf(xx);
        int y1i = min(y0 + 1, 47), x1i = min(x0 + 1, 47);
        float wy = yy - (float)y0, wx = xx - (float)x0;
        float f00 = f[y0 * 48 + x0],  f01 = f[y0 * 48 + x1i];
        float f10 = f[y1i * 48 + x0], f11 = f[y1i * 48 + x1i];
        res[p] = f00 * (1.f - wy) * (1.f - wx) + f01 * (1.f - wy) * wx
               + f10 * wy * (1.f - wx) + f11 * wy * wx;
    }
    float4 o4 = make_float4(res[0], res[1], res[2], res[3]);
    *(float4*)&cnn[n * 1024 + c * 4] = o4;
}

// ---------------------------------------------------------------------------
// box geometric features bf[n][4]
// ---------------------------------------------------------------------------
__global__ void mkbf_kernel(const float* __restrict__ boxes, float* __restrict__ bf) {
    int n = blockIdx.x * 256 + threadIdx.x;
    if (n >= BnN) return;
    float x1 = boxes[n * 4 + 0], y1 = boxes[n * 4 + 1];
    float x2 = boxes[n * 4 + 2], y2 = boxes[n * 4 + 3];
    bf[n * 4 + 0] = ((x1 + x2) * 0.5f) / 48.f;
    bf[n * 4 + 1] = ((y1 + y2) * 0.5f) / 48.f;
    bf[n * 4 + 2] = (x2 - x1) / 48.f;
    bf[n * 4 + 3] = (y2 - y1) / 48.f;
}

// ---------------------------------------------------------------------------
// generic tiled fp32 GEMM: C = act(A@B + bias). 64x64 tile, 4x4 per thread.
// ACT: 0 none, 1 relu, 2 leaky(0.01)
// ---------------------------------------------------------------------------
template <int ACT>
__global__ __launch_bounds__(256) void gemm_kernel(
    const float* __restrict__ A, const float* __restrict__ B,
    const float* __restrict__ bias, float* __restrict__ C,
    int M, int N, int K, int ldA, int ldB, int ldC)
{
    __shared__ float As[16][64];
    __shared__ float Bs[16][64];
    const int m0 = blockIdx.y * 64, n0 = blockIdx.x * 64;
    const int tid = threadIdx.x;
    const int ma = tid >> 2, ka = (tid & 3) * 4;
    const int kb = tid >> 4, nb = (tid & 15) * 4;
    const int ty = tid >> 4, tx = tid & 15;
    float acc[4][4] = {};
    for (int kk = 0; kk < K; kk += 16) {
        float a0 = 0.f, a1 = 0.f, a2 = 0.f, a3 = 0.f;
        if (m0 + ma < M) {
            const float* ap = A + (size_t)(m0 + ma) * ldA + kk + ka;
            if (kk + ka + 0 < K) a0 = ap[0];
            if (kk + ka + 1 < K) a1 = ap[1];
            if (kk + ka + 2 < K) a2 = ap[2];
            if (kk + ka + 3 < K) a3 = ap[3];
        }
        As[ka + 0][ma] = a0; As[ka + 1][ma] = a1; As[ka + 2][ma] = a2; As[ka + 3][ma] = a3;
        float4 bv = make_float4(0.f, 0.f, 0.f, 0.f);
        if (kk + kb < K) {
            const float* bp = B + (size_t)(kk + kb) * ldB + n0 + nb;
            if (n0 + nb + 0 < N) bv.x = bp[0];
            if (n0 + nb + 1 < N) bv.y = bp[1];
            if (n0 + nb + 2 < N) bv.z = bp[2];
            if (n0 + nb + 3 < N) bv.w = bp[3];
        }
        *(float4*)&Bs[kb][nb] = bv;
        __syncthreads();
#pragma unroll
        for (int k = 0; k < 16; ++k) {
            float4 av4 = *(const float4*)&As[k][ty * 4];
            float4 bv4 = *(const float4*)&Bs[k][tx * 4];
            float aarr[4] = { av4.x, av4.y, av4.z, av4.w };
            float barr[4] = { bv4.x, bv4.y, bv4.z, bv4.w };
#pragma unroll
            for (int i = 0; i < 4; ++i)
#pragma unroll
                for (int j = 0; j < 4; ++j) acc[i][j] += aarr[i] * barr[j];
        }
        __syncthreads();
    }
#pragma unroll
    for (int i = 0; i < 4; ++i) {
        int m = m0 + ty * 4 + i;
        if (m >= M) continue;
#pragma unroll
        for (int j = 0; j < 4; ++j) {
            int n = n0 + tx * 4 + j;
            if (n >= N) continue;
            float v = acc[i][j] + (bias ? bias[n] : 0.f);
            if (ACT == 1) v = fmaxf(v, 0.f);
            if (ACT == 2) v = (v >= 0.f) ? v : 0.01f * v;
            C[(size_t)m * ldC + n] = v;
        }
    }
}

// ---------------------------------------------------------------------------
// E0: per-batch centers (fp32, exact replica of reference op order)
//     + table extents (fp32 max-reduce)
// ---------------------------------------------------------------------------
__global__ __launch_bounds__(512) void e0_kernel(
    const float* __restrict__ boxes, const float* __restrict__ scales,
    const float* __restrict__ pdls, const float* __restrict__ pdts,
    float* __restrict__ cxA, float* __restrict__ cyA, float* __restrict__ tb)
{
    __shared__ float sw[512], sh[512];
    int b = blockIdx.x, n = threadIdx.x;
    float pdl = pdls[b], pdt = pdts[b], sc = scales[b];
    const float* bx = boxes + (size_t)(b * 512 + n) * 4;
    float o0 = (bx[0] - pdl) / sc;
    float o1 = (bx[1] - pdt) / sc;
    float o2 = (bx[2] - pdl) / sc;
    float o3 = (bx[3] - pdt) / sc;
    cxA[b * 512 + n] = (o0 + o2) * 0.5f;
    cyA[b * 512 + n] = (o1 + o3) * 0.5f;
    sw[n] = fmaxf(o0, o2); sh[n] = fmaxf(o1, o3);
    __syncthreads();
    for (int s = 256; s > 0; s >>= 1) {
        if (n < s) { sw[n] = fmaxf(sw[n], sw[n + s]); sh[n] = fmaxf(sh[n], sh[n + s]); }
        __syncthreads();
    }
    if (n == 0) { tb[b * 2 + 0] = sw[0]; tb[b * 2 + 1] = sh[0]; }
}

// ---------------------------------------------------------------------------
// Ranking key: reference top_k key is attr = exp(-q) (fp32), DESCENDING,
// ties broken by pair index. Key = ~bits(w) ascending == w descending.
// w computed correctly-rounded: f32(exp64(-q32)).
// ---------------------------------------------------------------------------
__device__ __forceinline__ float q_val(const float* sv, float tbv, int e) {
    int i = e / 511; int jj = e - i * 511; int j = jj + (jj >= i ? 1 : 0);
    float diff = sv[i] - sv[j];
    float u = (diff * 5.0f) / tbv;
    return u * u;
}
__device__ __forceinline__ u32 key_bits(const float* sv, float tbv, int e) {
    float q = q_val(sv, tbv, e);
    float w = (float)exp(-(double)q);
    return ~__float_as_uint(w);
}

// ---------------------------------------------------------------------------
// E2: 32-bit radix select of K-th smallest key (== K-th largest w).
// ---------------------------------------------------------------------------
__global__ __launch_bounds__(1024) void select_kernel(
    const float* __restrict__ cxA, const float* __restrict__ cyA,
    const float* __restrict__ tb,
    u32* __restrict__ candA, u32* __restrict__ candB,
    u32* __restrict__ kstar, int* __restrict__ rstar)
{
    const int sel = blockIdx.x;
    const int b = sel >> 1, t = sel & 1;
    const int tid = threadIdx.x;
    const int wv = tid >> 6;
    __shared__ float sv[512];
    __shared__ u32 h[16][256];
    __shared__ u32 tot[256];
    __shared__ int s_digit, s_need, s_cnt;
    __shared__ float s_tb;
    if (tid < 512) sv[tid] = (t == 0) ? cyA[b * 512 + tid] : cxA[b * 512 + tid];
    if (tid == 0) s_tb = tb[b * 2 + (t == 0 ? 1 : 0)];
    __syncthreads();
    const float tbv = s_tb;
    int need = KEDGE;
    u32 prefix = 0;

    for (int x = tid; x < 16 * 256; x += 1024) ((u32*)h)[x] = 0;
    __syncthreads();
    for (int e = tid; e < NE; e += 1024) {
        u32 kb2 = key_bits(sv, tbv, e);
        atomicAdd(&h[wv][(int)(kb2 >> 24)], 1u);
    }
    __syncthreads();
    if (tid < 256) { u32 s = 0; for (int w = 0; w < 16; ++w) s += h[w][tid]; tot[tid] = s; }
    __syncthreads();
    if (tid == 0) {
        u32 cum = 0; int d = 255;
        for (int bb = 0; bb < 256; ++bb) { if (cum + tot[bb] >= (u32)need) { d = bb; break; } cum += tot[bb]; }
        s_digit = d; s_need = need - (int)cum;
    }
    __syncthreads();
    prefix |= ((u32)s_digit) << 24; need = s_need;
    __syncthreads();

    for (int x = tid; x < 16 * 256; x += 1024) ((u32*)h)[x] = 0;
    __syncthreads();
    for (int e = tid; e < NE; e += 1024) {
        u32 kb2 = key_bits(sv, tbv, e);
        if ((kb2 >> 24) == (prefix >> 24)) atomicAdd(&h[wv][(int)((kb2 >> 16) & 0xFF)], 1u);
    }
    __syncthreads();
    if (tid < 256) { u32 s = 0; for (int w = 0; w < 16; ++w) s += h[w][tid]; tot[tid] = s; }
    __syncthreads();
    if (tid == 0) {
        u32 cum = 0; int d = 255;
        for (int bb = 0; bb < 256; ++bb) { if (cum + tot[bb] >= (u32)need) { d = bb; break; } cum += tot[bb]; }
        s_digit = d; s_need = need - (int)cum;
    }
    __syncthreads();
    prefix |= ((u32)s_digit) << 16; need = s_need;
    if (tid == 0) s_cnt = 0;
    __syncthreads();

    u32* cA = candA + (size_t)sel * CAP;
    u32* cB = candB + (size_t)sel * CAP;
    for (int e = tid; e < NE; e += 1024) {
        u32 kb2 = key_bits(sv, tbv, e);
        if ((kb2 >> 16) == (prefix >> 16)) {
            int pos = atomicAdd(&s_cnt, 1);
            if (pos < CAP) cA[pos] = kb2;
        }
    }
    __syncthreads();
    int C = min(s_cnt, CAP);
    u32* cur = cA; u32* nxt = cB;

    for (int shift = 8; shift >= 0; shift -= 8) {
        __syncthreads();
        for (int x = tid; x < 16 * 256; x += 1024) ((u32*)h)[x] = 0;
        __syncthreads();
        for (int k = tid; k < C; k += 1024)
            atomicAdd(&h[wv][(int)((cur[k] >> shift) & 0xFF)], 1u);
        __syncthreads();
        if (tid < 256) { u32 s = 0; for (int w = 0; w < 16; ++w) s += h[w][tid]; tot[tid] = s; }
        __syncthreads();
        if (tid == 0) {
            u32 cum = 0; int d = 255;
            for (int bb = 0; bb < 256; ++bb) { if (cum + tot[bb] >= (u32)need) { d = bb; break; } cum += tot[bb]; }
            s_digit = d; s_need = need - (int)cum;
            s_cnt = 0;
        }
        __syncthreads();
        int dig = s_digit;
        prefix |= ((u32)dig) << shift; need = s_need;
        for (int k = tid; k < C; k += 1024) {
            u32 kb2 = cur[k];
            if ((int)((kb2 >> shift) & 0xFF) == dig) {
                int pos = atomicAdd(&s_cnt, 1);
                if (pos < CAP) nxt[pos] = kb2;
            }
        }
        __syncthreads();
        C = min(s_cnt, CAP);
        u32* tmp = cur; cur = nxt; nxt = tmp;
    }
    if (tid == 0) { kstar[sel] = prefix; rstar[sel] = need; }
}

// ---------------------------------------------------------------------------
// E3: emit edges with key < k*; queue ties (key == k*)
// ---------------------------------------------------------------------------
__device__ __forceinline__ void emit_edge(int t, int src, int dst, float w,
    int* es, int* ed, float* ew, int* ecnt, int* indeg, float* degw)
{
    int slot = atomicAdd(&ecnt[t], 1);
    es[t * 16384 + slot] = src;
    ed[t * 16384 + slot] = dst;
    ew[t * 16384 + slot] = w;
    atomicAdd(&indeg[t * 2048 + dst], 1);
    atomicAdd(&degw[t * 2048 + dst], w);
}

__global__ void e3_kernel(
    const float* __restrict__ cxA, const float* __restrict__ cyA,
    const float* __restrict__ tb, const u32* __restrict__ kstar,
    int* __restrict__ tiebuf, int* __restrict__ tiecnt,
    int* __restrict__ es, int* __restrict__ ed, float* __restrict__ ew,
    int* __restrict__ ecnt, int* __restrict__ indeg, float* __restrict__ degw)
{
    int idx = blockIdx.x * 256 + threadIdx.x;
    if (idx >= 8 * NE) return;
    int sel = idx / NE; int e = idx - sel * NE;
    int b = sel >> 1, t = sel & 1;
    const float* v = (t == 0) ? cyA : cxA;
    float tbv = tb[b * 2 + (t == 0 ? 1 : 0)];
    int i = e / 511; int jj = e - i * 511; int j = jj + (jj >= i ? 1 : 0);
    float diff = v[b * 512 + i] - v[b * 512 + j];
    float u = (diff * 5.0f) / tbv;
    float q = u * u;
    float w = (float)exp(-(double)q);
    u32 kb2 = ~__float_as_uint(w);
    u32 ks = kstar[sel];
    if (kb2 < ks) {
        emit_edge(t, b * 512 + i, b * 512 + j, w, es, ed, ew, ecnt, indeg, degw);
    } else if (kb2 == ks) {
        int p = atomicAdd(&tiecnt[sel], 1);
        if (p < TIECAP) tiebuf[sel * TIECAP + p] = e;
    }
}

// E3b: resolve ties by smallest pair-index (lax.top_k semantics)
__global__ void e3b_kernel(
    const u32* __restrict__ kstar, const int* __restrict__ rstar,
    const int* __restrict__ tiebuf, const int* __restrict__ tiecnt,
    int* __restrict__ es, int* __restrict__ ed, float* __restrict__ ew,
    int* __restrict__ ecnt, int* __restrict__ indeg, float* __restrict__ degw)
{
    int sel = blockIdx.x;
    int b = sel >> 1, t = sel & 1;
    int m = min(tiecnt[sel], TIECAP);
    int r = rstar[sel];
    float w = __uint_as_float(~kstar[sel]);
    for (int k = threadIdx.x; k < m; k += blockDim.x) {
        int e = tiebuf[sel * TIECAP + k];
        int rank = 0;
        for (int l = 0; l < m; ++l) rank += (tiebuf[sel * TIECAP + l] < e) ? 1 : 0;
        if (rank < r) {
            int i = e / 511; int jj = e - i * 511; int j = jj + (jj >= i ? 1 : 0);
            emit_edge(t, b * 512 + i, b * 512 + j, w, es, ed, ew, ecnt, indeg, degw);
        }
    }
}

__global__ void e4_kernel(const float* __restrict__ degw, float* __restrict__ dis) {
    int i = blockIdx.x * 256 + threadIdx.x;
    if (i < 4096) dis[i] = 1.0f / sqrtf(degw[i]);
}

// E5: exclusive scan of indeg (2048 per type), one block per type
__global__ __launch_bounds__(1024) void scan_kernel(const int* __restrict__ indeg, int* __restrict__ offs) {
    __shared__ int bufA[2048], bufB[2048];
    int t = blockIdx.x, tid = threadIdx.x;
    bufA[tid] = indeg[t * 2048 + tid];
    bufA[tid + 1024] = indeg[t * 2048 + tid + 1024];
    __syncthreads();
    int* src = bufA; int* dst = bufB;
    for (int st = 1; st < 2048; st <<= 1) {
        dst[tid] = src[tid] + (tid >= st ? src[tid - st] : 0);
        int k1 = tid + 1024;
        dst[k1] = src[k1] + (k1 >= st ? src[k1 - st] : 0);
        __syncthreads();
        int* tmp = src; src = dst; dst = tmp;
    }
    offs[t * 2048 + tid] = (tid == 0) ? 0 : src[tid - 1];
    offs[t * 2048 + tid + 1024] = src[tid + 1023];
}

__global__ void fill_kernel(const int* __restrict__ ed, const int* __restrict__ offs,
                            int* __restrict__ fill, int* __restrict__ csr) {
    int idx = blockIdx.x * 256 + threadIdx.x;
    if (idx >= 32768) return;
    int t = idx >> 14, e = idx & 16383;
    int d = ed[t * 16384 + e];
    int pos = offs[t * 2048 + d] + atomicAdd(&fill[t * 2048 + d], 1);
    csr[t * 16384 + pos] = e;
}

// E7: GCN aggregate per (type, dst-node): relu(sum norm*xw[src] + self + bias)
__global__ __launch_bounds__(256) void gcn_agg_kernel(
    const float* __restrict__ xw_row, const float* __restrict__ xw_col,
    const float* __restrict__ b_row, const float* __restrict__ b_col,
    const int* __restrict__ es, const float* __restrict__ ew,
    const int* __restrict__ csr, const int* __restrict__ offs,
    const int* __restrict__ indeg, const float* __restrict__ dis,
    float* __restrict__ feat_row, float* __restrict__ feat_col)
{
    int d = blockIdx.x; int t = blockIdx.y;
    const float* xw = t ? xw_col : xw_row;
    const float* bg = t ? b_col : b_row;
    float* out = t ? feat_col : feat_row;
    int f0 = threadIdx.x, f1 = threadIdx.x + 256;
    float dd = dis[t * 2048 + d];
    float a0 = dd * dd * xw[(size_t)d * 512 + f0];
    float a1 = dd * dd * xw[(size_t)d * 512 + f1];
    int st = offs[t * 2048 + d], cnt = indeg[t * 2048 + d];
    for (int k = 0; k < cnt; ++k) {
        int e = csr[t * 16384 + st + k];
        int s = es[t * 16384 + e];
        float w = ew[t * 16384 + e];
        float coef = dis[t * 2048 + s] * w * dd;
        a0 += coef * xw[(size_t)s * 512 + f0];
        a1 += coef * xw[(size_t)s * 512 + f1];
    }
    a0 += bg[f0]; a1 += bg[f1];
    out[(size_t)d * 512 + f0] = fmaxf(a0, 0.f);
    out[(size_t)d * 512 + f1] = fmaxf(a1, 0.f);
}

// ---------------------------------------------------------------------------
extern "C" void kernel_launch(void* const* d_in, const int* in_sizes, int n_in,
                              void* d_out, int out_size, void* d_ws, size_t ws_size,
                              hipStream_t stream)
{
    const float* x      = (const float*)d_in[0];
    const float* boxes  = (const float*)d_in[1];
    const float* scales = (const float*)d_in[2];
    const float* pdls   = (const float*)d_in[3];
    const float* pdts   = (const float*)d_in[4];
    const float* W_dec  = (const float*)d_in[5];
    const float* b_dec  = (const float*)d_in[6];
    const float* W_box  = (const float*)d_in[7];
    const float* b_box  = (const float*)d_in[8];
    const float* W_cnn  = (const float*)d_in[9];
    const float* b_cnn  = (const float*)d_in[10];
    const float* W_grow = (const float*)d_in[11];
    const float* b_grow = (const float*)d_in[12];
    const float* W_gcol = (const float*)d_in[13];
    const float* b_gcol = (const float*)d_in[14];
    const float* W_rcls = (const float*)d_in[15];
    const float* b_rcls = (const float*)d_in[16];
    const float* W_ccls = (const float*)d_in[17];
    const float* b_ccls = (const float*)d_in[18];

    char* ws = (char*)d_ws;
    size_t off = 0;
    auto alloc = [&](size_t bytes) -> void* {
        void* p = ws + off;
        off = (off + bytes + 255) & ~(size_t)255;
        return p;
    };
    float* dec    = (float*)alloc((size_t)2359296 * 4);   // (4,256,48,48)
    float* fusion = (float*)alloc((size_t)1572864 * 4);   // (2048,768)
    float* cnn    = (float*)alloc((size_t)2097152 * 4);   // (2048,1024)
    float* xw     = (float*)alloc((size_t)2097152 * 4);   // xw_row|xw_col (2048,512)x2
    u32*   cand   = (u32*)  alloc((size_t)16 * CAP * 4);  // radix candidates A|B
    float* feats  = (float*)alloc((size_t)2097152 * 4);   // feat_row|feat_col
    float* bf     = (float*)alloc((size_t)8192 * 4);
    float* cxA    = (float*)alloc((size_t)2048 * 4);
    float* cyA    = (float*)alloc((size_t)2048 * 4);
    float* tbA    = (float*)alloc((size_t)8 * 4);
    u32*  kstar   = (u32*)  alloc((size_t)8 * 4);
    int*  rstar   = (int*)  alloc((size_t)8 * 4);
    int*  tiebuf  = (int*)  alloc((size_t)8 * TIECAP * 4);
    int*  tiecnt  = (int*)  alloc((size_t)8 * 4);
    int*  es      = (int*)  alloc((size_t)2 * 16384 * 4);
    int*  ed      = (int*)  alloc((size_t)2 * 16384 * 4);
    float* ewt    = (float*)alloc((size_t)2 * 16384 * 4);
    int*  ecnt    = (int*)  alloc((size_t)64);
    int*  indeg   = (int*)  alloc((size_t)4096 * 4);
    float* degw   = (float*)alloc((size_t)4096 * 4);
    float* dis    = (float*)alloc((size_t)4096 * 4);
    int*  offsA   = (int*)  alloc((size_t)4096 * 4);
    int*  fillA   = (int*)  alloc((size_t)4096 * 4);
    int*  csr     = (int*)  alloc((size_t)2 * 16384 * 4);
    // bf16 hi/lo split buffers (conv MFMA path)
    ushort* xh = (ushort*)alloc((size_t)4 * 48 * 48 * 1024 * 2);   // NHWC
    ushort* xl = (ushort*)alloc((size_t)4 * 48 * 48 * 1024 * 2);
    ushort* wh = (ushort*)alloc((size_t)256 * 9 * 1024 * 2);       // [o][tap][ch]
    ushort* wl = (ushort*)alloc((size_t)256 * 9 * 1024 * 2);

    float* out = (float*)d_out;

    init_kernel<<<16, 256, 0, stream>>>(degw, indeg, fillA, ecnt, tiecnt);
    split_x_kernel<<<dim3(16, 48, 4), 256, 0, stream>>>(x, xh, xl);
    split_w_kernel<<<dim3(9, 256), 256, 0, stream>>>(W_dec, wh, wl);
    conv_mfma_kernel<<<dim3(48, 8, 4), 128, 0, stream>>>(xh, xl, wh, wl, b_dec, dec);
    roi_kernel<<<2048, 256, 0, stream>>>(dec, boxes, cnn);
    mkbf_kernel<<<8, 256, 0, stream>>>(boxes, bf);
    // fusion = [relu(bf@W_box+b) | relu(cnn@W_cnn+b)]
    gemm_kernel<1><<<dim3(4, 32), 256, 0, stream>>>(bf, W_box, b_box, fusion, 2048, 256, 4, 4, 256, 768);
    gemm_kernel<1><<<dim3(8, 32), 256, 0, stream>>>(cnn, W_cnn, b_cnn, fusion + 256, 2048, 512, 1024, 1024, 512, 768);
    // edge selection
    e0_kernel<<<4, 512, 0, stream>>>(boxes, scales, pdls, pdts, cxA, cyA, tbA);
    select_kernel<<<8, 1024, 0, stream>>>(cxA, cyA, tbA, cand, cand + (size_t)8 * CAP, kstar, rstar);
    e3_kernel<<<8176, 256, 0, stream>>>(cxA, cyA, tbA, kstar, tiebuf, tiecnt, es, ed, ewt, ecnt, indeg, degw);
    e3b_kernel<<<8, 256, 0, stream>>>(kstar, rstar, tiebuf, tiecnt, es, ed, ewt, ecnt, indeg, degw);
    e4_kernel<<<16, 256, 0, stream>>>(degw, dis);
    scan_kernel<<<2, 1024, 0, stream>>>(indeg, offsA);
    fill_kernel<<<128, 256, 0, stream>>>(ed, offsA, fillA, csr);
    // xw = fusion @ W_g{row,col}  (no bias/act; bias applied after aggregation)
    gemm_kernel<0><<<dim3(8, 32), 256, 0, stream>>>(fusion, W_grow, nullptr, xw, 2048, 512, 768, 768, 512, 512);
    gemm_kernel<0><<<dim3(8, 32), 256, 0, stream>>>(fusion, W_gcol, nullptr, xw + 1048576, 2048, 512, 768, 768, 512, 512);
    gcn_agg_kernel<<<dim3(2048, 2), 256, 0, stream>>>(xw, xw + 1048576, b_grow, b_gcol,
                                                      es, ewt, csr, offsA, indeg, dis,
                                                      feats, feats + 1048576);
    // classifier heads (leaky relu 0.01)
    gemm_kernel<2><<<dim3(4, 32), 256, 0, stream>>>(feats, W_rcls, b_rcls, out, 2048, 228, 512, 512, 228, 228);
    gemm_kernel<2><<<dim3(2, 32), 256, 0, stream>>>(feats + 1048576, W_ccls, b_ccls, out + (size_t)2048 * 228,
                                                    2048, 116, 512, 512, 116, 116);
}

// Round 5
// 1118.427 us; speedup vs baseline: 3.4987x; 1.9419x over previous
//
#include <hip/hip_runtime.h>
#include <cstdint>
#include <math.h>

typedef unsigned int u32;
typedef unsigned long long u64;
typedef unsigned short ushort;

typedef __attribute__((ext_vector_type(8))) _Float16 f16x8;
typedef __attribute__((ext_vector_type(4))) _Float16 f16x4;
typedef __attribute__((ext_vector_type(4))) float f32x4;

#define NB    4
#define NPB   512
#define BnN   2048
#define CIN   1024
#define ODEC  256
#define NE    261632      // 512*511 ordered pairs per batch
#define KEDGE 4096
#define CAP   65536
#define TIECAP 2048

// ---------------------------------------------------------------------------
// init: zero/one the accumulators that the harness poisons with 0xAA
// ---------------------------------------------------------------------------
__global__ void init_kernel(float* degw, int* indeg, int* fill, int* ecnt, int* tiecnt) {
    int i = blockIdx.x * 256 + threadIdx.x;
    if (i < 4096) { degw[i] = 1.0f; indeg[i] = 0; fill[i] = 0; }
    if (i < 8)    tiecnt[i] = 0;
    if (i < 2)    ecnt[i]   = 0;
}

// ---------------------------------------------------------------------------
// convert input: NCHW fp32 -> NHWC f16.  grid (16 chgrp, 48 y, 4 b), block 256
// ---------------------------------------------------------------------------
__global__ __launch_bounds__(256) void cvt_x_kernel(
    const float* __restrict__ in, _Float16* __restrict__ xf)
{
    __shared__ _Float16 sh[64][49];
    int cg = blockIdx.x, y = blockIdx.y, b = blockIdx.z;
    int tid = threadIdx.x;
    for (int i = tid; i < 64 * 48; i += 256) {
        int cl = i / 48, x = i - cl * 48;
        sh[cl][x] = (_Float16)in[(((size_t)b * 1024 + cg * 64 + cl) * 48 + y) * 48 + x];
    }
    __syncthreads();
    for (int i = tid; i < 64 * 48; i += 256) {
        int x = i / 64, cl = i - x * 64;
        xf[((size_t)(b * 48 + y) * 48 + x) * 1024 + cg * 64 + cl] = sh[cl][x];
    }
}

// convert weights: [o][ch][3][3] fp32 -> [o][tap][ch] f16. grid 256, block 256
__global__ __launch_bounds__(256) void cvt_w_kernel(
    const float* __restrict__ W, _Float16* __restrict__ wf)
{
    __shared__ _Float16 sh[9216];
    int o = blockIdx.x, tid = threadIdx.x;
    for (int g = tid; g < 9216; g += 256)
        sh[g] = (_Float16)W[(size_t)o * 9216 + g];     // g = ch*9+tap
    __syncthreads();
    for (int g = tid; g < 9216; g += 256) {
        int tap = g >> 10, ch = g & 1023;
        wf[(size_t)o * 9216 + g] = sh[ch * 9 + tap];
    }
}

// transpose-convert: in fp32 [K][N] -> out f16 [N][K]. grid (ceil(N/32), ceil(K/32))
__global__ __launch_bounds__(256) void cvt_t_kernel(
    const float* __restrict__ in, _Float16* __restrict__ out, int K, int N)
{
    __shared__ _Float16 sh[32][33];
    int n0 = blockIdx.x * 32, k0 = blockIdx.y * 32;
    int tx = threadIdx.x & 31, ty = threadIdx.x >> 5;
#pragma unroll
    for (int i = 0; i < 4; ++i) {
        int k = k0 + ty + i * 8, n = n0 + tx;
        sh[ty + i * 8][tx] = (k < K && n < N) ? (_Float16)in[(size_t)k * N + n] : (_Float16)0.f;
    }
    __syncthreads();
#pragma unroll
    for (int i = 0; i < 4; ++i) {
        int n = n0 + ty + i * 8, k = k0 + tx;
        if (n < N && k < K) out[(size_t)n * K + k] = sh[tx][ty + i * 8];
    }
}

// ---------------------------------------------------------------------------
// conv 3x3 SAME 1024->256 +bias +relu. Implicit-GEMM MFMA f16 (fp32 acc).
// Block 256 thr (4 waves): 32 och x 4 rows (192 px), wave = 1 row.
// grid (12 ygroup, 8 og, 4 b). K-chunks of 32 ch, all 9 taps staged.
// Output: dec NHWC f16.
// ---------------------------------------------------------------------------
__global__ __launch_bounds__(256) void conv_f16_kernel(
    const _Float16* __restrict__ xf, const _Float16* __restrict__ wf,
    const float* __restrict__ bd, _Float16* __restrict__ dec)
{
    __shared__ _Float16 wS[9][4][32][8];   // 18.4 KB  [tap][q][och][8ch]
    __shared__ _Float16 xS[6][4][50][8];   // 19.2 KB  [row][q][col][8ch]
    const int y0 = blockIdx.x * 4;
    const int og = blockIdx.y;
    const int b  = blockIdx.z;
    const int tid = threadIdx.x;
    const int wv = tid >> 6;
    const int ln = tid & 63;
    const int n  = ln & 15;
    const int q  = ln >> 4;

    f32x4 acc[2][3];
#pragma unroll
    for (int mt = 0; mt < 2; ++mt)
#pragma unroll
        for (int nt = 0; nt < 3; ++nt) acc[mt][nt] = (f32x4){0.f, 0.f, 0.f, 0.f};

    for (int cc = 0; cc < 1024; cc += 32) {
        // stage weights: 1152 x 16B (shift-only indexing)
#pragma unroll
        for (int it = 0; it < 5; ++it) {
            int g = it * 256 + tid;
            if (g < 1152) {
                int tap = g >> 7, r = g & 127, qq = r >> 5, oc = r & 31;
                *(uint4*)&wS[tap][qq][oc][0] =
                    *(const uint4*)(wf + ((size_t)(og * 32 + oc) * 9 + tap) * 1024 + cc + qq * 8);
            }
        }
        // stage input rows y0-1 .. y0+4, cols -1..48 : 1200 x 16B
#pragma unroll
        for (int it = 0; it < 5; ++it) {
            int g = it * 256 + tid;
            if (g < 1200) {
                int row = g / 200, r2 = g - row * 200;
                int qq = r2 / 50, c = r2 - qq * 50;
                int gy = y0 + row - 1, gx = c - 1;
                uint4 v = make_uint4(0u, 0u, 0u, 0u);
                if ((unsigned)gy < 48u && (unsigned)gx < 48u)
                    v = *(const uint4*)(xf + ((size_t)(b * 48 + gy) * 48 + gx) * 1024 + cc + qq * 8);
                *(uint4*)&xS[row][qq][c][0] = v;
            }
        }
        __syncthreads();

#pragma unroll
        for (int tap = 0; tap < 9; ++tap) {
            const int dy = tap / 3, dx = tap % 3;
            f16x8 a0 = *(const f16x8*)&wS[tap][q][n][0];
            f16x8 a1 = *(const f16x8*)&wS[tap][q][16 + n][0];
#pragma unroll
            for (int nt = 0; nt < 3; ++nt) {
                f16x8 bb = *(const f16x8*)&xS[wv + dy][q][nt * 16 + n + dx][0];
                acc[0][nt] = __builtin_amdgcn_mfma_f32_16x16x32_f16(a0, bb, acc[0][nt], 0, 0, 0);
                acc[1][nt] = __builtin_amdgcn_mfma_f32_16x16x32_f16(a1, bb, acc[1][nt], 0, 0, 0);
            }
        }
        __syncthreads();
    }

    // epilogue: D col=ln&15 (x), row=q*4+r (och). dec NHWC f16, 8B stores.
    const int y = y0 + wv;
#pragma unroll
    for (int mt = 0; mt < 2; ++mt) {
        float4 b4 = *(const float4*)(bd + og * 32 + mt * 16 + q * 4);
#pragma unroll
        for (int nt = 0; nt < 3; ++nt) {
            int x = nt * 16 + n;
            f16x4 v;
            v.x = (_Float16)fmaxf(acc[mt][nt][0] + b4.x, 0.f);
            v.y = (_Float16)fmaxf(acc[mt][nt][1] + b4.y, 0.f);
            v.z = (_Float16)fmaxf(acc[mt][nt][2] + b4.z, 0.f);
            v.w = (_Float16)fmaxf(acc[mt][nt][3] + b4.w, 0.f);
            *(f16x4*)(dec + ((size_t)(b * 48 + y) * 48 + x) * 256 + og * 32 + mt * 16 + q * 4) = v;
        }
    }
}

// ---------------------------------------------------------------------------
// ROI align 2x2 on NHWC f16 dec: one block per box, thread = channel.
// cnn[n][c*4+p] f16.
// ---------------------------------------------------------------------------
__global__ __launch_bounds__(256) void roi_kernel(
    const _Float16* __restrict__ dec, const float* __restrict__ boxes,
    _Float16* __restrict__ cnn)
{
    int n = blockIdx.x; int c = threadIdx.x;
    int b = n >> 9;
    float x1 = boxes[n * 4 + 0], y1 = boxes[n * 4 + 1];
    float x2 = boxes[n * 4 + 2], y2 = boxes[n * 4 + 3];
    float bw = (x2 - x1) * 0.5f, bh = (y2 - y1) * 0.5f;
    float sxv[2] = { x1 + 0.5f * bw, x1 + 1.5f * bw };
    float syv[2] = { y1 + 0.5f * bh, y1 + 1.5f * bh };
    float px[4] = { sxv[0], sxv[1], sxv[0], sxv[1] };
    float py[4] = { syv[0], syv[0], syv[1], syv[1] };
    const _Float16* f = dec + (size_t)b * 2304 * 256;
    f16x4 o4;
    float res[4];
#pragma unroll
    for (int p = 0; p < 4; ++p) {
        float yy = fminf(fmaxf(py[p], 0.f), 47.f);
        float xx = fminf(fmaxf(px[p], 0.f), 47.f);
        int y0 = (int)floorf(yy), x0 = (int)floorf(xx);
        int y1i = min(y0 + 1, 47), x1i = min(x0 + 1, 47);
        float wy = yy - (float)y0, wx = xx - (float)x0;
        float f00 = (float)f[(size_t)(y0 * 48 + x0) * 256 + c];
        float f01 = (float)f[(size_t)(y0 * 48 + x1i) * 256 + c];
        float f10 = (float)f[(size_t)(y1i * 48 + x0) * 256 + c];
        float f11 = (float)f[(size_t)(y1i * 48 + x1i) * 256 + c];
        res[p] = f00 * (1.f - wy) * (1.f - wx) + f01 * (1.f - wy) * wx
               + f10 * wy * (1.f - wx) + f11 * wy * wx;
    }
    o4.x = (_Float16)res[0]; o4.y = (_Float16)res[1];
    o4.z = (_Float16)res[2]; o4.w = (_Float16)res[3];
    *(f16x4*)(cnn + (size_t)n * 1024 + c * 4) = o4;
}

// ---------------------------------------------------------------------------
// box head: fusion[:, 0:256] = relu(bf @ W_box + b_box), bf computed inline.
// grid 2048 (row), block 256 (col). f16 store.
// ---------------------------------------------------------------------------
__global__ __launch_bounds__(256) void box_kernel(
    const float* __restrict__ boxes, const float* __restrict__ Wb,
    const float* __restrict__ bb, _Float16* __restrict__ fusion)
{
    int nrow = blockIdx.x, c = threadIdx.x;
    float x1 = boxes[nrow * 4 + 0], y1 = boxes[nrow * 4 + 1];
    float x2 = boxes[nrow * 4 + 2], y2 = boxes[nrow * 4 + 3];
    float bf0 = ((x1 + x2) * 0.5f) / 48.f;
    float bf1 = ((y1 + y2) * 0.5f) / 48.f;
    float bf2 = (x2 - x1) / 48.f;
    float bf3 = (y2 - y1) / 48.f;
    float acc = bb[c];
    acc += bf0 * Wb[0 * 256 + c];
    acc += bf1 * Wb[1 * 256 + c];
    acc += bf2 * Wb[2 * 256 + c];
    acc += bf3 * Wb[3 * 256 + c];
    fusion[(size_t)nrow * 768 + c] = (_Float16)fmaxf(acc, 0.f);
}

// ---------------------------------------------------------------------------
// f16 MFMA GEMM: C = act(A @ Bt^T + bias). A [M][K] f16, Bt [N][K] f16.
// 64x64 tile, 256 thr (4 waves, 2x2), wave = 32x32 (2m x 2n).
// M mult of 64, K mult of 32; N guarded. ACT: 0 none, 1 relu, 2 leaky.
// ---------------------------------------------------------------------------
template <int ACT, typename OUTT>
__global__ __launch_bounds__(256) void gemm16_kernel(
    const _Float16* __restrict__ A, const _Float16* __restrict__ Bt,
    const float* __restrict__ bias, OUTT* __restrict__ C,
    int M, int N, int K, int ldC)
{
    __shared__ _Float16 aS[64][4][8];
    __shared__ _Float16 bS[64][4][8];
    const int n0 = blockIdx.x * 64, m0 = blockIdx.y * 64;
    const int tid = threadIdx.x;
    const int wv = tid >> 6, ln = tid & 63;
    const int wm = wv & 1, wn = wv >> 1;
    const int lm = ln & 15, lq = ln >> 4;
    const int sr = tid >> 2, sq = tid & 3;

    f32x4 acc[2][2];
#pragma unroll
    for (int i = 0; i < 2; ++i)
#pragma unroll
        for (int j = 0; j < 2; ++j) acc[i][j] = (f32x4){0.f, 0.f, 0.f, 0.f};

    for (int cc = 0; cc < K; cc += 32) {
        *(uint4*)&aS[sr][sq][0] = *(const uint4*)(A + (size_t)(m0 + sr) * K + cc + sq * 8);
        uint4 bv = make_uint4(0u, 0u, 0u, 0u);
        if (n0 + sr < N)
            bv = *(const uint4*)(Bt + (size_t)(n0 + sr) * K + cc + sq * 8);
        *(uint4*)&bS[sr][sq][0] = bv;
        __syncthreads();
        f16x8 af[2], bf[2];
#pragma unroll
        for (int mt = 0; mt < 2; ++mt) af[mt] = *(const f16x8*)&aS[wm * 32 + mt * 16 + lm][lq][0];
#pragma unroll
        for (int nt = 0; nt < 2; ++nt) bf[nt] = *(const f16x8*)&bS[wn * 32 + nt * 16 + lm][lq][0];
#pragma unroll
        for (int mt = 0; mt < 2; ++mt)
#pragma unroll
            for (int nt = 0; nt < 2; ++nt)
                acc[mt][nt] = __builtin_amdgcn_mfma_f32_16x16x32_f16(af[mt], bf[nt], acc[mt][nt], 0, 0, 0);
        __syncthreads();
    }

#pragma unroll
    for (int mt = 0; mt < 2; ++mt) {
#pragma unroll
        for (int nt = 0; nt < 2; ++nt) {
            int col = n0 + wn * 32 + nt * 16 + lm;
            if (col >= N) continue;
            float bs = bias ? bias[col] : 0.f;
#pragma unroll
            for (int r = 0; r < 4; ++r) {
                int row = m0 + wm * 32 + mt * 16 + lq * 4 + r;
                float v = acc[mt][nt][r] + bs;
                if (ACT == 1) v = fmaxf(v, 0.f);
                if (ACT == 2) v = (v >= 0.f) ? v : 0.01f * v;
                C[(size_t)row * ldC + col] = (OUTT)v;
            }
        }
    }
}

// ---------------------------------------------------------------------------
// E0: per-batch centers + table extents (fp32, exact ref op order)
// ---------------------------------------------------------------------------
__global__ __launch_bounds__(512) void e0_kernel(
    const float* __restrict__ boxes, const float* __restrict__ scales,
    const float* __restrict__ pdls, const float* __restrict__ pdts,
    float* __restrict__ cxA, float* __restrict__ cyA, float* __restrict__ tb)
{
    __shared__ float sw[512], sh[512];
    int b = blockIdx.x, n = threadIdx.x;
    float pdl = pdls[b], pdt = pdts[b], sc = scales[b];
    const float* bx = boxes + (size_t)(b * 512 + n) * 4;
    float o0 = (bx[0] - pdl) / sc;
    float o1 = (bx[1] - pdt) / sc;
    float o2 = (bx[2] - pdl) / sc;
    float o3 = (bx[3] - pdt) / sc;
    cxA[b * 512 + n] = (o0 + o2) * 0.5f;
    cyA[b * 512 + n] = (o1 + o3) * 0.5f;
    sw[n] = fmaxf(o0, o2); sh[n] = fmaxf(o1, o3);
    __syncthreads();
    for (int s = 256; s > 0; s >>= 1) {
        if (n < s) { sw[n] = fmaxf(sw[n], sw[n + s]); sh[n] = fmaxf(sh[n], sh[n + s]); }
        __syncthreads();
    }
    if (n == 0) { tb[b * 2 + 0] = sw[0]; tb[b * 2 + 1] = sh[0]; }
}

// ---------------------------------------------------------------------------
// Ranking key = ~bits(f32(exp64(-q32))): attr descending, ties by index.
// ---------------------------------------------------------------------------
__device__ __forceinline__ u32 key_bits(const float* sv, float tbv, int e) {
    int i = e / 511; int jj = e - i * 511; int j = jj + (jj >= i ? 1 : 0);
    float diff = sv[i] - sv[j];
    float u = (diff * 5.0f) / tbv;
    float q = u * u;
    float w = (float)exp(-(double)q);
    return ~__float_as_uint(w);
}

__global__ __launch_bounds__(1024) void select_kernel(
    const float* __restrict__ cxA, const float* __restrict__ cyA,
    const float* __restrict__ tb,
    u32* __restrict__ candA, u32* __restrict__ candB,
    u32* __restrict__ kstar, int* __restrict__ rstar)
{
    const int sel = blockIdx.x;
    const int b = sel >> 1, t = sel & 1;
    const int tid = threadIdx.x;
    const int wv = tid >> 6;
    __shared__ float sv[512];
    __shared__ u32 h[16][256];
    __shared__ u32 tot[256];
    __shared__ int s_digit, s_need, s_cnt;
    __shared__ float s_tb;
    if (tid < 512) sv[tid] = (t == 0) ? cyA[b * 512 + tid] : cxA[b * 512 + tid];
    if (tid == 0) s_tb = tb[b * 2 + (t == 0 ? 1 : 0)];
    __syncthreads();
    const float tbv = s_tb;
    int need = KEDGE;
    u32 prefix = 0;

    for (int x = tid; x < 16 * 256; x += 1024) ((u32*)h)[x] = 0;
    __syncthreads();
    for (int e = tid; e < NE; e += 1024) {
        u32 kb2 = key_bits(sv, tbv, e);
        atomicAdd(&h[wv][(int)(kb2 >> 24)], 1u);
    }
    __syncthreads();
    if (tid < 256) { u32 s = 0; for (int w = 0; w < 16; ++w) s += h[w][tid]; tot[tid] = s; }
    __syncthreads();
    if (tid == 0) {
        u32 cum = 0; int d = 255;
        for (int bb = 0; bb < 256; ++bb) { if (cum + tot[bb] >= (u32)need) { d = bb; break; } cum += tot[bb]; }
        s_digit = d; s_need = need - (int)cum;
    }
    __syncthreads();
    prefix |= ((u32)s_digit) << 24; need = s_need;
    __syncthreads();

    for (int x = tid; x < 16 * 256; x += 1024) ((u32*)h)[x] = 0;
    __syncthreads();
    for (int e = tid; e < NE; e += 1024) {
        u32 kb2 = key_bits(sv, tbv, e);
        if ((kb2 >> 24) == (prefix >> 24)) atomicAdd(&h[wv][(int)((kb2 >> 16) & 0xFF)], 1u);
    }
    __syncthreads();
    if (tid < 256) { u32 s = 0; for (int w = 0; w < 16; ++w) s += h[w][tid]; tot[tid] = s; }
    __syncthreads();
    if (tid == 0) {
        u32 cum = 0; int d = 255;
        for (int bb = 0; bb < 256; ++bb) { if (cum + tot[bb] >= (u32)need) { d = bb; break; } cum += tot[bb]; }
        s_digit = d; s_need = need - (int)cum;
    }
    __syncthreads();
    prefix |= ((u32)s_digit) << 16; need = s_need;
    if (tid == 0) s_cnt = 0;
    __syncthreads();

    u32* cA = candA + (size_t)sel * CAP;
    u32* cB = candB + (size_t)sel * CAP;
    for (int e = tid; e < NE; e += 1024) {
        u32 kb2 = key_bits(sv, tbv, e);
        if ((kb2 >> 16) == (prefix >> 16)) {
            int pos = atomicAdd(&s_cnt, 1);
            if (pos < CAP) cA[pos] = kb2;
        }
    }
    __syncthreads();
    int C = min(s_cnt, CAP);
    u32* cur = cA; u32* nxt = cB;

    for (int shift = 8; shift >= 0; shift -= 8) {
        __syncthreads();
        for (int x = tid; x < 16 * 256; x += 1024) ((u32*)h)[x] = 0;
        __syncthreads();
        for (int k = tid; k < C; k += 1024)
            atomicAdd(&h[wv][(int)((cur[k] >> shift) & 0xFF)], 1u);
        __syncthreads();
        if (tid < 256) { u32 s = 0; for (int w = 0; w < 16; ++w) s += h[w][tid]; tot[tid] = s; }
        __syncthreads();
        if (tid == 0) {
            u32 cum = 0; int d = 255;
            for (int bb = 0; bb < 256; ++bb) { if (cum + tot[bb] >= (u32)need) { d = bb; break; } cum += tot[bb]; }
            s_digit = d; s_need = need - (int)cum;
            s_cnt = 0;
        }
        __syncthreads();
        int dig = s_digit;
        prefix |= ((u32)dig) << shift; need = s_need;
        for (int k = tid; k < C; k += 1024) {
            u32 kb2 = cur[k];
            if ((int)((kb2 >> shift) & 0xFF) == dig) {
                int pos = atomicAdd(&s_cnt, 1);
                if (pos < CAP) nxt[pos] = kb2;
            }
        }
        __syncthreads();
        C = min(s_cnt, CAP);
        u32* tmp = cur; cur = nxt; nxt = tmp;
    }
    if (tid == 0) { kstar[sel] = prefix; rstar[sel] = need; }
}

// ---------------------------------------------------------------------------
// E3: emit edges with key < k*; queue ties
// ---------------------------------------------------------------------------
__device__ __forceinline__ void emit_edge(int t, int src, int dst, float w,
    int* es, int* ed, float* ew, int* ecnt, int* indeg, float* degw)
{
    int slot = atomicAdd(&ecnt[t], 1);
    es[t * 16384 + slot] = src;
    ed[t * 16384 + slot] = dst;
    ew[t * 16384 + slot] = w;
    atomicAdd(&indeg[t * 2048 + dst], 1);
    atomicAdd(&degw[t * 2048 + dst], w);
}

__global__ void e3_kernel(
    const float* __restrict__ cxA, const float* __restrict__ cyA,
    const float* __restrict__ tb, const u32* __restrict__ kstar,
    int* __restrict__ tiebuf, int* __restrict__ tiecnt,
    int* __restrict__ es, int* __restrict__ ed, float* __restrict__ ew,
    int* __restrict__ ecnt, int* __restrict__ indeg, float* __restrict__ degw)
{
    int idx = blockIdx.x * 256 + threadIdx.x;
    if (idx >= 8 * NE) return;
    int sel = idx / NE; int e = idx - sel * NE;
    int b = sel >> 1, t = sel & 1;
    const float* v = (t == 0) ? cyA : cxA;
    float tbv = tb[b * 2 + (t == 0 ? 1 : 0)];
    int i = e / 511; int jj = e - i * 511; int j = jj + (jj >= i ? 1 : 0);
    float diff = v[b * 512 + i] - v[b * 512 + j];
    float u = (diff * 5.0f) / tbv;
    float q = u * u;
    float w = (float)exp(-(double)q);
    u32 kb2 = ~__float_as_uint(w);
    u32 ks = kstar[sel];
    if (kb2 < ks) {
        emit_edge(t, b * 512 + i, b * 512 + j, w, es, ed, ew, ecnt, indeg, degw);
    } else if (kb2 == ks) {
        int p = atomicAdd(&tiecnt[sel], 1);
        if (p < TIECAP) tiebuf[sel * TIECAP + p] = e;
    }
}

__global__ void e3b_kernel(
    const u32* __restrict__ kstar, const int* __restrict__ rstar,
    const int* __restrict__ tiebuf, const int* __restrict__ tiecnt,
    int* __restrict__ es, int* __restrict__ ed, float* __restrict__ ew,
    int* __restrict__ ecnt, int* __restrict__ indeg, float* __restrict__ degw)
{
    int sel = blockIdx.x;
    int b = sel >> 1, t = sel & 1;
    int m = min(tiecnt[sel], TIECAP);
    int r = rstar[sel];
    float w = __uint_as_float(~kstar[sel]);
    for (int k = threadIdx.x; k < m; k += blockDim.x) {
        int e = tiebuf[sel * TIECAP + k];
        int rank = 0;
        for (int l = 0; l < m; ++l) rank += (tiebuf[sel * TIECAP + l] < e) ? 1 : 0;
        if (rank < r) {
            int i = e / 511; int jj = e - i * 511; int j = jj + (jj >= i ? 1 : 0);
            emit_edge(t, b * 512 + i, b * 512 + j, w, es, ed, ew, ecnt, indeg, degw);
        }
    }
}

__global__ void e4_kernel(const float* __restrict__ degw, float* __restrict__ dis) {
    int i = blockIdx.x * 256 + threadIdx.x;
    if (i < 4096) dis[i] = 1.0f / sqrtf(degw[i]);
}

__global__ __launch_bounds__(1024) void scan_kernel(const int* __restrict__ indeg, int* __restrict__ offs) {
    __shared__ int bufA[2048], bufB[2048];
    int t = blockIdx.x, tid = threadIdx.x;
    bufA[tid] = indeg[t * 2048 + tid];
    bufA[tid + 1024] = indeg[t * 2048 + tid + 1024];
    __syncthreads();
    int* src = bufA; int* dst = bufB;
    for (int st = 1; st < 2048; st <<= 1) {
        dst[tid] = src[tid] + (tid >= st ? src[tid - st] : 0);
        int k1 = tid + 1024;
        dst[k1] = src[k1] + (k1 >= st ? src[k1 - st] : 0);
        __syncthreads();
        int* tmp = src; src = dst; dst = tmp;
    }
    offs[t * 2048 + tid] = (tid == 0) ? 0 : src[tid - 1];
    offs[t * 2048 + tid + 1024] = src[tid + 1023];
}

__global__ void fill_kernel(const int* __restrict__ ed, const int* __restrict__ offs,
                            int* __restrict__ fill, int* __restrict__ csr) {
    int idx = blockIdx.x * 256 + threadIdx.x;
    if (idx >= 32768) return;
    int t = idx >> 14, e = idx & 16383;
    int d = ed[t * 16384 + e];
    int pos = offs[t * 2048 + d] + atomicAdd(&fill[t * 2048 + d], 1);
    csr[t * 16384 + pos] = e;
}

// E7: GCN aggregate -> feats f16
__global__ __launch_bounds__(256) void gcn_agg_kernel(
    const float* __restrict__ xw_row, const float* __restrict__ xw_col,
    const float* __restrict__ b_row, const float* __restrict__ b_col,
    const int* __restrict__ es, const float* __restrict__ ew,
    const int* __restrict__ csr, const int* __restrict__ offs,
    const int* __restrict__ indeg, const float* __restrict__ dis,
    _Float16* __restrict__ feat_row, _Float16* __restrict__ feat_col)
{
    int d = blockIdx.x; int t = blockIdx.y;
    const float* xw = t ? xw_col : xw_row;
    const float* bg = t ? b_col : b_row;
    _Float16* out = t ? feat_col : feat_row;
    int f0 = threadIdx.x, f1 = threadIdx.x + 256;
    float dd = dis[t * 2048 + d];
    float a0 = dd * dd * xw[(size_t)d * 512 + f0];
    float a1 = dd * dd * xw[(size_t)d * 512 + f1];
    int st = offs[t * 2048 + d], cnt = indeg[t * 2048 + d];
    for (int k = 0; k < cnt; ++k) {
        int e = csr[t * 16384 + st + k];
        int s = es[t * 16384 + e];
        float w = ew[t * 16384 + e];
        float coef = dis[t * 2048 + s] * w * dd;
        a0 += coef * xw[(size_t)s * 512 + f0];
        a1 += coef * xw[(size_t)s * 512 + f1];
    }
    a0 += bg[f0]; a1 += bg[f1];
    out[(size_t)d * 512 + f0] = (_Float16)fmaxf(a0, 0.f);
    out[(size_t)d * 512 + f1] = (_Float16)fmaxf(a1, 0.f);
}

// ---------------------------------------------------------------------------
extern "C" void kernel_launch(void* const* d_in, const int* in_sizes, int n_in,
                              void* d_out, int out_size, void* d_ws, size_t ws_size,
                              hipStream_t stream)
{
    const float* x      = (const float*)d_in[0];
    const float* boxes  = (const float*)d_in[1];
    const float* scales = (const float*)d_in[2];
    const float* pdls   = (const float*)d_in[3];
    const float* pdts   = (const float*)d_in[4];
    const float* W_dec  = (const float*)d_in[5];
    const float* b_dec  = (const float*)d_in[6];
    const float* W_box  = (const float*)d_in[7];
    const float* b_box  = (const float*)d_in[8];
    const float* W_cnn  = (const float*)d_in[9];
    const float* b_cnn  = (const float*)d_in[10];
    const float* W_grow = (const float*)d_in[11];
    const float* b_grow = (const float*)d_in[12];
    const float* W_gcol = (const float*)d_in[13];
    const float* b_gcol = (const float*)d_in[14];
    const float* W_rcls = (const float*)d_in[15];
    const float* b_rcls = (const float*)d_in[16];
    const float* W_ccls = (const float*)d_in[17];
    const float* b_ccls = (const float*)d_in[18];

    char* ws = (char*)d_ws;
    size_t off = 0;
    auto alloc = [&](size_t bytes) -> void* {
        void* p = ws + off;
        off = (off + bytes + 255) & ~(size_t)255;
        return p;
    };
    _Float16* xf16   = (_Float16*)alloc((size_t)4 * 2304 * 1024 * 2);  // NHWC in
    _Float16* wf16   = (_Float16*)alloc((size_t)256 * 9216 * 2);       // [o][tap][ch]
    _Float16* dec    = (_Float16*)alloc((size_t)4 * 2304 * 256 * 2);   // NHWC
    _Float16* cnn    = (_Float16*)alloc((size_t)2048 * 1024 * 2);
    _Float16* fusion = (_Float16*)alloc((size_t)2048 * 768 * 2);
    _Float16* WcT    = (_Float16*)alloc((size_t)512 * 1024 * 2);
    _Float16* WgrT   = (_Float16*)alloc((size_t)512 * 768 * 2);
    _Float16* WgcT   = (_Float16*)alloc((size_t)512 * 768 * 2);
    _Float16* WrT    = (_Float16*)alloc((size_t)228 * 512 * 2);
    _Float16* WccT   = (_Float16*)alloc((size_t)116 * 512 * 2);
    float* xw        = (float*)alloc((size_t)2097152 * 4);             // xw_row|xw_col
    _Float16* feats  = (_Float16*)alloc((size_t)2 * 2048 * 512 * 2);   // row|col
    u32*   cand  = (u32*)  alloc((size_t)16 * CAP * 4);
    float* cxA   = (float*)alloc((size_t)2048 * 4);
    float* cyA   = (float*)alloc((size_t)2048 * 4);
    float* tbA   = (float*)alloc((size_t)8 * 4);
    u32*  kstar  = (u32*)  alloc((size_t)8 * 4);
    int*  rstar  = (int*)  alloc((size_t)8 * 4);
    int*  tiebuf = (int*)  alloc((size_t)8 * TIECAP * 4);
    int*  tiecnt = (int*)  alloc((size_t)8 * 4);
    int*  es     = (int*)  alloc((size_t)2 * 16384 * 4);
    int*  ed     = (int*)  alloc((size_t)2 * 16384 * 4);
    float* ewt   = (float*)alloc((size_t)2 * 16384 * 4);
    int*  ecnt   = (int*)  alloc((size_t)64);
    int*  indeg  = (int*)  alloc((size_t)4096 * 4);
    float* degw  = (float*)alloc((size_t)4096 * 4);
    float* dis   = (float*)alloc((size_t)4096 * 4);
    int*  offsA  = (int*)  alloc((size_t)4096 * 4);
    int*  fillA  = (int*)  alloc((size_t)4096 * 4);
    int*  csr    = (int*)  alloc((size_t)2 * 16384 * 4);

    float* out = (float*)d_out;

    init_kernel<<<16, 256, 0, stream>>>(degw, indeg, fillA, ecnt, tiecnt);
    cvt_x_kernel<<<dim3(16, 48, 4), 256, 0, stream>>>(x, xf16);
    cvt_w_kernel<<<256, 256, 0, stream>>>(W_dec, wf16);
    conv_f16_kernel<<<dim3(12, 8, 4), 256, 0, stream>>>(xf16, wf16, b_dec, dec);
    roi_kernel<<<2048, 256, 0, stream>>>(dec, boxes, cnn);
    box_kernel<<<2048, 256, 0, stream>>>(boxes, W_box, b_box, fusion);
    // weight transposes (f16 [N][K])
    cvt_t_kernel<<<dim3(16, 32), 256, 0, stream>>>(W_cnn, WcT, 1024, 512);
    cvt_t_kernel<<<dim3(16, 24), 256, 0, stream>>>(W_grow, WgrT, 768, 512);
    cvt_t_kernel<<<dim3(16, 24), 256, 0, stream>>>(W_gcol, WgcT, 768, 512);
    cvt_t_kernel<<<dim3(8, 16), 256, 0, stream>>>(W_rcls, WrT, 512, 228);
    cvt_t_kernel<<<dim3(4, 16), 256, 0, stream>>>(W_ccls, WccT, 512, 116);
    // fusion[:,256:768] = relu(cnn @ W_cnn + b)
    gemm16_kernel<1, _Float16><<<dim3(8, 32), 256, 0, stream>>>(cnn, WcT, b_cnn, fusion + 256, 2048, 512, 1024, 768);
    // edge pipeline
    e0_kernel<<<4, 512, 0, stream>>>(boxes, scales, pdls, pdts, cxA, cyA, tbA);
    select_kernel<<<8, 1024, 0, stream>>>(cxA, cyA, tbA, cand, cand + (size_t)8 * CAP, kstar, rstar);
    e3_kernel<<<8176, 256, 0, stream>>>(cxA, cyA, tbA, kstar, tiebuf, tiecnt, es, ed, ewt, ecnt, indeg, degw);
    e3b_kernel<<<8, 256, 0, stream>>>(kstar, rstar, tiebuf, tiecnt, es, ed, ewt, ecnt, indeg, degw);
    e4_kernel<<<16, 256, 0, stream>>>(degw, dis);
    scan_kernel<<<2, 1024, 0, stream>>>(indeg, offsA);
    fill_kernel<<<128, 256, 0, stream>>>(ed, offsA, fillA, csr);
    // xw = fusion @ W_g{row,col} (bias applied in aggregation)
    gemm16_kernel<0, float><<<dim3(8, 32), 256, 0, stream>>>(fusion, WgrT, nullptr, xw, 2048, 512, 768, 512);
    gemm16_kernel<0, float><<<dim3(8, 32), 256, 0, stream>>>(fusion, WgcT, nullptr, xw + 1048576, 2048, 512, 768, 512);
    gcn_agg_kernel<<<dim3(2048, 2), 256, 0, stream>>>(xw, xw + 1048576, b_grow, b_gcol,
                                                      es, ewt, csr, offsA, indeg, dis,
                                                      feats, feats + (size_t)2048 * 512);
    // classifier heads (leaky 0.01) -> fp32 out
    gemm16_kernel<2, float><<<dim3(4, 32), 256, 0, stream>>>(feats, WrT, b_rcls, out, 2048, 228, 512, 228);
    gemm16_kernel<2, float><<<dim3(2, 32), 256, 0, stream>>>(feats + (size_t)2048 * 512, WccT, b_ccls,
                                                             out + (size_t)2048 * 228, 2048, 116, 512, 116);
}

// Round 6
// 844.006 us; speedup vs baseline: 4.6362x; 1.3251x over previous
//
#include <hip/hip_runtime.h>
#include <cstdint>
#include <math.h>

typedef unsigned int u32;
typedef unsigned long long u64;
typedef unsigned short ushort;

typedef __attribute__((ext_vector_type(8))) _Float16 f16x8;
typedef __attribute__((ext_vector_type(4))) _Float16 f16x4;
typedef __attribute__((ext_vector_type(4))) float f32x4;

#define NB    4
#define NPB   512
#define BnN   2048
#define CIN   1024
#define ODEC  256
#define NE    261632      // 512*511 ordered pairs per batch
#define KEDGE 4096
#define CAP   65536
#define TIECAP 2048

// ---------------------------------------------------------------------------
// convert input: NCHW fp32 -> NHWC f16.  grid (16 chgrp, 48 y, 4 b), block 256
// ---------------------------------------------------------------------------
__global__ __launch_bounds__(256) void cvt_x_kernel(
    const float* __restrict__ in, _Float16* __restrict__ xf)
{
    __shared__ _Float16 sh[64][49];
    int cg = blockIdx.x, y = blockIdx.y, b = blockIdx.z;
    int tid = threadIdx.x;
    for (int i = tid; i < 64 * 48; i += 256) {
        int cl = i / 48, x = i - cl * 48;
        sh[cl][x] = (_Float16)in[(((size_t)b * 1024 + cg * 64 + cl) * 48 + y) * 48 + x];
    }
    __syncthreads();
    for (int i = tid; i < 64 * 48; i += 256) {
        int x = i / 64, cl = i - x * 64;
        xf[((size_t)(b * 48 + y) * 48 + x) * 1024 + cg * 64 + cl] = sh[cl][x];
    }
}

// convert weights: [o][ch][3][3] fp32 -> [o][tap][ch] f16. grid 256, block 256
__global__ __launch_bounds__(256) void cvt_w_kernel(
    const float* __restrict__ W, _Float16* __restrict__ wf)
{
    __shared__ _Float16 sh[9216];
    int o = blockIdx.x, tid = threadIdx.x;
    for (int g = tid; g < 9216; g += 256)
        sh[g] = (_Float16)W[(size_t)o * 9216 + g];     // g = ch*9+tap
    __syncthreads();
    for (int g = tid; g < 9216; g += 256) {
        int tap = g >> 10, ch = g & 1023;
        wf[(size_t)o * 9216 + g] = sh[ch * 9 + tap];
    }
}

// transpose-convert: in fp32 [K][N] -> out f16 [N][K]. grid (ceil(N/32), ceil(K/32))
__global__ __launch_bounds__(256) void cvt_t_kernel(
    const float* __restrict__ in, _Float16* __restrict__ out, int K, int N)
{
    __shared__ _Float16 sh[32][33];
    int n0 = blockIdx.x * 32, k0 = blockIdx.y * 32;
    int tx = threadIdx.x & 31, ty = threadIdx.x >> 5;
#pragma unroll
    for (int i = 0; i < 4; ++i) {
        int k = k0 + ty + i * 8, n = n0 + tx;
        sh[ty + i * 8][tx] = (k < K && n < N) ? (_Float16)in[(size_t)k * N + n] : (_Float16)0.f;
    }
    __syncthreads();
#pragma unroll
    for (int i = 0; i < 4; ++i) {
        int n = n0 + ty + i * 8, k = k0 + tx;
        if (n < N && k < K) out[(size_t)n * K + k] = sh[tx][ty + i * 8];
    }
}

// ---------------------------------------------------------------------------
// conv 3x3 SAME 1024->256 +bias +relu. Implicit-GEMM MFMA f16 (fp32 acc).
// Block 256 thr (4 waves): 32 och x 4 rows (192 px), wave = 1 row.
// grid (12 ygroup, 8 og, 4 b). K-chunks of 32 ch, all 9 taps staged.
// ---------------------------------------------------------------------------
__global__ __launch_bounds__(256) void conv_f16_kernel(
    const _Float16* __restrict__ xf, const _Float16* __restrict__ wf,
    const float* __restrict__ bd, _Float16* __restrict__ dec)
{
    __shared__ _Float16 wS[9][4][32][8];   // 18.4 KB  [tap][q][och][8ch]
    __shared__ _Float16 xS[6][4][50][8];   // 19.2 KB  [row][q][col][8ch]
    const int y0 = blockIdx.x * 4;
    const int og = blockIdx.y;
    const int b  = blockIdx.z;
    const int tid = threadIdx.x;
    const int wv = tid >> 6;
    const int ln = tid & 63;
    const int n  = ln & 15;
    const int q  = ln >> 4;

    f32x4 acc[2][3];
#pragma unroll
    for (int mt = 0; mt < 2; ++mt)
#pragma unroll
        for (int nt = 0; nt < 3; ++nt) acc[mt][nt] = (f32x4){0.f, 0.f, 0.f, 0.f};

    for (int cc = 0; cc < 1024; cc += 32) {
#pragma unroll
        for (int it = 0; it < 5; ++it) {
            int g = it * 256 + tid;
            if (g < 1152) {
                int tap = g >> 7, r = g & 127, qq = r >> 5, oc = r & 31;
                *(uint4*)&wS[tap][qq][oc][0] =
                    *(const uint4*)(wf + ((size_t)(og * 32 + oc) * 9 + tap) * 1024 + cc + qq * 8);
            }
        }
#pragma unroll
        for (int it = 0; it < 5; ++it) {
            int g = it * 256 + tid;
            if (g < 1200) {
                int row = g / 200, r2 = g - row * 200;
                int qq = r2 / 50, c = r2 - qq * 50;
                int gy = y0 + row - 1, gx = c - 1;
                uint4 v = make_uint4(0u, 0u, 0u, 0u);
                if ((unsigned)gy < 48u && (unsigned)gx < 48u)
                    v = *(const uint4*)(xf + ((size_t)(b * 48 + gy) * 48 + gx) * 1024 + cc + qq * 8);
                *(uint4*)&xS[row][qq][c][0] = v;
            }
        }
        __syncthreads();

#pragma unroll
        for (int tap = 0; tap < 9; ++tap) {
            const int dy = tap / 3, dx = tap % 3;
            f16x8 a0 = *(const f16x8*)&wS[tap][q][n][0];
            f16x8 a1 = *(const f16x8*)&wS[tap][q][16 + n][0];
#pragma unroll
            for (int nt = 0; nt < 3; ++nt) {
                f16x8 bb = *(const f16x8*)&xS[wv + dy][q][nt * 16 + n + dx][0];
                acc[0][nt] = __builtin_amdgcn_mfma_f32_16x16x32_f16(a0, bb, acc[0][nt], 0, 0, 0);
                acc[1][nt] = __builtin_amdgcn_mfma_f32_16x16x32_f16(a1, bb, acc[1][nt], 0, 0, 0);
            }
        }
        __syncthreads();
    }

    const int y = y0 + wv;
#pragma unroll
    for (int mt = 0; mt < 2; ++mt) {
        float4 b4 = *(const float4*)(bd + og * 32 + mt * 16 + q * 4);
#pragma unroll
        for (int nt = 0; nt < 3; ++nt) {
            int x = nt * 16 + n;
            f16x4 v;
            v.x = (_Float16)fmaxf(acc[mt][nt][0] + b4.x, 0.f);
            v.y = (_Float16)fmaxf(acc[mt][nt][1] + b4.y, 0.f);
            v.z = (_Float16)fmaxf(acc[mt][nt][2] + b4.z, 0.f);
            v.w = (_Float16)fmaxf(acc[mt][nt][3] + b4.w, 0.f);
            *(f16x4*)(dec + ((size_t)(b * 48 + y) * 48 + x) * 256 + og * 32 + mt * 16 + q * 4) = v;
        }
    }
}

// ---------------------------------------------------------------------------
// ROI align 2x2 on NHWC f16 dec: one block per box, thread = channel.
// ---------------------------------------------------------------------------
__global__ __launch_bounds__(256) void roi_kernel(
    const _Float16* __restrict__ dec, const float* __restrict__ boxes,
    _Float16* __restrict__ cnn)
{
    int n = blockIdx.x; int c = threadIdx.x;
    int b = n >> 9;
    float x1 = boxes[n * 4 + 0], y1 = boxes[n * 4 + 1];
    float x2 = boxes[n * 4 + 2], y2 = boxes[n * 4 + 3];
    float bw = (x2 - x1) * 0.5f, bh = (y2 - y1) * 0.5f;
    float sxv[2] = { x1 + 0.5f * bw, x1 + 1.5f * bw };
    float syv[2] = { y1 + 0.5f * bh, y1 + 1.5f * bh };
    float px[4] = { sxv[0], sxv[1], sxv[0], sxv[1] };
    float py[4] = { syv[0], syv[0], syv[1], syv[1] };
    const _Float16* f = dec + (size_t)b * 2304 * 256;
    f16x4 o4;
    float res[4];
#pragma unroll
    for (int p = 0; p < 4; ++p) {
        float yy = fminf(fmaxf(py[p], 0.f), 47.f);
        float xx = fminf(fmaxf(px[p], 0.f), 47.f);
        int y0 = (int)floorf(yy), x0 = (int)floorf(xx);
        int y1i = min(y0 + 1, 47), x1i = min(x0 + 1, 47);
        float wy = yy - (float)y0, wx = xx - (float)x0;
        float f00 = (float)f[(size_t)(y0 * 48 + x0) * 256 + c];
        float f01 = (float)f[(size_t)(y0 * 48 + x1i) * 256 + c];
        float f10 = (float)f[(size_t)(y1i * 48 + x0) * 256 + c];
        float f11 = (float)f[(size_t)(y1i * 48 + x1i) * 256 + c];
        res[p] = f00 * (1.f - wy) * (1.f - wx) + f01 * (1.f - wy) * wx
               + f10 * wy * (1.f - wx) + f11 * wy * wx;
    }
    o4.x = (_Float16)res[0]; o4.y = (_Float16)res[1];
    o4.z = (_Float16)res[2]; o4.w = (_Float16)res[3];
    *(f16x4*)(cnn + (size_t)n * 1024 + c * 4) = o4;
}

// ---------------------------------------------------------------------------
// box head: fusion[:, 0:256] = relu(bf @ W_box + b_box)
// ---------------------------------------------------------------------------
__global__ __launch_bounds__(256) void box_kernel(
    const float* __restrict__ boxes, const float* __restrict__ Wb,
    const float* __restrict__ bb, _Float16* __restrict__ fusion)
{
    int nrow = blockIdx.x, c = threadIdx.x;
    float x1 = boxes[nrow * 4 + 0], y1 = boxes[nrow * 4 + 1];
    float x2 = boxes[nrow * 4 + 2], y2 = boxes[nrow * 4 + 3];
    float bf0 = ((x1 + x2) * 0.5f) / 48.f;
    float bf1 = ((y1 + y2) * 0.5f) / 48.f;
    float bf2 = (x2 - x1) / 48.f;
    float bf3 = (y2 - y1) / 48.f;
    float acc = bb[c];
    acc += bf0 * Wb[0 * 256 + c];
    acc += bf1 * Wb[1 * 256 + c];
    acc += bf2 * Wb[2 * 256 + c];
    acc += bf3 * Wb[3 * 256 + c];
    fusion[(size_t)nrow * 768 + c] = (_Float16)fmaxf(acc, 0.f);
}

// ---------------------------------------------------------------------------
// f16 MFMA GEMM: C = act(A @ Bt^T + bias). 64x64 tile, 4 waves 2x2.
// ---------------------------------------------------------------------------
template <int ACT, typename OUTT>
__global__ __launch_bounds__(256) void gemm16_kernel(
    const _Float16* __restrict__ A, const _Float16* __restrict__ Bt,
    const float* __restrict__ bias, OUTT* __restrict__ C,
    int M, int N, int K, int ldC)
{
    __shared__ _Float16 aS[64][4][8];
    __shared__ _Float16 bS[64][4][8];
    const int n0 = blockIdx.x * 64, m0 = blockIdx.y * 64;
    const int tid = threadIdx.x;
    const int wv = tid >> 6, ln = tid & 63;
    const int wm = wv & 1, wn = wv >> 1;
    const int lm = ln & 15, lq = ln >> 4;
    const int sr = tid >> 2, sq = tid & 3;

    f32x4 acc[2][2];
#pragma unroll
    for (int i = 0; i < 2; ++i)
#pragma unroll
        for (int j = 0; j < 2; ++j) acc[i][j] = (f32x4){0.f, 0.f, 0.f, 0.f};

    for (int cc = 0; cc < K; cc += 32) {
        *(uint4*)&aS[sr][sq][0] = *(const uint4*)(A + (size_t)(m0 + sr) * K + cc + sq * 8);
        uint4 bv = make_uint4(0u, 0u, 0u, 0u);
        if (n0 + sr < N)
            bv = *(const uint4*)(Bt + (size_t)(n0 + sr) * K + cc + sq * 8);
        *(uint4*)&bS[sr][sq][0] = bv;
        __syncthreads();
        f16x8 af[2], bf[2];
#pragma unroll
        for (int mt = 0; mt < 2; ++mt) af[mt] = *(const f16x8*)&aS[wm * 32 + mt * 16 + lm][lq][0];
#pragma unroll
        for (int nt = 0; nt < 2; ++nt) bf[nt] = *(const f16x8*)&bS[wn * 32 + nt * 16 + lm][lq][0];
#pragma unroll
        for (int mt = 0; mt < 2; ++mt)
#pragma unroll
            for (int nt = 0; nt < 2; ++nt)
                acc[mt][nt] = __builtin_amdgcn_mfma_f32_16x16x32_f16(af[mt], bf[nt], acc[mt][nt], 0, 0, 0);
        __syncthreads();
    }

#pragma unroll
    for (int mt = 0; mt < 2; ++mt) {
#pragma unroll
        for (int nt = 0; nt < 2; ++nt) {
            int col = n0 + wn * 32 + nt * 16 + lm;
            if (col >= N) continue;
            float bs = bias ? bias[col] : 0.f;
#pragma unroll
            for (int r = 0; r < 4; ++r) {
                int row = m0 + wm * 32 + mt * 16 + lq * 4 + r;
                float v = acc[mt][nt][r] + bs;
                if (ACT == 1) v = fmaxf(v, 0.f);
                if (ACT == 2) v = (v >= 0.f) ? v : 0.01f * v;
                C[(size_t)row * ldC + col] = (OUTT)v;
            }
        }
    }
}

// ---------------------------------------------------------------------------
// E0: per-batch centers + table extents (fp32, exact ref op order)
// ---------------------------------------------------------------------------
__global__ __launch_bounds__(512) void e0_kernel(
    const float* __restrict__ boxes, const float* __restrict__ scales,
    const float* __restrict__ pdls, const float* __restrict__ pdts,
    float* __restrict__ cxA, float* __restrict__ cyA, float* __restrict__ tb)
{
    __shared__ float sw[512], sh[512];
    int b = blockIdx.x, n = threadIdx.x;
    float pdl = pdls[b], pdt = pdts[b], sc = scales[b];
    const float* bx = boxes + (size_t)(b * 512 + n) * 4;
    float o0 = (bx[0] - pdl) / sc;
    float o1 = (bx[1] - pdt) / sc;
    float o2 = (bx[2] - pdl) / sc;
    float o3 = (bx[3] - pdt) / sc;
    cxA[b * 512 + n] = (o0 + o2) * 0.5f;
    cyA[b * 512 + n] = (o1 + o3) * 0.5f;
    sw[n] = fmaxf(o0, o2); sh[n] = fmaxf(o1, o3);
    __syncthreads();
    for (int s = 256; s > 0; s >>= 1) {
        if (n < s) { sw[n] = fmaxf(sw[n], sw[n + s]); sh[n] = fmaxf(sh[n], sh[n + s]); }
        __syncthreads();
    }
    if (n == 0) { tb[b * 2 + 0] = sw[0]; tb[b * 2 + 1] = sh[0]; }
}

// ---------------------------------------------------------------------------
// Fused selection + emission + CSR build.  One block per sel=(b,t).
// Key = ~bits(f32(exp64(-q32))) ascending == attr descending; ties by index.
// After radix select: emit key<k* edges + first r* ties into the block's
// private region [t*16384 + b*4096 .. +4096), accumulate indeg/degw in LDS
// (each (t,node) owned by exactly one block -> NO global atomics), then
// dis = 1/sqrt(degw), 512-wide scan -> CSR offsets, local CSR fill.
// ---------------------------------------------------------------------------
__global__ __launch_bounds__(1024) void select_emit_kernel(
    const float* __restrict__ cxA, const float* __restrict__ cyA,
    const float* __restrict__ tb,
    u32* __restrict__ candA, u32* __restrict__ candB,
    int* __restrict__ es, int* __restrict__ ed, float* __restrict__ ewt,
    int* __restrict__ indeg_g, float* __restrict__ dis_g,
    int* __restrict__ offs_g, int* __restrict__ csr_g)
{
    const int sel = blockIdx.x;
    const int b = sel >> 1, t = sel & 1;
    const int tid = threadIdx.x;
    const int wv = tid >> 6;
    __shared__ float sv[512];
    __shared__ u32 h[16][256];
    __shared__ u32 tot[256];
    __shared__ int s_digit, s_need, s_cnt;
    __shared__ float s_tb;
    __shared__ int tiebuf[TIECAP];
    __shared__ int tiecnt, emitcnt;
    __shared__ int ideg[512];
    __shared__ float dgw[512];
    __shared__ int offs_l[512];
    __shared__ int fill_l[512];
    __shared__ int sA[512], sB[512];

    if (tid < 512) sv[tid] = (t == 0) ? cyA[b * 512 + tid] : cxA[b * 512 + tid];
    if (tid < 512) { ideg[tid] = 0; dgw[tid] = 1.0f; fill_l[tid] = 0; }
    if (tid == 0) { s_tb = tb[b * 2 + (t == 0 ? 1 : 0)]; tiecnt = 0; emitcnt = 0; }
    __syncthreads();
    const float tbv = s_tb;
    int need = KEDGE;
    u32 prefix = 0;

    // helper lambda-free key computation macro
#define KEYOF(e, KB, WV_)                                              \
    {                                                                  \
        int i_ = (e) / 511; int jj_ = (e) - i_ * 511;                  \
        int j_ = jj_ + (jj_ >= i_ ? 1 : 0);                            \
        float diff_ = sv[i_] - sv[j_];                                 \
        float u_ = (diff_ * 5.0f) / tbv;                               \
        float q_ = u_ * u_;                                            \
        WV_ = (float)exp(-(double)q_);                                 \
        KB = ~__float_as_uint(WV_);                                    \
    }

    // ---- byte 3 (full array) ----
    for (int x = tid; x < 16 * 256; x += 1024) ((u32*)h)[x] = 0;
    __syncthreads();
    for (int e = tid; e < NE; e += 1024) {
        u32 kb2; float wdummy; KEYOF(e, kb2, wdummy);
        atomicAdd(&h[wv][(int)(kb2 >> 24)], 1u);
    }
    __syncthreads();
    if (tid < 256) { u32 s = 0; for (int w = 0; w < 16; ++w) s += h[w][tid]; tot[tid] = s; }
    __syncthreads();
    if (tid == 0) {
        u32 cum = 0; int d = 255;
        for (int bb = 0; bb < 256; ++bb) { if (cum + tot[bb] >= (u32)need) { d = bb; break; } cum += tot[bb]; }
        s_digit = d; s_need = need - (int)cum;
    }
    __syncthreads();
    prefix |= ((u32)s_digit) << 24; need = s_need;
    __syncthreads();

    // ---- byte 2 (full array, filtered) ----
    for (int x = tid; x < 16 * 256; x += 1024) ((u32*)h)[x] = 0;
    __syncthreads();
    for (int e = tid; e < NE; e += 1024) {
        u32 kb2; float wdummy; KEYOF(e, kb2, wdummy);
        if ((kb2 >> 24) == (prefix >> 24)) atomicAdd(&h[wv][(int)((kb2 >> 16) & 0xFF)], 1u);
    }
    __syncthreads();
    if (tid < 256) { u32 s = 0; for (int w = 0; w < 16; ++w) s += h[w][tid]; tot[tid] = s; }
    __syncthreads();
    if (tid == 0) {
        u32 cum = 0; int d = 255;
        for (int bb = 0; bb < 256; ++bb) { if (cum + tot[bb] >= (u32)need) { d = bb; break; } cum += tot[bb]; }
        s_digit = d; s_need = need - (int)cum;
    }
    __syncthreads();
    prefix |= ((u32)s_digit) << 16; need = s_need;
    if (tid == 0) s_cnt = 0;
    __syncthreads();

    // ---- compact top-16-bit matches ----
    u32* cA = candA + (size_t)sel * CAP;
    u32* cB = candB + (size_t)sel * CAP;
    for (int e = tid; e < NE; e += 1024) {
        u32 kb2; float wdummy; KEYOF(e, kb2, wdummy);
        if ((kb2 >> 16) == (prefix >> 16)) {
            int pos = atomicAdd(&s_cnt, 1);
            if (pos < CAP) cA[pos] = kb2;
        }
    }
    __syncthreads();
    int C = min(s_cnt, CAP);
    u32* cur = cA; u32* nxt = cB;

    // ---- bytes 1..0 over candidates ----
    for (int shift = 8; shift >= 0; shift -= 8) {
        __syncthreads();
        for (int x = tid; x < 16 * 256; x += 1024) ((u32*)h)[x] = 0;
        __syncthreads();
        for (int k = tid; k < C; k += 1024)
            atomicAdd(&h[wv][(int)((cur[k] >> shift) & 0xFF)], 1u);
        __syncthreads();
        if (tid < 256) { u32 s = 0; for (int w = 0; w < 16; ++w) s += h[w][tid]; tot[tid] = s; }
        __syncthreads();
        if (tid == 0) {
            u32 cum = 0; int d = 255;
            for (int bb = 0; bb < 256; ++bb) { if (cum + tot[bb] >= (u32)need) { d = bb; break; } cum += tot[bb]; }
            s_digit = d; s_need = need - (int)cum;
            s_cnt = 0;
        }
        __syncthreads();
        int dig = s_digit;
        prefix |= ((u32)dig) << shift; need = s_need;
        for (int k = tid; k < C; k += 1024) {
            u32 kb2 = cur[k];
            if ((int)((kb2 >> shift) & 0xFF) == dig) {
                int pos = atomicAdd(&s_cnt, 1);
                if (pos < CAP) nxt[pos] = kb2;
            }
        }
        __syncthreads();
        C = min(s_cnt, CAP);
        u32* tmp = cur; cur = nxt; nxt = tmp;
    }
    // prefix = k*, need = r* (ties to take, index-ascending)

    // ---- emission pass (LDS counter, private region -> no contention) ----
    const int base = t * 16384 + b * 4096;
    for (int e = tid; e < NE; e += 1024) {
        u32 kb2; float wval; KEYOF(e, kb2, wval);
        if (kb2 < prefix) {
            int i = e / 511; int jj = e - i * 511; int j = jj + (jj >= i ? 1 : 0);
            int slot = atomicAdd(&emitcnt, 1);
            es[base + slot] = b * 512 + i;
            ed[base + slot] = b * 512 + j;
            ewt[base + slot] = wval;
            atomicAdd(&ideg[j], 1);
            atomicAdd(&dgw[j], wval);
        } else if (kb2 == prefix) {
            int p = atomicAdd(&tiecnt, 1);
            if (p < TIECAP) tiebuf[p] = e;
        }
    }
    __syncthreads();

    // ---- tie resolution: smallest pair-index first (lax.top_k) ----
    {
        int m = min(tiecnt, TIECAP);
        int r = need;
        float wt = __uint_as_float(~prefix);
        for (int k = tid; k < m; k += 1024) {
            int e = tiebuf[k];
            int rank = 0;
            for (int l = 0; l < m; ++l) rank += (tiebuf[l] < e) ? 1 : 0;
            if (rank < r) {
                int i = e / 511; int jj = e - i * 511; int j = jj + (jj >= i ? 1 : 0);
                int slot = atomicAdd(&emitcnt, 1);
                es[base + slot] = b * 512 + i;
                ed[base + slot] = b * 512 + j;
                ewt[base + slot] = wt;
                atomicAdd(&ideg[j], 1);
                atomicAdd(&dgw[j], wt);
            }
        }
    }
    __syncthreads();

    // ---- scan indeg -> offs_l (exclusive) ----
    if (tid < 512) sA[tid] = ideg[tid];
    __syncthreads();
    {
        int* src = sA; int* dst = sB;
        for (int st = 1; st < 512; st <<= 1) {
            if (tid < 512) dst[tid] = src[tid] + (tid >= st ? src[tid - st] : 0);
            __syncthreads();
            int* tmp = src; src = dst; dst = tmp;
        }
        if (tid < 512) offs_l[tid] = (tid == 0) ? 0 : src[tid - 1];
    }
    __syncthreads();

    // ---- CSR fill (local) ----
    for (int s = tid; s < 4096; s += 1024) {
        int dl = ed[base + s] & 511;
        int pos = offs_l[dl] + atomicAdd(&fill_l[dl], 1);
        csr_g[base + pos] = b * 4096 + s;     // edge id within [t][16384]
    }
    // ---- per-node globals ----
    if (tid < 512) {
        int gd = t * 2048 + b * 512 + tid;
        indeg_g[gd] = ideg[tid];
        offs_g[gd] = b * 4096 + offs_l[tid];
        dis_g[gd] = 1.0f / sqrtf(dgw[tid]);
    }
#undef KEYOF
}

// E7: GCN aggregate -> feats f16
__global__ __launch_bounds__(256) void gcn_agg_kernel(
    const float* __restrict__ xw_row, const float* __restrict__ xw_col,
    const float* __restrict__ b_row, const float* __restrict__ b_col,
    const int* __restrict__ es, const float* __restrict__ ew,
    const int* __restrict__ csr, const int* __restrict__ offs,
    const int* __restrict__ indeg, const float* __restrict__ dis,
    _Float16* __restrict__ feat_row, _Float16* __restrict__ feat_col)
{
    int d = blockIdx.x; int t = blockIdx.y;
    const float* xw = t ? xw_col : xw_row;
    const float* bg = t ? b_col : b_row;
    _Float16* out = t ? feat_col : feat_row;
    int f0 = threadIdx.x, f1 = threadIdx.x + 256;
    float dd = dis[t * 2048 + d];
    float a0 = dd * dd * xw[(size_t)d * 512 + f0];
    float a1 = dd * dd * xw[(size_t)d * 512 + f1];
    int st = offs[t * 2048 + d], cnt = indeg[t * 2048 + d];
    for (int k = 0; k < cnt; ++k) {
        int e = csr[t * 16384 + st + k];
        int s = es[t * 16384 + e];
        float w = ew[t * 16384 + e];
        float coef = dis[t * 2048 + s] * w * dd;
        a0 += coef * xw[(size_t)s * 512 + f0];
        a1 += coef * xw[(size_t)s * 512 + f1];
    }
    a0 += bg[f0]; a1 += bg[f1];
    out[(size_t)d * 512 + f0] = (_Float16)fmaxf(a0, 0.f);
    out[(size_t)d * 512 + f1] = (_Float16)fmaxf(a1, 0.f);
}

// ---------------------------------------------------------------------------
extern "C" void kernel_launch(void* const* d_in, const int* in_sizes, int n_in,
                              void* d_out, int out_size, void* d_ws, size_t ws_size,
                              hipStream_t stream)
{
    const float* x      = (const float*)d_in[0];
    const float* boxes  = (const float*)d_in[1];
    const float* scales = (const float*)d_in[2];
    const float* pdls   = (const float*)d_in[3];
    const float* pdts   = (const float*)d_in[4];
    const float* W_dec  = (const float*)d_in[5];
    const float* b_dec  = (const float*)d_in[6];
    const float* W_box  = (const float*)d_in[7];
    const float* b_box  = (const float*)d_in[8];
    const float* W_cnn  = (const float*)d_in[9];
    const float* b_cnn  = (const float*)d_in[10];
    const float* W_grow = (const float*)d_in[11];
    const float* b_grow = (const float*)d_in[12];
    const float* W_gcol = (const float*)d_in[13];
    const float* b_gcol = (const float*)d_in[14];
    const float* W_rcls = (const float*)d_in[15];
    const float* b_rcls = (const float*)d_in[16];
    const float* W_ccls = (const float*)d_in[17];
    const float* b_ccls = (const float*)d_in[18];

    char* ws = (char*)d_ws;
    size_t off = 0;
    auto alloc = [&](size_t bytes) -> void* {
        void* p = ws + off;
        off = (off + bytes + 255) & ~(size_t)255;
        return p;
    };
    _Float16* xf16   = (_Float16*)alloc((size_t)4 * 2304 * 1024 * 2);  // NHWC in
    _Float16* wf16   = (_Float16*)alloc((size_t)256 * 9216 * 2);       // [o][tap][ch]
    _Float16* dec    = (_Float16*)alloc((size_t)4 * 2304 * 256 * 2);   // NHWC
    _Float16* cnn    = (_Float16*)alloc((size_t)2048 * 1024 * 2);
    _Float16* fusion = (_Float16*)alloc((size_t)2048 * 768 * 2);
    _Float16* WcT    = (_Float16*)alloc((size_t)512 * 1024 * 2);
    _Float16* WgrT   = (_Float16*)alloc((size_t)512 * 768 * 2);
    _Float16* WgcT   = (_Float16*)alloc((size_t)512 * 768 * 2);
    _Float16* WrT    = (_Float16*)alloc((size_t)228 * 512 * 2);
    _Float16* WccT   = (_Float16*)alloc((size_t)116 * 512 * 2);
    float* xw        = (float*)alloc((size_t)2097152 * 4);             // xw_row|xw_col
    _Float16* feats  = (_Float16*)alloc((size_t)2 * 2048 * 512 * 2);   // row|col
    u32*   cand  = (u32*)  alloc((size_t)16 * CAP * 4);
    float* cxA   = (float*)alloc((size_t)2048 * 4);
    float* cyA   = (float*)alloc((size_t)2048 * 4);
    float* tbA   = (float*)alloc((size_t)8 * 4);
    int*  es     = (int*)  alloc((size_t)2 * 16384 * 4);
    int*  ed     = (int*)  alloc((size_t)2 * 16384 * 4);
    float* ewt   = (float*)alloc((size_t)2 * 16384 * 4);
    int*  indeg  = (int*)  alloc((size_t)4096 * 4);
    float* dis   = (float*)alloc((size_t)4096 * 4);
    int*  offsA  = (int*)  alloc((size_t)4096 * 4);
    int*  csr    = (int*)  alloc((size_t)2 * 16384 * 4);

    float* out = (float*)d_out;

    cvt_x_kernel<<<dim3(16, 48, 4), 256, 0, stream>>>(x, xf16);
    cvt_w_kernel<<<256, 256, 0, stream>>>(W_dec, wf16);
    conv_f16_kernel<<<dim3(12, 8, 4), 256, 0, stream>>>(xf16, wf16, b_dec, dec);
    roi_kernel<<<2048, 256, 0, stream>>>(dec, boxes, cnn);
    box_kernel<<<2048, 256, 0, stream>>>(boxes, W_box, b_box, fusion);
    // weight transposes (f16 [N][K])
    cvt_t_kernel<<<dim3(16, 32), 256, 0, stream>>>(W_cnn, WcT, 1024, 512);
    cvt_t_kernel<<<dim3(16, 24), 256, 0, stream>>>(W_grow, WgrT, 768, 512);
    cvt_t_kernel<<<dim3(16, 24), 256, 0, stream>>>(W_gcol, WgcT, 768, 512);
    cvt_t_kernel<<<dim3(8, 16), 256, 0, stream>>>(W_rcls, WrT, 512, 228);
    cvt_t_kernel<<<dim3(4, 16), 256, 0, stream>>>(W_ccls, WccT, 512, 116);
    // fusion[:,256:768] = relu(cnn @ W_cnn + b)
    gemm16_kernel<1, _Float16><<<dim3(8, 32), 256, 0, stream>>>(cnn, WcT, b_cnn, fusion + 256, 2048, 512, 1024, 768);
    // edge pipeline: fused select + emit + CSR
    e0_kernel<<<4, 512, 0, stream>>>(boxes, scales, pdls, pdts, cxA, cyA, tbA);
    select_emit_kernel<<<8, 1024, 0, stream>>>(cxA, cyA, tbA, cand, cand + (size_t)8 * CAP,
                                               es, ed, ewt, indeg, dis, offsA, csr);
    // xw = fusion @ W_g{row,col} (bias applied in aggregation)
    gemm16_kernel<0, float><<<dim3(8, 32), 256, 0, stream>>>(fusion, WgrT, nullptr, xw, 2048, 512, 768, 512);
    gemm16_kernel<0, float><<<dim3(8, 32), 256, 0, stream>>>(fusion, WgcT, nullptr, xw + 1048576, 2048, 512, 768, 512);
    gcn_agg_kernel<<<dim3(2048, 2), 256, 0, stream>>>(xw, xw + 1048576, b_grow, b_gcol,
                                                      es, ewt, csr, offsA, indeg, dis,
                                                      feats, feats + (size_t)2048 * 512);
    // classifier heads (leaky 0.01) -> fp32 out
    gemm16_kernel<2, float><<<dim3(4, 32), 256, 0, stream>>>(feats, WrT, b_rcls, out, 2048, 228, 512, 228);
    gemm16_kernel<2, float><<<dim3(2, 32), 256, 0, stream>>>(feats + (size_t)2048 * 512, WccT, b_ccls,
                                                             out + (size_t)2048 * 228, 2048, 116, 512, 116);
}

// Round 7
// 774.633 us; speedup vs baseline: 5.0514x; 1.0896x over previous
//
#include <hip/hip_runtime.h>
#include <cstdint>
#include <math.h>

typedef unsigned int u32;
typedef unsigned long long u64;
typedef unsigned short ushort;

typedef __attribute__((ext_vector_type(8))) _Float16 f16x8;
typedef __attribute__((ext_vector_type(4))) _Float16 f16x4;
typedef __attribute__((ext_vector_type(4))) float f32x4;

#define NB    4
#define NPB   512
#define BnN   2048
#define CIN   1024
#define ODEC  256
#define NE    261632      // 512*511 ordered pairs per batch
#define KEDGE 4096
#define TIECAP 2048

// ---------------------------------------------------------------------------
// convert input: NCHW fp32 -> NHWC f16.  grid (16 chgrp, 48 y, 4 b), block 256
// ---------------------------------------------------------------------------
__global__ __launch_bounds__(256) void cvt_x_kernel(
    const float* __restrict__ in, _Float16* __restrict__ xf)
{
    __shared__ _Float16 sh[64][49];
    int cg = blockIdx.x, y = blockIdx.y, b = blockIdx.z;
    int tid = threadIdx.x;
    for (int i = tid; i < 64 * 48; i += 256) {
        int cl = i / 48, x = i - cl * 48;
        sh[cl][x] = (_Float16)in[(((size_t)b * 1024 + cg * 64 + cl) * 48 + y) * 48 + x];
    }
    __syncthreads();
    for (int i = tid; i < 64 * 48; i += 256) {
        int x = i / 64, cl = i - x * 64;
        xf[((size_t)(b * 48 + y) * 48 + x) * 1024 + cg * 64 + cl] = sh[cl][x];
    }
}

// convert weights: [o][ch][3][3] fp32 -> [o][tap][ch] f16. grid 256, block 256
__global__ __launch_bounds__(256) void cvt_w_kernel(
    const float* __restrict__ W, _Float16* __restrict__ wf)
{
    __shared__ _Float16 sh[9216];
    int o = blockIdx.x, tid = threadIdx.x;
    for (int g = tid; g < 9216; g += 256)
        sh[g] = (_Float16)W[(size_t)o * 9216 + g];     // g = ch*9+tap
    __syncthreads();
    for (int g = tid; g < 9216; g += 256) {
        int tap = g >> 10, ch = g & 1023;
        wf[(size_t)o * 9216 + g] = sh[ch * 9 + tap];
    }
}

// transpose-convert: in fp32 [K][N] -> out f16 [N][K]. grid (ceil(N/32), ceil(K/32))
__global__ __launch_bounds__(256) void cvt_t_kernel(
    const float* __restrict__ in, _Float16* __restrict__ out, int K, int N)
{
    __shared__ _Float16 sh[32][33];
    int n0 = blockIdx.x * 32, k0 = blockIdx.y * 32;
    int tx = threadIdx.x & 31, ty = threadIdx.x >> 5;
#pragma unroll
    for (int i = 0; i < 4; ++i) {
        int k = k0 + ty + i * 8, n = n0 + tx;
        sh[ty + i * 8][tx] = (k < K && n < N) ? (_Float16)in[(size_t)k * N + n] : (_Float16)0.f;
    }
    __syncthreads();
#pragma unroll
    for (int i = 0; i < 4; ++i) {
        int n = n0 + ty + i * 8, k = k0 + tx;
        if (n < N && k < K) out[(size_t)n * K + k] = sh[tx][ty + i * 8];
    }
}

// ---------------------------------------------------------------------------
// conv 3x3 SAME 1024->256 +bias +relu. Implicit-GEMM MFMA f16 (fp32 acc).
// ---------------------------------------------------------------------------
__global__ __launch_bounds__(256) void conv_f16_kernel(
    const _Float16* __restrict__ xf, const _Float16* __restrict__ wf,
    const float* __restrict__ bd, _Float16* __restrict__ dec)
{
    __shared__ _Float16 wS[9][4][32][8];   // 18.4 KB  [tap][q][och][8ch]
    __shared__ _Float16 xS[6][4][50][8];   // 19.2 KB  [row][q][col][8ch]
    const int y0 = blockIdx.x * 4;
    const int og = blockIdx.y;
    const int b  = blockIdx.z;
    const int tid = threadIdx.x;
    const int wv = tid >> 6;
    const int ln = tid & 63;
    const int n  = ln & 15;
    const int q  = ln >> 4;

    f32x4 acc[2][3];
#pragma unroll
    for (int mt = 0; mt < 2; ++mt)
#pragma unroll
        for (int nt = 0; nt < 3; ++nt) acc[mt][nt] = (f32x4){0.f, 0.f, 0.f, 0.f};

    for (int cc = 0; cc < 1024; cc += 32) {
#pragma unroll
        for (int it = 0; it < 5; ++it) {
            int g = it * 256 + tid;
            if (g < 1152) {
                int tap = g >> 7, r = g & 127, qq = r >> 5, oc = r & 31;
                *(uint4*)&wS[tap][qq][oc][0] =
                    *(const uint4*)(wf + ((size_t)(og * 32 + oc) * 9 + tap) * 1024 + cc + qq * 8);
            }
        }
#pragma unroll
        for (int it = 0; it < 5; ++it) {
            int g = it * 256 + tid;
            if (g < 1200) {
                int row = g / 200, r2 = g - row * 200;
                int qq = r2 / 50, c = r2 - qq * 50;
                int gy = y0 + row - 1, gx = c - 1;
                uint4 v = make_uint4(0u, 0u, 0u, 0u);
                if ((unsigned)gy < 48u && (unsigned)gx < 48u)
                    v = *(const uint4*)(xf + ((size_t)(b * 48 + gy) * 48 + gx) * 1024 + cc + qq * 8);
                *(uint4*)&xS[row][qq][c][0] = v;
            }
        }
        __syncthreads();

#pragma unroll
        for (int tap = 0; tap < 9; ++tap) {
            const int dy = tap / 3, dx = tap % 3;
            f16x8 a0 = *(const f16x8*)&wS[tap][q][n][0];
            f16x8 a1 = *(const f16x8*)&wS[tap][q][16 + n][0];
#pragma unroll
            for (int nt = 0; nt < 3; ++nt) {
                f16x8 bb = *(const f16x8*)&xS[wv + dy][q][nt * 16 + n + dx][0];
                acc[0][nt] = __builtin_amdgcn_mfma_f32_16x16x32_f16(a0, bb, acc[0][nt], 0, 0, 0);
                acc[1][nt] = __builtin_amdgcn_mfma_f32_16x16x32_f16(a1, bb, acc[1][nt], 0, 0, 0);
            }
        }
        __syncthreads();
    }

    const int y = y0 + wv;
#pragma unroll
    for (int mt = 0; mt < 2; ++mt) {
        float4 b4 = *(const float4*)(bd + og * 32 + mt * 16 + q * 4);
#pragma unroll
        for (int nt = 0; nt < 3; ++nt) {
            int x = nt * 16 + n;
            f16x4 v;
            v.x = (_Float16)fmaxf(acc[mt][nt][0] + b4.x, 0.f);
            v.y = (_Float16)fmaxf(acc[mt][nt][1] + b4.y, 0.f);
            v.z = (_Float16)fmaxf(acc[mt][nt][2] + b4.z, 0.f);
            v.w = (_Float16)fmaxf(acc[mt][nt][3] + b4.w, 0.f);
            *(f16x4*)(dec + ((size_t)(b * 48 + y) * 48 + x) * 256 + og * 32 + mt * 16 + q * 4) = v;
        }
    }
}

// ---------------------------------------------------------------------------
// ROI align 2x2 on NHWC f16 dec: one block per box, thread = channel.
// ---------------------------------------------------------------------------
__global__ __launch_bounds__(256) void roi_kernel(
    const _Float16* __restrict__ dec, const float* __restrict__ boxes,
    _Float16* __restrict__ cnn)
{
    int n = blockIdx.x; int c = threadIdx.x;
    int b = n >> 9;
    float x1 = boxes[n * 4 + 0], y1 = boxes[n * 4 + 1];
    float x2 = boxes[n * 4 + 2], y2 = boxes[n * 4 + 3];
    float bw = (x2 - x1) * 0.5f, bh = (y2 - y1) * 0.5f;
    float sxv[2] = { x1 + 0.5f * bw, x1 + 1.5f * bw };
    float syv[2] = { y1 + 0.5f * bh, y1 + 1.5f * bh };
    float px[4] = { sxv[0], sxv[1], sxv[0], sxv[1] };
    float py[4] = { syv[0], syv[0], syv[1], syv[1] };
    const _Float16* f = dec + (size_t)b * 2304 * 256;
    f16x4 o4;
    float res[4];
#pragma unroll
    for (int p = 0; p < 4; ++p) {
        float yy = fminf(fmaxf(py[p], 0.f), 47.f);
        float xx = fminf(fmaxf(px[p], 0.f), 47.f);
        int y0 = (int)floorf(yy), x0 = (int)floorf(xx);
        int y1i = min(y0 + 1, 47), x1i = min(x0 + 1, 47);
        float wy = yy - (float)y0, wx = xx - (float)x0;
        float f00 = (float)f[(size_t)(y0 * 48 + x0) * 256 + c];
        float f01 = (float)f[(size_t)(y0 * 48 + x1i) * 256 + c];
        float f10 = (float)f[(size_t)(y1i * 48 + x0) * 256 + c];
        float f11 = (float)f[(size_t)(y1i * 48 + x1i) * 256 + c];
        res[p] = f00 * (1.f - wy) * (1.f - wx) + f01 * (1.f - wy) * wx
               + f10 * wy * (1.f - wx) + f11 * wy * wx;
    }
    o4.x = (_Float16)res[0]; o4.y = (_Float16)res[1];
    o4.z = (_Float16)res[2]; o4.w = (_Float16)res[3];
    *(f16x4*)(cnn + (size_t)n * 1024 + c * 4) = o4;
}

// ---------------------------------------------------------------------------
// box head: fusion[:, 0:256] = relu(bf @ W_box + b_box)
// ---------------------------------------------------------------------------
__global__ __launch_bounds__(256) void box_kernel(
    const float* __restrict__ boxes, const float* __restrict__ Wb,
    const float* __restrict__ bb, _Float16* __restrict__ fusion)
{
    int nrow = blockIdx.x, c = threadIdx.x;
    float x1 = boxes[nrow * 4 + 0], y1 = boxes[nrow * 4 + 1];
    float x2 = boxes[nrow * 4 + 2], y2 = boxes[nrow * 4 + 3];
    float bf0 = ((x1 + x2) * 0.5f) / 48.f;
    float bf1 = ((y1 + y2) * 0.5f) / 48.f;
    float bf2 = (x2 - x1) / 48.f;
    float bf3 = (y2 - y1) / 48.f;
    float acc = bb[c];
    acc += bf0 * Wb[0 * 256 + c];
    acc += bf1 * Wb[1 * 256 + c];
    acc += bf2 * Wb[2 * 256 + c];
    acc += bf3 * Wb[3 * 256 + c];
    fusion[(size_t)nrow * 768 + c] = (_Float16)fmaxf(acc, 0.f);
}

// ---------------------------------------------------------------------------
// f16 MFMA GEMM: C = act(A @ Bt^T + bias). 64x64 tile, 4 waves 2x2.
// ---------------------------------------------------------------------------
template <int ACT, typename OUTT>
__global__ __launch_bounds__(256) void gemm16_kernel(
    const _Float16* __restrict__ A, const _Float16* __restrict__ Bt,
    const float* __restrict__ bias, OUTT* __restrict__ C,
    int M, int N, int K, int ldC)
{
    __shared__ _Float16 aS[64][4][8];
    __shared__ _Float16 bS[64][4][8];
    const int n0 = blockIdx.x * 64, m0 = blockIdx.y * 64;
    const int tid = threadIdx.x;
    const int wv = tid >> 6, ln = tid & 63;
    const int wm = wv & 1, wn = wv >> 1;
    const int lm = ln & 15, lq = ln >> 4;
    const int sr = tid >> 2, sq = tid & 3;

    f32x4 acc[2][2];
#pragma unroll
    for (int i = 0; i < 2; ++i)
#pragma unroll
        for (int j = 0; j < 2; ++j) acc[i][j] = (f32x4){0.f, 0.f, 0.f, 0.f};

    for (int cc = 0; cc < K; cc += 32) {
        *(uint4*)&aS[sr][sq][0] = *(const uint4*)(A + (size_t)(m0 + sr) * K + cc + sq * 8);
        uint4 bv = make_uint4(0u, 0u, 0u, 0u);
        if (n0 + sr < N)
            bv = *(const uint4*)(Bt + (size_t)(n0 + sr) * K + cc + sq * 8);
        *(uint4*)&bS[sr][sq][0] = bv;
        __syncthreads();
        f16x8 af[2], bf[2];
#pragma unroll
        for (int mt = 0; mt < 2; ++mt) af[mt] = *(const f16x8*)&aS[wm * 32 + mt * 16 + lm][lq][0];
#pragma unroll
        for (int nt = 0; nt < 2; ++nt) bf[nt] = *(const f16x8*)&bS[wn * 32 + nt * 16 + lm][lq][0];
#pragma unroll
        for (int mt = 0; mt < 2; ++mt)
#pragma unroll
            for (int nt = 0; nt < 2; ++nt)
                acc[mt][nt] = __builtin_amdgcn_mfma_f32_16x16x32_f16(af[mt], bf[nt], acc[mt][nt], 0, 0, 0);
        __syncthreads();
    }

#pragma unroll
    for (int mt = 0; mt < 2; ++mt) {
#pragma unroll
        for (int nt = 0; nt < 2; ++nt) {
            int col = n0 + wn * 32 + nt * 16 + lm;
            if (col >= N) continue;
            float bs = bias ? bias[col] : 0.f;
#pragma unroll
            for (int r = 0; r < 4; ++r) {
                int row = m0 + wm * 32 + mt * 16 + lq * 4 + r;
                float v = acc[mt][nt][r] + bs;
                if (ACT == 1) v = fmaxf(v, 0.f);
                if (ACT == 2) v = (v >= 0.f) ? v : 0.01f * v;
                C[(size_t)row * ldC + col] = (OUTT)v;
            }
        }
    }
}

// ---------------------------------------------------------------------------
// E0: per-batch centers + table extents (fp32, exact ref op order)
// ---------------------------------------------------------------------------
__global__ __launch_bounds__(512) void e0_kernel(
    const float* __restrict__ boxes, const float* __restrict__ scales,
    const float* __restrict__ pdls, const float* __restrict__ pdts,
    float* __restrict__ cxA, float* __restrict__ cyA, float* __restrict__ tb)
{
    __shared__ float sw[512], sh[512];
    int b = blockIdx.x, n = threadIdx.x;
    float pdl = pdls[b], pdt = pdts[b], sc = scales[b];
    const float* bx = boxes + (size_t)(b * 512 + n) * 4;
    float o0 = (bx[0] - pdl) / sc;
    float o1 = (bx[1] - pdt) / sc;
    float o2 = (bx[2] - pdl) / sc;
    float o3 = (bx[3] - pdt) / sc;
    cxA[b * 512 + n] = (o0 + o2) * 0.5f;
    cyA[b * 512 + n] = (o1 + o3) * 0.5f;
    sw[n] = fmaxf(o0, o2); sh[n] = fmaxf(o1, o3);
    __syncthreads();
    for (int s = 256; s > 0; s >>= 1) {
        if (n < s) { sw[n] = fmaxf(sw[n], sw[n + s]); sh[n] = fmaxf(sh[n], sh[n + s]); }
        __syncthreads();
    }
    if (n == 0) { tb[b * 2 + 0] = sw[0]; tb[b * 2 + 1] = sh[0]; }
}

// ---------------------------------------------------------------------------
// Fused selection + emission + CSR build.  One block per sel=(b,t).
//
// Reference key = attr = f32 exp(-q), descending, ties by pair index.
// exp is MONOTONE nonincreasing in q, so the multiset order statistics map:
// K-th largest w == exp(-(K-th smallest q)).  We therefore radix-select on
// cheap q-bits (NO exp in the O(NE) passes), then recover the w-tie group as
// the q-bit interval [q_lo, q_hi] mapping to w* (two 32-step binary searches
// on thread 0).  Emission: qb < q_lo <=> w > w* (emit, exp only for winners);
// qb in [q_lo,q_hi] <=> w == w* (tie, resolved by smallest pair index,
// r = K - emitted).  Identical selected set to the R6 key-select.
// ---------------------------------------------------------------------------
__global__ __launch_bounds__(1024) void select_emit_kernel(
    const float* __restrict__ cxA, const float* __restrict__ cyA,
    const float* __restrict__ tb,
    int* __restrict__ es, int* __restrict__ ed, float* __restrict__ ewt,
    int* __restrict__ indeg_g, float* __restrict__ dis_g,
    int* __restrict__ offs_g, int* __restrict__ csr_g)
{
    const int sel = blockIdx.x;
    const int b = sel >> 1, t = sel & 1;
    const int tid = threadIdx.x;
    const int wv = tid >> 6;
    __shared__ float sv[512];
    __shared__ u32 h[16][256];
    __shared__ u32 tot[256];
    __shared__ int s_digit, s_need;
    __shared__ float s_tb;
    __shared__ u32 s_qlo, s_qhi;
    __shared__ float s_wstar;
    __shared__ int tiebuf[TIECAP];
    __shared__ int tiecnt, emitcnt;
    __shared__ int ideg[512];
    __shared__ float dgw[512];
    __shared__ int offs_l[512];
    __shared__ int fill_l[512];
    __shared__ int sA[512], sB[512];

    if (tid < 512) sv[tid] = (t == 0) ? cyA[b * 512 + tid] : cxA[b * 512 + tid];
    if (tid < 512) { ideg[tid] = 0; dgw[tid] = 1.0f; fill_l[tid] = 0; }
    if (tid == 0) { s_tb = tb[b * 2 + (t == 0 ? 1 : 0)]; tiecnt = 0; emitcnt = 0; }
    __syncthreads();
    const float tbv = s_tb;
    int need = KEDGE;
    u32 prefix = 0;

    // q-bits of edge e: fp32, exact reference op order (sub, mul5, div, sqr)
#define QBITS(e, QB)                                                   \
    {                                                                  \
        int i_ = (e) / 511; int jj_ = (e) - i_ * 511;                  \
        int j_ = jj_ + (jj_ >= i_ ? 1 : 0);                            \
        float diff_ = sv[i_] - sv[j_];                                 \
        float u_ = (diff_ * 5.0f) / tbv;                               \
        float q_ = u_ * u_;                                            \
        QB = __float_as_uint(q_);                                      \
    }

    // ---- 4 radix passes over q-bits (MSB -> LSB), prefix-filtered ----
    for (int byte = 3; byte >= 0; --byte) {
        const int sh = byte * 8;
        const u32 mask = (byte == 3) ? 0u : (0xFFFFFFFFu << (sh + 8));
        for (int x = tid; x < 16 * 256; x += 1024) ((u32*)h)[x] = 0;
        __syncthreads();
        for (int e = tid; e < NE; e += 1024) {
            u32 qb; QBITS(e, qb);
            if ((qb & mask) == (prefix & mask))
                atomicAdd(&h[wv][(int)((qb >> sh) & 0xFF)], 1u);
        }
        __syncthreads();
        if (tid < 256) { u32 s = 0; for (int w = 0; w < 16; ++w) s += h[w][tid]; tot[tid] = s; }
        __syncthreads();
        if (tid == 0) {
            u32 cum = 0; int d = 255;
            for (int bb = 0; bb < 256; ++bb) { if (cum + tot[bb] >= (u32)need) { d = bb; break; } cum += tot[bb]; }
            s_digit = d; s_need = need - (int)cum;
        }
        __syncthreads();
        prefix |= ((u32)s_digit) << sh; need = s_need;
        __syncthreads();
    }
    // prefix = q*_bits (K-th smallest q)

    // ---- thread 0: w* and the q-bit interval mapping to w* ----
    if (tid == 0) {
        float qstar = __uint_as_float(prefix);
        float wstar = (float)exp(-(double)qstar);
        u32 lo = 0, hi = prefix;              // smallest qb with exp(-q)==w*
        while (lo < hi) {
            u32 mid = (lo + hi) >> 1;
            float wm = (float)exp(-(double)__uint_as_float(mid));
            if (wm > wstar) lo = mid + 1; else hi = mid;
        }
        s_qlo = lo;
        lo = prefix; hi = 0x7F800000u;        // largest qb with exp(-q)==w*
        while (lo < hi) {
            u32 mid = (lo + hi + 1) >> 1;
            float wm = (float)exp(-(double)__uint_as_float(mid));
            if (wm < wstar) hi = mid - 1; else lo = mid;
        }
        s_qhi = lo;
        s_wstar = wstar;
    }
    __syncthreads();
    const u32 qlo = s_qlo, qhi = s_qhi;

    // ---- emission pass (exp only for the ~4096 winners) ----
    const int base = t * 16384 + b * 4096;
    for (int e = tid; e < NE; e += 1024) {
        u32 qb; QBITS(e, qb);
        if (qb < qlo) {
            int i = e / 511; int jj = e - i * 511; int j = jj + (jj >= i ? 1 : 0);
            float wval = (float)exp(-(double)__uint_as_float(qb));
            int slot = atomicAdd(&emitcnt, 1);
            es[base + slot] = b * 512 + i;
            ed[base + slot] = b * 512 + j;
            ewt[base + slot] = wval;
            atomicAdd(&ideg[j], 1);
            atomicAdd(&dgw[j], wval);
        } else if (qb <= qhi) {
            int p = atomicAdd(&tiecnt, 1);
            if (p < TIECAP) tiebuf[p] = e;
        }
    }
    __syncthreads();

    // ---- tie resolution: smallest pair-index first (lax.top_k) ----
    {
        int m = min(tiecnt, TIECAP);
        int r = KEDGE - emitcnt;
        float wt = s_wstar;
        for (int k = tid; k < m; k += 1024) {
            int e = tiebuf[k];
            int rank = 0;
            for (int l = 0; l < m; ++l) rank += (tiebuf[l] < e) ? 1 : 0;
            if (rank < r) {
                int i = e / 511; int jj = e - i * 511; int j = jj + (jj >= i ? 1 : 0);
                int slot = atomicAdd(&emitcnt, 1);
                es[base + slot] = b * 512 + i;
                ed[base + slot] = b * 512 + j;
                ewt[base + slot] = wt;
                atomicAdd(&ideg[j], 1);
                atomicAdd(&dgw[j], wt);
            }
        }
    }
    __syncthreads();

    // ---- scan indeg -> offs_l (exclusive) ----
    if (tid < 512) sA[tid] = ideg[tid];
    __syncthreads();
    {
        int* src = sA; int* dst = sB;
        for (int st = 1; st < 512; st <<= 1) {
            if (tid < 512) dst[tid] = src[tid] + (tid >= st ? src[tid - st] : 0);
            __syncthreads();
            int* tmp = src; src = dst; dst = tmp;
        }
        if (tid < 512) offs_l[tid] = (tid == 0) ? 0 : src[tid - 1];
    }
    __syncthreads();

    // ---- CSR fill (local) ----
    for (int s = tid; s < 4096; s += 1024) {
        int dl = ed[base + s] & 511;
        int pos = offs_l[dl] + atomicAdd(&fill_l[dl], 1);
        csr_g[base + pos] = b * 4096 + s;
    }
    // ---- per-node globals ----
    if (tid < 512) {
        int gd = t * 2048 + b * 512 + tid;
        indeg_g[gd] = ideg[tid];
        offs_g[gd] = b * 4096 + offs_l[tid];
        dis_g[gd] = 1.0f / sqrtf(dgw[tid]);
    }
#undef QBITS
}

// E7: GCN aggregate -> feats f16
__global__ __launch_bounds__(256) void gcn_agg_kernel(
    const float* __restrict__ xw_row, const float* __restrict__ xw_col,
    const float* __restrict__ b_row, const float* __restrict__ b_col,
    const int* __restrict__ es, const float* __restrict__ ew,
    const int* __restrict__ csr, const int* __restrict__ offs,
    const int* __restrict__ indeg, const float* __restrict__ dis,
    _Float16* __restrict__ feat_row, _Float16* __restrict__ feat_col)
{
    int d = blockIdx.x; int t = blockIdx.y;
    const float* xw = t ? xw_col : xw_row;
    const float* bg = t ? b_col : b_row;
    _Float16* out = t ? feat_col : feat_row;
    int f0 = threadIdx.x, f1 = threadIdx.x + 256;
    float dd = dis[t * 2048 + d];
    float a0 = dd * dd * xw[(size_t)d * 512 + f0];
    float a1 = dd * dd * xw[(size_t)d * 512 + f1];
    int st = offs[t * 2048 + d], cnt = indeg[t * 2048 + d];
    for (int k = 0; k < cnt; ++k) {
        int e = csr[t * 16384 + st + k];
        int s = es[t * 16384 + e];
        float w = ew[t * 16384 + e];
        float coef = dis[t * 2048 + s] * w * dd;
        a0 += coef * xw[(size_t)s * 512 + f0];
        a1 += coef * xw[(size_t)s * 512 + f1];
    }
    a0 += bg[f0]; a1 += bg[f1];
    out[(size_t)d * 512 + f0] = (_Float16)fmaxf(a0, 0.f);
    out[(size_t)d * 512 + f1] = (_Float16)fmaxf(a1, 0.f);
}

// ---------------------------------------------------------------------------
extern "C" void kernel_launch(void* const* d_in, const int* in_sizes, int n_in,
                              void* d_out, int out_size, void* d_ws, size_t ws_size,
                              hipStream_t stream)
{
    const float* x      = (const float*)d_in[0];
    const float* boxes  = (const float*)d_in[1];
    const float* scales = (const float*)d_in[2];
    const float* pdls   = (const float*)d_in[3];
    const float* pdts   = (const float*)d_in[4];
    const float* W_dec  = (const float*)d_in[5];
    const float* b_dec  = (const float*)d_in[6];
    const float* W_box  = (const float*)d_in[7];
    const float* b_box  = (const float*)d_in[8];
    const float* W_cnn  = (const float*)d_in[9];
    const float* b_cnn  = (const float*)d_in[10];
    const float* W_grow = (const float*)d_in[11];
    const float* b_grow = (const float*)d_in[12];
    const float* W_gcol = (const float*)d_in[13];
    const float* b_gcol = (const float*)d_in[14];
    const float* W_rcls = (const float*)d_in[15];
    const float* b_rcls = (const float*)d_in[16];
    const float* W_ccls = (const float*)d_in[17];
    const float* b_ccls = (const float*)d_in[18];

    char* ws = (char*)d_ws;
    size_t off = 0;
    auto alloc = [&](size_t bytes) -> void* {
        void* p = ws + off;
        off = (off + bytes + 255) & ~(size_t)255;
        return p;
    };
    _Float16* xf16   = (_Float16*)alloc((size_t)4 * 2304 * 1024 * 2);  // NHWC in
    _Float16* wf16   = (_Float16*)alloc((size_t)256 * 9216 * 2);       // [o][tap][ch]
    _Float16* dec    = (_Float16*)alloc((size_t)4 * 2304 * 256 * 2);   // NHWC
    _Float16* cnn    = (_Float16*)alloc((size_t)2048 * 1024 * 2);
    _Float16* fusion = (_Float16*)alloc((size_t)2048 * 768 * 2);
    _Float16* WcT    = (_Float16*)alloc((size_t)512 * 1024 * 2);
    _Float16* WgrT   = (_Float16*)alloc((size_t)512 * 768 * 2);
    _Float16* WgcT   = (_Float16*)alloc((size_t)512 * 768 * 2);
    _Float16* WrT    = (_Float16*)alloc((size_t)228 * 512 * 2);
    _Float16* WccT   = (_Float16*)alloc((size_t)116 * 512 * 2);
    float* xw        = (float*)alloc((size_t)2097152 * 4);             // xw_row|xw_col
    _Float16* feats  = (_Float16*)alloc((size_t)2 * 2048 * 512 * 2);   // row|col
    float* cxA   = (float*)alloc((size_t)2048 * 4);
    float* cyA   = (float*)alloc((size_t)2048 * 4);
    float* tbA   = (float*)alloc((size_t)8 * 4);
    int*  es     = (int*)  alloc((size_t)2 * 16384 * 4);
    int*  ed     = (int*)  alloc((size_t)2 * 16384 * 4);
    float* ewt   = (float*)alloc((size_t)2 * 16384 * 4);
    int*  indeg  = (int*)  alloc((size_t)4096 * 4);
    float* dis   = (float*)alloc((size_t)4096 * 4);
    int*  offsA  = (int*)  alloc((size_t)4096 * 4);
    int*  csr    = (int*)  alloc((size_t)2 * 16384 * 4);

    float* out = (float*)d_out;

    cvt_x_kernel<<<dim3(16, 48, 4), 256, 0, stream>>>(x, xf16);
    cvt_w_kernel<<<256, 256, 0, stream>>>(W_dec, wf16);
    conv_f16_kernel<<<dim3(12, 8, 4), 256, 0, stream>>>(xf16, wf16, b_dec, dec);
    roi_kernel<<<2048, 256, 0, stream>>>(dec, boxes, cnn);
    box_kernel<<<2048, 256, 0, stream>>>(boxes, W_box, b_box, fusion);
    // weight transposes (f16 [N][K])
    cvt_t_kernel<<<dim3(16, 32), 256, 0, stream>>>(W_cnn, WcT, 1024, 512);
    cvt_t_kernel<<<dim3(16, 24), 256, 0, stream>>>(W_grow, WgrT, 768, 512);
    cvt_t_kernel<<<dim3(16, 24), 256, 0, stream>>>(W_gcol, WgcT, 768, 512);
    cvt_t_kernel<<<dim3(8, 16), 256, 0, stream>>>(W_rcls, WrT, 512, 228);
    cvt_t_kernel<<<dim3(4, 16), 256, 0, stream>>>(W_ccls, WccT, 512, 116);
    // fusion[:,256:768] = relu(cnn @ W_cnn + b)
    gemm16_kernel<1, _Float16><<<dim3(8, 32), 256, 0, stream>>>(cnn, WcT, b_cnn, fusion + 256, 2048, 512, 1024, 768);
    // edge pipeline: fused select + emit + CSR (q-bit radix, exp-free sweeps)
    e0_kernel<<<4, 512, 0, stream>>>(boxes, scales, pdls, pdts, cxA, cyA, tbA);
    select_emit_kernel<<<8, 1024, 0, stream>>>(cxA, cyA, tbA,
                                               es, ed, ewt, indeg, dis, offsA, csr);
    // xw = fusion @ W_g{row,col} (bias applied in aggregation)
    gemm16_kernel<0, float><<<dim3(8, 32), 256, 0, stream>>>(fusion, WgrT, nullptr, xw, 2048, 512, 768, 512);
    gemm16_kernel<0, float><<<dim3(8, 32), 256, 0, stream>>>(fusion, WgcT, nullptr, xw + 1048576, 2048, 512, 768, 512);
    gcn_agg_kernel<<<dim3(2048, 2), 256, 0, stream>>>(xw, xw + 1048576, b_grow, b_gcol,
                                                      es, ewt, csr, offsA, indeg, dis,
                                                      feats, feats + (size_t)2048 * 512);
    // classifier heads (leaky 0.01) -> fp32 out
    gemm16_kernel<2, float><<<dim3(4, 32), 256, 0, stream>>>(feats, WrT, b_rcls, out, 2048, 228, 512, 228);
    gemm16_kernel<2, float><<<dim3(2, 32), 256, 0, stream>>>(feats + (size_t)2048 * 512, WccT, b_ccls,
                                                             out + (size_t)2048 * 228, 2048, 116, 512, 116);
}

// Round 8
// 653.097 us; speedup vs baseline: 5.9914x; 1.1861x over previous
//
#include <hip/hip_runtime.h>
#include <cstdint>
#include <math.h>

typedef unsigned int u32;
typedef unsigned long long u64;
typedef unsigned short ushort;

typedef __attribute__((ext_vector_type(8))) _Float16 f16x8;
typedef __attribute__((ext_vector_type(4))) _Float16 f16x4;
typedef __attribute__((ext_vector_type(4))) float f32x4;

#define NB    4
#define BnN   2048
#define NE    261632      // 512*511 ordered pairs per batch
#define NCHUNK 16
#define ECHUNK 16352      // NE/16
#define KEDGE 4096
#define TIECAP 2048

// meta[sel*8 + i]: 0 prefix16, 1 needA, 2 qlo, 3 qhi, 4 wstar_bits, 5 emitcnt
// ---------------------------------------------------------------------------
// convert input: NCHW fp32 -> NHWC f16.  grid (16 chgrp, 48 y, 4 b), block 256
// ---------------------------------------------------------------------------
__global__ __launch_bounds__(256) void cvt_x_kernel(
    const float* __restrict__ in, _Float16* __restrict__ xf)
{
    __shared__ _Float16 sh[64][49];
    int cg = blockIdx.x, y = blockIdx.y, b = blockIdx.z;
    int tid = threadIdx.x;
    for (int i = tid; i < 64 * 48; i += 256) {
        int cl = i / 48, x = i - cl * 48;
        sh[cl][x] = (_Float16)in[(((size_t)b * 1024 + cg * 64 + cl) * 48 + y) * 48 + x];
    }
    __syncthreads();
    for (int i = tid; i < 64 * 48; i += 256) {
        int x = i / 64, cl = i - x * 64;
        xf[((size_t)(b * 48 + y) * 48 + x) * 1024 + cg * 64 + cl] = sh[cl][x];
    }
}

// convert weights: [o][ch][3][3] fp32 -> [o][tap][ch] f16. grid 256, block 256
__global__ __launch_bounds__(256) void cvt_w_kernel(
    const float* __restrict__ W, _Float16* __restrict__ wf)
{
    __shared__ _Float16 sh[9216];
    int o = blockIdx.x, tid = threadIdx.x;
    for (int g = tid; g < 9216; g += 256)
        sh[g] = (_Float16)W[(size_t)o * 9216 + g];     // g = ch*9+tap
    __syncthreads();
    for (int g = tid; g < 9216; g += 256) {
        int tap = g >> 10, ch = g & 1023;
        wf[(size_t)o * 9216 + g] = sh[ch * 9 + tap];
    }
}

// transpose-convert: in fp32 [K][N] -> out f16 [N][K]. grid (ceil(N/32), ceil(K/32))
__global__ __launch_bounds__(256) void cvt_t_kernel(
    const float* __restrict__ in, _Float16* __restrict__ out, int K, int N)
{
    __shared__ _Float16 sh[32][33];
    int n0 = blockIdx.x * 32, k0 = blockIdx.y * 32;
    int tx = threadIdx.x & 31, ty = threadIdx.x >> 5;
#pragma unroll
    for (int i = 0; i < 4; ++i) {
        int k = k0 + ty + i * 8, n = n0 + tx;
        sh[ty + i * 8][tx] = (k < K && n < N) ? (_Float16)in[(size_t)k * N + n] : (_Float16)0.f;
    }
    __syncthreads();
#pragma unroll
    for (int i = 0; i < 4; ++i) {
        int n = n0 + ty + i * 8, k = k0 + tx;
        if (n < N && k < K) out[(size_t)n * K + k] = sh[tx][ty + i * 8];
    }
}

// ---------------------------------------------------------------------------
// conv 3x3 SAME 1024->256 +bias +relu. Implicit-GEMM MFMA f16 (fp32 acc).
// ---------------------------------------------------------------------------
__global__ __launch_bounds__(256) void conv_f16_kernel(
    const _Float16* __restrict__ xf, const _Float16* __restrict__ wf,
    const float* __restrict__ bd, _Float16* __restrict__ dec)
{
    __shared__ _Float16 wS[9][4][32][8];   // 18.4 KB  [tap][q][och][8ch]
    __shared__ _Float16 xS[6][4][50][8];   // 19.2 KB  [row][q][col][8ch]
    const int y0 = blockIdx.x * 4;
    const int og = blockIdx.y;
    const int b  = blockIdx.z;
    const int tid = threadIdx.x;
    const int wv = tid >> 6;
    const int ln = tid & 63;
    const int n  = ln & 15;
    const int q  = ln >> 4;

    f32x4 acc[2][3];
#pragma unroll
    for (int mt = 0; mt < 2; ++mt)
#pragma unroll
        for (int nt = 0; nt < 3; ++nt) acc[mt][nt] = (f32x4){0.f, 0.f, 0.f, 0.f};

    for (int cc = 0; cc < 1024; cc += 32) {
#pragma unroll
        for (int it = 0; it < 5; ++it) {
            int g = it * 256 + tid;
            if (g < 1152) {
                int tap = g >> 7, r = g & 127, qq = r >> 5, oc = r & 31;
                *(uint4*)&wS[tap][qq][oc][0] =
                    *(const uint4*)(wf + ((size_t)(og * 32 + oc) * 9 + tap) * 1024 + cc + qq * 8);
            }
        }
#pragma unroll
        for (int it = 0; it < 5; ++it) {
            int g = it * 256 + tid;
            if (g < 1200) {
                int row = g / 200, r2 = g - row * 200;
                int qq = r2 / 50, c = r2 - qq * 50;
                int gy = y0 + row - 1, gx = c - 1;
                uint4 v = make_uint4(0u, 0u, 0u, 0u);
                if ((unsigned)gy < 48u && (unsigned)gx < 48u)
                    v = *(const uint4*)(xf + ((size_t)(b * 48 + gy) * 48 + gx) * 1024 + cc + qq * 8);
                *(uint4*)&xS[row][qq][c][0] = v;
            }
        }
        __syncthreads();

#pragma unroll
        for (int tap = 0; tap < 9; ++tap) {
            const int dy = tap / 3, dx = tap % 3;
            f16x8 a0 = *(const f16x8*)&wS[tap][q][n][0];
            f16x8 a1 = *(const f16x8*)&wS[tap][q][16 + n][0];
#pragma unroll
            for (int nt = 0; nt < 3; ++nt) {
                f16x8 bb = *(const f16x8*)&xS[wv + dy][q][nt * 16 + n + dx][0];
                acc[0][nt] = __builtin_amdgcn_mfma_f32_16x16x32_f16(a0, bb, acc[0][nt], 0, 0, 0);
                acc[1][nt] = __builtin_amdgcn_mfma_f32_16x16x32_f16(a1, bb, acc[1][nt], 0, 0, 0);
            }
        }
        __syncthreads();
    }

    const int y = y0 + wv;
#pragma unroll
    for (int mt = 0; mt < 2; ++mt) {
        float4 b4 = *(const float4*)(bd + og * 32 + mt * 16 + q * 4);
#pragma unroll
        for (int nt = 0; nt < 3; ++nt) {
            int x = nt * 16 + n;
            f16x4 v;
            v.x = (_Float16)fmaxf(acc[mt][nt][0] + b4.x, 0.f);
            v.y = (_Float16)fmaxf(acc[mt][nt][1] + b4.y, 0.f);
            v.z = (_Float16)fmaxf(acc[mt][nt][2] + b4.z, 0.f);
            v.w = (_Float16)fmaxf(acc[mt][nt][3] + b4.w, 0.f);
            *(f16x4*)(dec + ((size_t)(b * 48 + y) * 48 + x) * 256 + og * 32 + mt * 16 + q * 4) = v;
        }
    }
}

// ---------------------------------------------------------------------------
// ROI align 2x2 on NHWC f16 dec
// ---------------------------------------------------------------------------
__global__ __launch_bounds__(256) void roi_kernel(
    const _Float16* __restrict__ dec, const float* __restrict__ boxes,
    _Float16* __restrict__ cnn)
{
    int n = blockIdx.x; int c = threadIdx.x;
    int b = n >> 9;
    float x1 = boxes[n * 4 + 0], y1 = boxes[n * 4 + 1];
    float x2 = boxes[n * 4 + 2], y2 = boxes[n * 4 + 3];
    float bw = (x2 - x1) * 0.5f, bh = (y2 - y1) * 0.5f;
    float sxv[2] = { x1 + 0.5f * bw, x1 + 1.5f * bw };
    float syv[2] = { y1 + 0.5f * bh, y1 + 1.5f * bh };
    float px[4] = { sxv[0], sxv[1], sxv[0], sxv[1] };
    float py[4] = { syv[0], syv[0], syv[1], syv[1] };
    const _Float16* f = dec + (size_t)b * 2304 * 256;
    f16x4 o4;
    float res[4];
#pragma unroll
    for (int p = 0; p < 4; ++p) {
        float yy = fminf(fmaxf(py[p], 0.f), 47.f);
        float xx = fminf(fmaxf(px[p], 0.f), 47.f);
        int y0 = (int)floorf(yy), x0 = (int)floorf(xx);
        int y1i = min(y0 + 1, 47), x1i = min(x0 + 1, 47);
        float wy = yy - (float)y0, wx = xx - (float)x0;
        float f00 = (float)f[(size_t)(y0 * 48 + x0) * 256 + c];
        float f01 = (float)f[(size_t)(y0 * 48 + x1i) * 256 + c];
        float f10 = (float)f[(size_t)(y1i * 48 + x0) * 256 + c];
        float f11 = (float)f[(size_t)(y1i * 48 + x1i) * 256 + c];
        res[p] = f00 * (1.f - wy) * (1.f - wx) + f01 * (1.f - wy) * wx
               + f10 * wy * (1.f - wx) + f11 * wy * wx;
    }
    o4.x = (_Float16)res[0]; o4.y = (_Float16)res[1];
    o4.z = (_Float16)res[2]; o4.w = (_Float16)res[3];
    *(f16x4*)(cnn + (size_t)n * 1024 + c * 4) = o4;
}

// ---------------------------------------------------------------------------
// box head: fusion[:, 0:256] = relu(bf @ W_box + b_box)
// ---------------------------------------------------------------------------
__global__ __launch_bounds__(256) void box_kernel(
    const float* __restrict__ boxes, const float* __restrict__ Wb,
    const float* __restrict__ bb, _Float16* __restrict__ fusion)
{
    int nrow = blockIdx.x, c = threadIdx.x;
    float x1 = boxes[nrow * 4 + 0], y1 = boxes[nrow * 4 + 1];
    float x2 = boxes[nrow * 4 + 2], y2 = boxes[nrow * 4 + 3];
    float bf0 = ((x1 + x2) * 0.5f) / 48.f;
    float bf1 = ((y1 + y2) * 0.5f) / 48.f;
    float bf2 = (x2 - x1) / 48.f;
    float bf3 = (y2 - y1) / 48.f;
    float acc = bb[c];
    acc += bf0 * Wb[0 * 256 + c];
    acc += bf1 * Wb[1 * 256 + c];
    acc += bf2 * Wb[2 * 256 + c];
    acc += bf3 * Wb[3 * 256 + c];
    fusion[(size_t)nrow * 768 + c] = (_Float16)fmaxf(acc, 0.f);
}

// ---------------------------------------------------------------------------
// f16 MFMA GEMM: C = act(A @ Bt^T + bias). 64x64 tile, 4 waves 2x2.
// ---------------------------------------------------------------------------
template <int ACT, typename OUTT>
__global__ __launch_bounds__(256) void gemm16_kernel(
    const _Float16* __restrict__ A, const _Float16* __restrict__ Bt,
    const float* __restrict__ bias, OUTT* __restrict__ C,
    int M, int N, int K, int ldC)
{
    __shared__ _Float16 aS[64][4][8];
    __shared__ _Float16 bS[64][4][8];
    const int n0 = blockIdx.x * 64, m0 = blockIdx.y * 64;
    const int tid = threadIdx.x;
    const int wv = tid >> 6, ln = tid & 63;
    const int wm = wv & 1, wn = wv >> 1;
    const int lm = ln & 15, lq = ln >> 4;
    const int sr = tid >> 2, sq = tid & 3;

    f32x4 acc[2][2];
#pragma unroll
    for (int i = 0; i < 2; ++i)
#pragma unroll
        for (int j = 0; j < 2; ++j) acc[i][j] = (f32x4){0.f, 0.f, 0.f, 0.f};

    for (int cc = 0; cc < K; cc += 32) {
        *(uint4*)&aS[sr][sq][0] = *(const uint4*)(A + (size_t)(m0 + sr) * K + cc + sq * 8);
        uint4 bv = make_uint4(0u, 0u, 0u, 0u);
        if (n0 + sr < N)
            bv = *(const uint4*)(Bt + (size_t)(n0 + sr) * K + cc + sq * 8);
        *(uint4*)&bS[sr][sq][0] = bv;
        __syncthreads();
        f16x8 af[2], bf[2];
#pragma unroll
        for (int mt = 0; mt < 2; ++mt) af[mt] = *(const f16x8*)&aS[wm * 32 + mt * 16 + lm][lq][0];
#pragma unroll
        for (int nt = 0; nt < 2; ++nt) bf[nt] = *(const f16x8*)&bS[wn * 32 + nt * 16 + lm][lq][0];
#pragma unroll
        for (int mt = 0; mt < 2; ++mt)
#pragma unroll
            for (int nt = 0; nt < 2; ++nt)
                acc[mt][nt] = __builtin_amdgcn_mfma_f32_16x16x32_f16(af[mt], bf[nt], acc[mt][nt], 0, 0, 0);
        __syncthreads();
    }

#pragma unroll
    for (int mt = 0; mt < 2; ++mt) {
#pragma unroll
        for (int nt = 0; nt < 2; ++nt) {
            int col = n0 + wn * 32 + nt * 16 + lm;
            if (col >= N) continue;
            float bs = bias ? bias[col] : 0.f;
#pragma unroll
            for (int r = 0; r < 4; ++r) {
                int row = m0 + wm * 32 + mt * 16 + lq * 4 + r;
                float v = acc[mt][nt][r] + bs;
                if (ACT == 1) v = fmaxf(v, 0.f);
                if (ACT == 2) v = (v >= 0.f) ? v : 0.01f * v;
                C[(size_t)row * ldC + col] = (OUTT)v;
            }
        }
    }
}

// ---------------------------------------------------------------------------
// shared helper: compute per-sel centers sv[512] (LDS) + table extent tbv.
// Bit-exact replica of the reference op order; identical reduce tree in all
// callers so every block derives identical tbv.
// ---------------------------------------------------------------------------
__device__ __forceinline__ float compute_sv_tb(
    const float* __restrict__ boxes, const float* __restrict__ scales,
    const float* __restrict__ pdls, const float* __restrict__ pdts,
    int b, int t, float* sv, float* red)
{
    int tid = threadIdx.x;
    float pdl = pdls[b], pdt = pdts[b], sc = scales[b];
    if (tid < 512) {
        const float* bx = boxes + (size_t)(b * 512 + tid) * 4;
        float o0 = (bx[0] - pdl) / sc;
        float o1 = (bx[1] - pdt) / sc;
        float o2 = (bx[2] - pdl) / sc;
        float o3 = (bx[3] - pdt) / sc;
        sv[tid]  = (t == 0) ? (o1 + o3) * 0.5f : (o0 + o2) * 0.5f;
        red[tid] = (t == 0) ? fmaxf(o1, o3)    : fmaxf(o0, o2);
    }
    __syncthreads();
    for (int s = 256; s > 0; s >>= 1) {
        if (tid < s) red[tid] = fmaxf(red[tid], red[tid + s]);
        __syncthreads();
    }
    float tbv = red[0];
    __syncthreads();
    return tbv;
}

#define QBITS(e, QB)                                                   \
    {                                                                  \
        int i_ = (e) / 511; int jj_ = (e) - i_ * 511;                  \
        int j_ = jj_ + (jj_ >= i_ ? 1 : 0);                            \
        float diff_ = sv[i_] - sv[j_];                                 \
        float u_ = (diff_ * 5.0f) / tbv;                               \
        float q_ = u_ * u_;                                            \
        QB = __float_as_uint(q_);                                      \
    }

// ---------------------------------------------------------------------------
// histA: global 65536-bin hist of top-16 q-bits. grid (16 chunks, 8 sels).
// ---------------------------------------------------------------------------
__global__ __launch_bounds__(1024) void histA_kernel(
    const float* __restrict__ boxes, const float* __restrict__ scales,
    const float* __restrict__ pdls, const float* __restrict__ pdts,
    u32* __restrict__ ghistA)
{
    __shared__ float sv[512]; __shared__ float red[512];
    const int sel = blockIdx.y, b = sel >> 1, t = sel & 1;
    const float tbv = compute_sv_tb(boxes, scales, pdls, pdts, b, t, sv, red);
    u32* H = ghistA + (size_t)sel * 65536;
    const int e1 = min((int)(blockIdx.x + 1) * ECHUNK, NE);
    for (int e = blockIdx.x * ECHUNK + threadIdx.x; e < e1; e += 1024) {
        u32 qb; QBITS(e, qb);
        atomicAdd(&H[qb >> 16], 1u);
    }
}

// ---------------------------------------------------------------------------
// scanA: find 16-bit prefix containing K-th smallest. 8 blocks x 1024.
// ---------------------------------------------------------------------------
__global__ __launch_bounds__(1024) void scanA_kernel(
    const u32* __restrict__ ghistA, u32* __restrict__ meta)
{
    const int sel = blockIdx.x, tid = threadIdx.x;
    const u32* H = ghistA + (size_t)sel * 65536;
    __shared__ u32 sc[2][1024];
    u32 part = 0;
    for (int j = 0; j < 64; ++j) part += H[tid * 64 + j];
    sc[0][tid] = part;
    __syncthreads();
    int src = 0;
    for (int st = 1; st < 1024; st <<= 1) {
        sc[1 - src][tid] = sc[src][tid] + (tid >= st ? sc[src][tid - st] : 0);
        __syncthreads(); src = 1 - src;
    }
    u32 inc = sc[src][tid], exc = inc - part;
    if (exc < (u32)KEDGE && (u32)KEDGE <= inc) {
        u32 cum = exc;
        for (int j = 0; j < 64; ++j) {
            u32 c = H[tid * 64 + j];
            if (cum + c >= (u32)KEDGE) {
                meta[sel * 8 + 0] = (u32)(tid * 64 + j);
                meta[sel * 8 + 1] = (u32)KEDGE - cum;
                break;
            }
            cum += c;
        }
    }
}

// ---------------------------------------------------------------------------
// histB: hist of low-16 bits among edges matching prefix16.
// ---------------------------------------------------------------------------
__global__ __launch_bounds__(1024) void histB_kernel(
    const float* __restrict__ boxes, const float* __restrict__ scales,
    const float* __restrict__ pdls, const float* __restrict__ pdts,
    const u32* __restrict__ meta, u32* __restrict__ ghistB)
{
    __shared__ float sv[512]; __shared__ float red[512];
    const int sel = blockIdx.y, b = sel >> 1, t = sel & 1;
    const float tbv = compute_sv_tb(boxes, scales, pdls, pdts, b, t, sv, red);
    const u32 p16 = meta[sel * 8 + 0];
    u32* H = ghistB + (size_t)sel * 65536;
    const int e1 = min((int)(blockIdx.x + 1) * ECHUNK, NE);
    for (int e = blockIdx.x * ECHUNK + threadIdx.x; e < e1; e += 1024) {
        u32 qb; QBITS(e, qb);
        if ((qb >> 16) == p16) atomicAdd(&H[qb & 0xFFFF], 1u);
    }
}

// ---------------------------------------------------------------------------
// scanB: exact q*, then thread 0 binary-searches the w*-tie q-interval.
// ---------------------------------------------------------------------------
__global__ __launch_bounds__(1024) void scanB_kernel(
    const u32* __restrict__ ghistB, u32* __restrict__ meta)
{
    const int sel = blockIdx.x, tid = threadIdx.x;
    const u32* H = ghistB + (size_t)sel * 65536;
    const u32 TH = meta[sel * 8 + 1];
    __shared__ u32 sc[2][1024];
    __shared__ u32 s_qstar;
    u32 part = 0;
    for (int j = 0; j < 64; ++j) part += H[tid * 64 + j];
    sc[0][tid] = part;
    __syncthreads();
    int src = 0;
    for (int st = 1; st < 1024; st <<= 1) {
        sc[1 - src][tid] = sc[src][tid] + (tid >= st ? sc[src][tid - st] : 0);
        __syncthreads(); src = 1 - src;
    }
    u32 inc = sc[src][tid], exc = inc - part;
    if (exc < TH && TH <= inc) {
        u32 cum = exc;
        for (int j = 0; j < 64; ++j) {
            u32 c = H[tid * 64 + j];
            if (cum + c >= TH) {
                s_qstar = (meta[sel * 8 + 0] << 16) | (u32)(tid * 64 + j);
                break;
            }
            cum += c;
        }
    }
    __syncthreads();
    if (tid == 0) {
        u32 prefix = s_qstar;
        float qstar = __uint_as_float(prefix);
        float wstar = (float)exp(-(double)qstar);
        u32 lo = 0, hi = prefix;              // smallest qb with exp(-q)==w*
        while (lo < hi) {
            u32 mid = (lo + hi) >> 1;
            float wm = (float)exp(-(double)__uint_as_float(mid));
            if (wm > wstar) lo = mid + 1; else hi = mid;
        }
        meta[sel * 8 + 2] = lo;
        lo = prefix; hi = 0x7F800000u;        // largest qb with exp(-q)==w*
        while (lo < hi) {
            u32 mid = (lo + hi + 1) >> 1;
            float wm = (float)exp(-(double)__uint_as_float(mid));
            if (wm < wstar) hi = mid - 1; else lo = mid;
        }
        meta[sel * 8 + 3] = lo;
        meta[sel * 8 + 4] = __float_as_uint(wstar);
    }
}

// ---------------------------------------------------------------------------
// emit: winners (qb<qlo) -> slots via per-sel counter; ties -> tiebuf.
// ---------------------------------------------------------------------------
__global__ __launch_bounds__(1024) void emit_kernel(
    const float* __restrict__ boxes, const float* __restrict__ scales,
    const float* __restrict__ pdls, const float* __restrict__ pdts,
    u32* __restrict__ meta, int* __restrict__ tiebuf, int* __restrict__ tiecnt,
    int* __restrict__ es, int* __restrict__ ed, float* __restrict__ ewt,
    int* __restrict__ indeg, float* __restrict__ degw)
{
    __shared__ float sv[512]; __shared__ float red[512];
    const int sel = blockIdx.y, b = sel >> 1, t = sel & 1;
    const float tbv = compute_sv_tb(boxes, scales, pdls, pdts, b, t, sv, red);
    const u32 qlo = meta[sel * 8 + 2], qhi = meta[sel * 8 + 3];
    const int base = t * 16384 + b * 4096;
    const int e1 = min((int)(blockIdx.x + 1) * ECHUNK, NE);
    for (int e = blockIdx.x * ECHUNK + threadIdx.x; e < e1; e += 1024) {
        u32 qb; QBITS(e, qb);
        if (qb < qlo) {
            int i = e / 511; int jj = e - i * 511; int j = jj + (jj >= i ? 1 : 0);
            float wval = (float)exp(-(double)__uint_as_float(qb));
            int slot = (int)atomicAdd(&meta[sel * 8 + 5], 1u);
            es[base + slot] = b * 512 + i;
            ed[base + slot] = b * 512 + j;
            ewt[base + slot] = wval;
            atomicAdd(&indeg[t * 2048 + b * 512 + j], 1);
            atomicAdd(&degw[t * 2048 + b * 512 + j], wval);
        } else if (qb <= qhi) {
            int p = atomicAdd(&tiecnt[sel], 1);
            if (p < TIECAP) tiebuf[sel * TIECAP + p] = e;
        }
    }
}

// ---------------------------------------------------------------------------
// tie resolution (index-ascending, r = K - emitted) + indeg scan + dis.
// grid 2 (t), block 1024.
// ---------------------------------------------------------------------------
__global__ __launch_bounds__(1024) void tie_scan_kernel(
    u32* __restrict__ meta, const int* __restrict__ tiebuf, const int* __restrict__ tiecnt,
    int* __restrict__ es, int* __restrict__ ed, float* __restrict__ ewt,
    int* __restrict__ indeg, float* __restrict__ degw,
    int* __restrict__ offs, float* __restrict__ dis)
{
    __shared__ int bufA[2048], bufB[2048];
    const int t = blockIdx.x, tid = threadIdx.x;
    for (int b = 0; b < 4; ++b) {
        int sel = b * 2 + t;
        int m = min(tiecnt[sel], TIECAP);
        int r = KEDGE - (int)meta[sel * 8 + 5];
        float wt = __uint_as_float(meta[sel * 8 + 4]);
        int base = t * 16384 + b * 4096;
        for (int k = tid; k < m; k += 1024) {
            int e = tiebuf[sel * TIECAP + k];
            int rank = 0;
            for (int l = 0; l < m; ++l) rank += (tiebuf[sel * TIECAP + l] < e) ? 1 : 0;
            if (rank < r) {
                int i = e / 511; int jj = e - i * 511; int j = jj + (jj >= i ? 1 : 0);
                int slot = (int)atomicAdd(&meta[sel * 8 + 5], 1u);
                es[base + slot] = b * 512 + i;
                ed[base + slot] = b * 512 + j;
                ewt[base + slot] = wt;
                atomicAdd(&indeg[t * 2048 + b * 512 + j], 1);
                atomicAdd(&degw[t * 2048 + b * 512 + j], wt);
            }
        }
    }
    __threadfence();
    __syncthreads();
    // exclusive scan of indeg over this t's 2048 nodes -> offs; dis = rsqrt(1+degw)
    bufA[tid] = indeg[t * 2048 + tid];
    bufA[tid + 1024] = indeg[t * 2048 + tid + 1024];
    __syncthreads();
    int* src = bufA; int* dst = bufB;
    for (int st = 1; st < 2048; st <<= 1) {
        dst[tid] = src[tid] + (tid >= st ? src[tid - st] : 0);
        int k1 = tid + 1024;
        dst[k1] = src[k1] + (k1 >= st ? src[k1 - st] : 0);
        __syncthreads();
        int* tmp = src; src = dst; dst = tmp;
    }
    offs[t * 2048 + tid] = (tid == 0) ? 0 : src[tid - 1];
    offs[t * 2048 + tid + 1024] = src[tid + 1023];
    dis[t * 2048 + tid] = 1.0f / sqrtf(1.0f + degw[t * 2048 + tid]);
    dis[t * 2048 + tid + 1024] = 1.0f / sqrtf(1.0f + degw[t * 2048 + tid + 1024]);
}

// CSR fill: 32768 edges, global-atomic per-node cursor (fill zeroed by memset)
__global__ void fill_kernel(const int* __restrict__ ed, const int* __restrict__ offs,
                            int* __restrict__ fill, int* __restrict__ csr) {
    int idx = blockIdx.x * 256 + threadIdx.x;
    if (idx >= 32768) return;
    int t = idx >> 14, e = idx & 16383;
    int d = ed[t * 16384 + e] & 2047;
    int pos = offs[t * 2048 + d] + atomicAdd(&fill[t * 2048 + d], 1);
    csr[t * 16384 + pos] = e;
}

// E7: GCN aggregate -> feats f16
__global__ __launch_bounds__(256) void gcn_agg_kernel(
    const float* __restrict__ xw_row, const float* __restrict__ xw_col,
    const float* __restrict__ b_row, const float* __restrict__ b_col,
    const int* __restrict__ es, const float* __restrict__ ew,
    const int* __restrict__ csr, const int* __restrict__ offs,
    const int* __restrict__ indeg, const float* __restrict__ dis,
    _Float16* __restrict__ feat_row, _Float16* __restrict__ feat_col)
{
    int d = blockIdx.x; int t = blockIdx.y;
    const float* xw = t ? xw_col : xw_row;
    const float* bg = t ? b_col : b_row;
    _Float16* out = t ? feat_col : feat_row;
    int f0 = threadIdx.x, f1 = threadIdx.x + 256;
    float dd = dis[t * 2048 + d];
    float a0 = dd * dd * xw[(size_t)d * 512 + f0];
    float a1 = dd * dd * xw[(size_t)d * 512 + f1];
    int st = offs[t * 2048 + d], cnt = indeg[t * 2048 + d];
    for (int k = 0; k < cnt; ++k) {
        int e = csr[t * 16384 + st + k];
        int s = es[t * 16384 + e];
        float w = ew[t * 16384 + e];
        float coef = dis[t * 2048 + s] * w * dd;
        a0 += coef * xw[(size_t)s * 512 + f0];
        a1 += coef * xw[(size_t)s * 512 + f1];
    }
    a0 += bg[f0]; a1 += bg[f1];
    out[(size_t)d * 512 + f0] = (_Float16)fmaxf(a0, 0.f);
    out[(size_t)d * 512 + f1] = (_Float16)fmaxf(a1, 0.f);
}

// ---------------------------------------------------------------------------
extern "C" void kernel_launch(void* const* d_in, const int* in_sizes, int n_in,
                              void* d_out, int out_size, void* d_ws, size_t ws_size,
                              hipStream_t stream)
{
    const float* x      = (const float*)d_in[0];
    const float* boxes  = (const float*)d_in[1];
    const float* scales = (const float*)d_in[2];
    const float* pdls   = (const float*)d_in[3];
    const float* pdts   = (const float*)d_in[4];
    const float* W_dec  = (const float*)d_in[5];
    const float* b_dec  = (const float*)d_in[6];
    const float* W_box  = (const float*)d_in[7];
    const float* b_box  = (const float*)d_in[8];
    const float* W_cnn  = (const float*)d_in[9];
    const float* b_cnn  = (const float*)d_in[10];
    const float* W_grow = (const float*)d_in[11];
    const float* b_grow = (const float*)d_in[12];
    const float* W_gcol = (const float*)d_in[13];
    const float* b_gcol = (const float*)d_in[14];
    const float* W_rcls = (const float*)d_in[15];
    const float* b_rcls = (const float*)d_in[16];
    const float* W_ccls = (const float*)d_in[17];
    const float* b_ccls = (const float*)d_in[18];

    char* ws = (char*)d_ws;
    size_t off = 0;
    auto alloc = [&](size_t bytes) -> void* {
        void* p = ws + off;
        off = (off + bytes + 255) & ~(size_t)255;
        return p;
    };
    _Float16* xf16   = (_Float16*)alloc((size_t)4 * 2304 * 1024 * 2);  // NHWC in
    _Float16* wf16   = (_Float16*)alloc((size_t)256 * 9216 * 2);       // [o][tap][ch]
    _Float16* dec    = (_Float16*)alloc((size_t)4 * 2304 * 256 * 2);   // NHWC
    _Float16* cnn    = (_Float16*)alloc((size_t)2048 * 1024 * 2);
    _Float16* fusion = (_Float16*)alloc((size_t)2048 * 768 * 2);
    _Float16* WcT    = (_Float16*)alloc((size_t)512 * 1024 * 2);
    _Float16* WgrT   = (_Float16*)alloc((size_t)512 * 768 * 2);
    _Float16* WgcT   = (_Float16*)alloc((size_t)512 * 768 * 2);
    _Float16* WrT    = (_Float16*)alloc((size_t)228 * 512 * 2);
    _Float16* WccT   = (_Float16*)alloc((size_t)116 * 512 * 2);
    float* xw        = (float*)alloc((size_t)2097152 * 4);             // xw_row|xw_col
    _Float16* feats  = (_Float16*)alloc((size_t)2 * 2048 * 512 * 2);   // row|col
    int*  es     = (int*)  alloc((size_t)2 * 16384 * 4);
    int*  ed     = (int*)  alloc((size_t)2 * 16384 * 4);
    float* ewt   = (float*)alloc((size_t)2 * 16384 * 4);
    int*  offsA  = (int*)  alloc((size_t)4096 * 4);
    float* dis   = (float*)alloc((size_t)4096 * 4);
    int*  csr    = (int*)  alloc((size_t)2 * 16384 * 4);
    int*  tiebuf = (int*)  alloc((size_t)8 * TIECAP * 4);
    // ---- zero zone (one hipMemsetAsync) ----
    size_t z0 = off;
    u32*  ghistA = (u32*)  alloc((size_t)8 * 65536 * 4);
    u32*  ghistB = (u32*)  alloc((size_t)8 * 65536 * 4);
    u32*  meta   = (u32*)  alloc((size_t)8 * 8 * 4);
    int*  tiecnt = (int*)  alloc((size_t)8 * 4);
    int*  indeg  = (int*)  alloc((size_t)4096 * 4);
    float* degw  = (float*)alloc((size_t)4096 * 4);
    int*  fillA  = (int*)  alloc((size_t)4096 * 4);
    size_t z1 = off;

    float* out = (float*)d_out;

    hipMemsetAsync(ws + z0, 0, z1 - z0, stream);

    cvt_x_kernel<<<dim3(16, 48, 4), 256, 0, stream>>>(x, xf16);
    cvt_w_kernel<<<256, 256, 0, stream>>>(W_dec, wf16);
    conv_f16_kernel<<<dim3(12, 8, 4), 256, 0, stream>>>(xf16, wf16, b_dec, dec);
    roi_kernel<<<2048, 256, 0, stream>>>(dec, boxes, cnn);
    box_kernel<<<2048, 256, 0, stream>>>(boxes, W_box, b_box, fusion);
    // weight transposes (f16 [N][K])
    cvt_t_kernel<<<dim3(16, 32), 256, 0, stream>>>(W_cnn, WcT, 1024, 512);
    cvt_t_kernel<<<dim3(16, 24), 256, 0, stream>>>(W_grow, WgrT, 768, 512);
    cvt_t_kernel<<<dim3(16, 24), 256, 0, stream>>>(W_gcol, WgcT, 768, 512);
    cvt_t_kernel<<<dim3(8, 16), 256, 0, stream>>>(W_rcls, WrT, 512, 228);
    cvt_t_kernel<<<dim3(4, 16), 256, 0, stream>>>(W_ccls, WccT, 512, 116);
    // fusion[:,256:768] = relu(cnn @ W_cnn + b)
    gemm16_kernel<1, _Float16><<<dim3(8, 32), 256, 0, stream>>>(cnn, WcT, b_cnn, fusion + 256, 2048, 512, 1024, 768);
    // edge pipeline: distributed two-level radix select + emit + CSR
    histA_kernel<<<dim3(NCHUNK, 8), 1024, 0, stream>>>(boxes, scales, pdls, pdts, ghistA);
    scanA_kernel<<<8, 1024, 0, stream>>>(ghistA, meta);
    histB_kernel<<<dim3(NCHUNK, 8), 1024, 0, stream>>>(boxes, scales, pdls, pdts, meta, ghistB);
    scanB_kernel<<<8, 1024, 0, stream>>>(ghistB, meta);
    emit_kernel<<<dim3(NCHUNK, 8), 1024, 0, stream>>>(boxes, scales, pdls, pdts, meta,
                                                      tiebuf, tiecnt, es, ed, ewt, indeg, degw);
    tie_scan_kernel<<<2, 1024, 0, stream>>>(meta, tiebuf, tiecnt, es, ed, ewt,
                                            indeg, degw, offsA, dis);
    fill_kernel<<<128, 256, 0, stream>>>(ed, offsA, fillA, csr);
    // xw = fusion @ W_g{row,col} (bias applied in aggregation)
    gemm16_kernel<0, float><<<dim3(8, 32), 256, 0, stream>>>(fusion, WgrT, nullptr, xw, 2048, 512, 768, 512);
    gemm16_kernel<0, float><<<dim3(8, 32), 256, 0, stream>>>(fusion, WgcT, nullptr, xw + 1048576, 2048, 512, 768, 512);
    gcn_agg_kernel<<<dim3(2048, 2), 256, 0, stream>>>(xw, xw + 1048576, b_grow, b_gcol,
                                                      es, ewt, csr, offsA, indeg, dis,
                                                      feats, feats + (size_t)2048 * 512);
    // classifier heads (leaky 0.01) -> fp32 out
    gemm16_kernel<2, float><<<dim3(4, 32), 256, 0, stream>>>(feats, WrT, b_rcls, out, 2048, 228, 512, 228);
    gemm16_kernel<2, float><<<dim3(2, 32), 256, 0, stream>>>(feats + (size_t)2048 * 512, WccT, b_ccls,
                                                             out + (size_t)2048 * 228, 2048, 116, 512, 116);
}

// Round 9
// 518.427 us; speedup vs baseline: 7.5478x; 1.2598x over previous
//
#include <hip/hip_runtime.h>
#include <cstdint>
#include <math.h>

typedef unsigned int u32;
typedef unsigned long long u64;
typedef unsigned short ushort;

typedef __attribute__((ext_vector_type(8))) _Float16 f16x8;
typedef __attribute__((ext_vector_type(4))) _Float16 f16x4;
typedef __attribute__((ext_vector_type(4))) float f32x4;

#define NB    4
#define BnN   2048
#define NE    261632      // 512*511 ordered pairs per batch
#define NCHUNK 16
#define ECHUNK 16352      // NE/16
#define KEDGE 4096
#define TIECAP 2048

// meta[sel*8+i]: 0:p12  1:need1  2:qlo  3:qhi  4:wstar  5:emitcnt  6:prefix24  7:need2
// ---------------------------------------------------------------------------
// convert input: NCHW fp32 -> NHWC f16.  grid (16 chgrp, 48 y, 4 b), block 256
// ---------------------------------------------------------------------------
__global__ __launch_bounds__(256) void cvt_x_kernel(
    const float* __restrict__ in, _Float16* __restrict__ xf)
{
    __shared__ _Float16 sh[64][49];
    int cg = blockIdx.x, y = blockIdx.y, b = blockIdx.z;
    int tid = threadIdx.x;
    for (int i = tid; i < 64 * 48; i += 256) {
        int cl = i / 48, x = i - cl * 48;
        sh[cl][x] = (_Float16)in[(((size_t)b * 1024 + cg * 64 + cl) * 48 + y) * 48 + x];
    }
    __syncthreads();
    for (int i = tid; i < 64 * 48; i += 256) {
        int x = i / 64, cl = i - x * 64;
        xf[((size_t)(b * 48 + y) * 48 + x) * 1024 + cg * 64 + cl] = sh[cl][x];
    }
}

// convert weights: [o][ch][3][3] fp32 -> [o][tap][ch] f16. grid 256, block 256
__global__ __launch_bounds__(256) void cvt_w_kernel(
    const float* __restrict__ W, _Float16* __restrict__ wf)
{
    __shared__ _Float16 sh[9216];
    int o = blockIdx.x, tid = threadIdx.x;
    for (int g = tid; g < 9216; g += 256)
        sh[g] = (_Float16)W[(size_t)o * 9216 + g];     // g = ch*9+tap
    __syncthreads();
    for (int g = tid; g < 9216; g += 256) {
        int tap = g >> 10, ch = g & 1023;
        wf[(size_t)o * 9216 + g] = sh[ch * 9 + tap];
    }
}

// transpose-convert: in fp32 [K][N] -> out f16 [N][K]. grid (ceil(N/32), ceil(K/32))
__global__ __launch_bounds__(256) void cvt_t_kernel(
    const float* __restrict__ in, _Float16* __restrict__ out, int K, int N)
{
    __shared__ _Float16 sh[32][33];
    int n0 = blockIdx.x * 32, k0 = blockIdx.y * 32;
    int tx = threadIdx.x & 31, ty = threadIdx.x >> 5;
#pragma unroll
    for (int i = 0; i < 4; ++i) {
        int k = k0 + ty + i * 8, n = n0 + tx;
        sh[ty + i * 8][tx] = (k < K && n < N) ? (_Float16)in[(size_t)k * N + n] : (_Float16)0.f;
    }
    __syncthreads();
#pragma unroll
    for (int i = 0; i < 4; ++i) {
        int n = n0 + ty + i * 8, k = k0 + tx;
        if (n < N && k < K) out[(size_t)n * K + k] = sh[tx][ty + i * 8];
    }
}

// ---------------------------------------------------------------------------
// conv 3x3 SAME 1024->256 +bias +relu. Implicit-GEMM MFMA f16 (fp32 acc).
// ---------------------------------------------------------------------------
__global__ __launch_bounds__(256) void conv_f16_kernel(
    const _Float16* __restrict__ xf, const _Float16* __restrict__ wf,
    const float* __restrict__ bd, _Float16* __restrict__ dec)
{
    __shared__ _Float16 wS[9][4][32][8];   // 18.4 KB  [tap][q][och][8ch]
    __shared__ _Float16 xS[6][4][50][8];   // 19.2 KB  [row][q][col][8ch]
    const int y0 = blockIdx.x * 4;
    const int og = blockIdx.y;
    const int b  = blockIdx.z;
    const int tid = threadIdx.x;
    const int wv = tid >> 6;
    const int ln = tid & 63;
    const int n  = ln & 15;
    const int q  = ln >> 4;

    f32x4 acc[2][3];
#pragma unroll
    for (int mt = 0; mt < 2; ++mt)
#pragma unroll
        for (int nt = 0; nt < 3; ++nt) acc[mt][nt] = (f32x4){0.f, 0.f, 0.f, 0.f};

    for (int cc = 0; cc < 1024; cc += 32) {
#pragma unroll
        for (int it = 0; it < 5; ++it) {
            int g = it * 256 + tid;
            if (g < 1152) {
                int tap = g >> 7, r = g & 127, qq = r >> 5, oc = r & 31;
                *(uint4*)&wS[tap][qq][oc][0] =
                    *(const uint4*)(wf + ((size_t)(og * 32 + oc) * 9 + tap) * 1024 + cc + qq * 8);
            }
        }
#pragma unroll
        for (int it = 0; it < 5; ++it) {
            int g = it * 256 + tid;
            if (g < 1200) {
                int row = g / 200, r2 = g - row * 200;
                int qq = r2 / 50, c = r2 - qq * 50;
                int gy = y0 + row - 1, gx = c - 1;
                uint4 v = make_uint4(0u, 0u, 0u, 0u);
                if ((unsigned)gy < 48u && (unsigned)gx < 48u)
                    v = *(const uint4*)(xf + ((size_t)(b * 48 + gy) * 48 + gx) * 1024 + cc + qq * 8);
                *(uint4*)&xS[row][qq][c][0] = v;
            }
        }
        __syncthreads();

#pragma unroll
        for (int tap = 0; tap < 9; ++tap) {
            const int dy = tap / 3, dx = tap % 3;
            f16x8 a0 = *(const f16x8*)&wS[tap][q][n][0];
            f16x8 a1 = *(const f16x8*)&wS[tap][q][16 + n][0];
#pragma unroll
            for (int nt = 0; nt < 3; ++nt) {
                f16x8 bb = *(const f16x8*)&xS[wv + dy][q][nt * 16 + n + dx][0];
                acc[0][nt] = __builtin_amdgcn_mfma_f32_16x16x32_f16(a0, bb, acc[0][nt], 0, 0, 0);
                acc[1][nt] = __builtin_amdgcn_mfma_f32_16x16x32_f16(a1, bb, acc[1][nt], 0, 0, 0);
            }
        }
        __syncthreads();
    }

    const int y = y0 + wv;
#pragma unroll
    for (int mt = 0; mt < 2; ++mt) {
        float4 b4 = *(const float4*)(bd + og * 32 + mt * 16 + q * 4);
#pragma unroll
        for (int nt = 0; nt < 3; ++nt) {
            int x = nt * 16 + n;
            f16x4 v;
            v.x = (_Float16)fmaxf(acc[mt][nt][0] + b4.x, 0.f);
            v.y = (_Float16)fmaxf(acc[mt][nt][1] + b4.y, 0.f);
            v.z = (_Float16)fmaxf(acc[mt][nt][2] + b4.z, 0.f);
            v.w = (_Float16)fmaxf(acc[mt][nt][3] + b4.w, 0.f);
            *(f16x4*)(dec + ((size_t)(b * 48 + y) * 48 + x) * 256 + og * 32 + mt * 16 + q * 4) = v;
        }
    }
}

// ---------------------------------------------------------------------------
// ROI align 2x2 on NHWC f16 dec
// ---------------------------------------------------------------------------
__global__ __launch_bounds__(256) void roi_kernel(
    const _Float16* __restrict__ dec, const float* __restrict__ boxes,
    _Float16* __restrict__ cnn)
{
    int n = blockIdx.x; int c = threadIdx.x;
    int b = n >> 9;
    float x1 = boxes[n * 4 + 0], y1 = boxes[n * 4 + 1];
    float x2 = boxes[n * 4 + 2], y2 = boxes[n * 4 + 3];
    float bw = (x2 - x1) * 0.5f, bh = (y2 - y1) * 0.5f;
    float sxv[2] = { x1 + 0.5f * bw, x1 + 1.5f * bw };
    float syv[2] = { y1 + 0.5f * bh, y1 + 1.5f * bh };
    float px[4] = { sxv[0], sxv[1], sxv[0], sxv[1] };
    float py[4] = { syv[0], syv[0], syv[1], syv[1] };
    const _Float16* f = dec + (size_t)b * 2304 * 256;
    f16x4 o4;
    float res[4];
#pragma unroll
    for (int p = 0; p < 4; ++p) {
        float yy = fminf(fmaxf(py[p], 0.f), 47.f);
        float xx = fminf(fmaxf(px[p], 0.f), 47.f);
        int y0 = (int)floorf(yy), x0 = (int)floorf(xx);
        int y1i = min(y0 + 1, 47), x1i = min(x0 + 1, 47);
        float wy = yy - (float)y0, wx = xx - (float)x0;
        float f00 = (float)f[(size_t)(y0 * 48 + x0) * 256 + c];
        float f01 = (float)f[(size_t)(y0 * 48 + x1i) * 256 + c];
        float f10 = (float)f[(size_t)(y1i * 48 + x0) * 256 + c];
        float f11 = (float)f[(size_t)(y1i * 48 + x1i) * 256 + c];
        res[p] = f00 * (1.f - wy) * (1.f - wx) + f01 * (1.f - wy) * wx
               + f10 * wy * (1.f - wx) + f11 * wy * wx;
    }
    o4.x = (_Float16)res[0]; o4.y = (_Float16)res[1];
    o4.z = (_Float16)res[2]; o4.w = (_Float16)res[3];
    *(f16x4*)(cnn + (size_t)n * 1024 + c * 4) = o4;
}

// ---------------------------------------------------------------------------
// box head: fusion[:, 0:256] = relu(bf @ W_box + b_box)
// ---------------------------------------------------------------------------
__global__ __launch_bounds__(256) void box_kernel(
    const float* __restrict__ boxes, const float* __restrict__ Wb,
    const float* __restrict__ bb, _Float16* __restrict__ fusion)
{
    int nrow = blockIdx.x, c = threadIdx.x;
    float x1 = boxes[nrow * 4 + 0], y1 = boxes[nrow * 4 + 1];
    float x2 = boxes[nrow * 4 + 2], y2 = boxes[nrow * 4 + 3];
    float bf0 = ((x1 + x2) * 0.5f) / 48.f;
    float bf1 = ((y1 + y2) * 0.5f) / 48.f;
    float bf2 = (x2 - x1) / 48.f;
    float bf3 = (y2 - y1) / 48.f;
    float acc = bb[c];
    acc += bf0 * Wb[0 * 256 + c];
    acc += bf1 * Wb[1 * 256 + c];
    acc += bf2 * Wb[2 * 256 + c];
    acc += bf3 * Wb[3 * 256 + c];
    fusion[(size_t)nrow * 768 + c] = (_Float16)fmaxf(acc, 0.f);
}

// ---------------------------------------------------------------------------
// f16 MFMA GEMM: C = act(A @ Bt^T + bias). 64x64 tile, 4 waves 2x2.
// ---------------------------------------------------------------------------
template <int ACT, typename OUTT>
__global__ __launch_bounds__(256) void gemm16_kernel(
    const _Float16* __restrict__ A, const _Float16* __restrict__ Bt,
    const float* __restrict__ bias, OUTT* __restrict__ C,
    int M, int N, int K, int ldC)
{
    __shared__ _Float16 aS[64][4][8];
    __shared__ _Float16 bS[64][4][8];
    const int n0 = blockIdx.x * 64, m0 = blockIdx.y * 64;
    const int tid = threadIdx.x;
    const int wv = tid >> 6, ln = tid & 63;
    const int wm = wv & 1, wn = wv >> 1;
    const int lm = ln & 15, lq = ln >> 4;
    const int sr = tid >> 2, sq = tid & 3;

    f32x4 acc[2][2];
#pragma unroll
    for (int i = 0; i < 2; ++i)
#pragma unroll
        for (int j = 0; j < 2; ++j) acc[i][j] = (f32x4){0.f, 0.f, 0.f, 0.f};

    for (int cc = 0; cc < K; cc += 32) {
        *(uint4*)&aS[sr][sq][0] = *(const uint4*)(A + (size_t)(m0 + sr) * K + cc + sq * 8);
        uint4 bv = make_uint4(0u, 0u, 0u, 0u);
        if (n0 + sr < N)
            bv = *(const uint4*)(Bt + (size_t)(n0 + sr) * K + cc + sq * 8);
        *(uint4*)&bS[sr][sq][0] = bv;
        __syncthreads();
        f16x8 af[2], bf[2];
#pragma unroll
        for (int mt = 0; mt < 2; ++mt) af[mt] = *(const f16x8*)&aS[wm * 32 + mt * 16 + lm][lq][0];
#pragma unroll
        for (int nt = 0; nt < 2; ++nt) bf[nt] = *(const f16x8*)&bS[wn * 32 + nt * 16 + lm][lq][0];
#pragma unroll
        for (int mt = 0; mt < 2; ++mt)
#pragma unroll
            for (int nt = 0; nt < 2; ++nt)
                acc[mt][nt] = __builtin_amdgcn_mfma_f32_16x16x32_f16(af[mt], bf[nt], acc[mt][nt], 0, 0, 0);
        __syncthreads();
    }

#pragma unroll
    for (int mt = 0; mt < 2; ++mt) {
#pragma unroll
        for (int nt = 0; nt < 2; ++nt) {
            int col = n0 + wn * 32 + nt * 16 + lm;
            if (col >= N) continue;
            float bs = bias ? bias[col] : 0.f;
#pragma unroll
            for (int r = 0; r < 4; ++r) {
                int row = m0 + wm * 32 + mt * 16 + lq * 4 + r;
                float v = acc[mt][nt][r] + bs;
                if (ACT == 1) v = fmaxf(v, 0.f);
                if (ACT == 2) v = (v >= 0.f) ? v : 0.01f * v;
                C[(size_t)row * ldC + col] = (OUTT)v;
            }
        }
    }
}

// ---------------------------------------------------------------------------
// shared helper: per-sel centers sv[512] (LDS) + table extent tbv.
// Bit-exact reference op order; identical reduce tree in all callers.
// ---------------------------------------------------------------------------
__device__ __forceinline__ float compute_sv_tb(
    const float* __restrict__ boxes, const float* __restrict__ scales,
    const float* __restrict__ pdls, const float* __restrict__ pdts,
    int b, int t, float* sv, float* red)
{
    int tid = threadIdx.x;
    float pdl = pdls[b], pdt = pdts[b], sc = scales[b];
    if (tid < 512) {
        const float* bx = boxes + (size_t)(b * 512 + tid) * 4;
        float o0 = (bx[0] - pdl) / sc;
        float o1 = (bx[1] - pdt) / sc;
        float o2 = (bx[2] - pdl) / sc;
        float o3 = (bx[3] - pdt) / sc;
        sv[tid]  = (t == 0) ? (o1 + o3) * 0.5f : (o0 + o2) * 0.5f;
        red[tid] = (t == 0) ? fmaxf(o1, o3)    : fmaxf(o0, o2);
    }
    __syncthreads();
    for (int s = 256; s > 0; s >>= 1) {
        if (tid < s) red[tid] = fmaxf(red[tid], red[tid + s]);
        __syncthreads();
    }
    float tbv = red[0];
    __syncthreads();
    return tbv;
}

#define QBITS(e, QB)                                                   \
    {                                                                  \
        int i_ = (e) / 511; int jj_ = (e) - i_ * 511;                  \
        int j_ = jj_ + (jj_ >= i_ ? 1 : 0);                            \
        float diff_ = sv[i_] - sv[j_];                                 \
        float u_ = (diff_ * 5.0f) / tbv;                               \
        float q_ = u_ * u_;                                            \
        QB = __float_as_uint(q_);                                      \
    }

// ---------------------------------------------------------------------------
// histA: LDS 4096-bin hist of top-12 q-bits, per-chunk partial (plain stores,
// NO global atomics). grid (16 chunks, 8 sels).
// ---------------------------------------------------------------------------
__global__ __launch_bounds__(1024) void histA_kernel(
    const float* __restrict__ boxes, const float* __restrict__ scales,
    const float* __restrict__ pdls, const float* __restrict__ pdts,
    u32* __restrict__ gpart)
{
    __shared__ float sv[512]; __shared__ float red[512];
    __shared__ u32 lh[4096];
    const int sel = blockIdx.y, b = sel >> 1, t = sel & 1;
    const int tid = threadIdx.x;
    for (int i = tid; i < 4096; i += 1024) lh[i] = 0;
    const float tbv = compute_sv_tb(boxes, scales, pdls, pdts, b, t, sv, red);
    const int e1 = min((int)(blockIdx.x + 1) * ECHUNK, NE);
    for (int e = blockIdx.x * ECHUNK + tid; e < e1; e += 1024) {
        u32 qb; QBITS(e, qb);
        atomicAdd(&lh[qb >> 20], 1u);
    }
    __syncthreads();
    u32* G = gpart + ((size_t)sel * NCHUNK + blockIdx.x) * 4096;
    for (int i = tid; i < 4096; i += 1024) G[i] = lh[i];
}

// scanA: sum partials, block scan over 4096 bins, locate K-th -> p12, need1.
__global__ __launch_bounds__(1024) void scanA_kernel(
    const u32* __restrict__ gpart, u32* __restrict__ meta)
{
    const int sel = blockIdx.x, tid = threadIdx.x;
    __shared__ u32 bins[4096];
    __shared__ u32 sc[2][1024];
    for (int b = tid; b < 4096; b += 1024) {
        u32 s = 0;
        for (int c = 0; c < NCHUNK; ++c) s += gpart[((size_t)sel * NCHUNK + c) * 4096 + b];
        bins[b] = s;
    }
    __syncthreads();
    u32 part = 0;
#pragma unroll
    for (int j = 0; j < 4; ++j) part += bins[tid * 4 + j];
    sc[0][tid] = part;
    __syncthreads();
    int src = 0;
    for (int st = 1; st < 1024; st <<= 1) {
        sc[1 - src][tid] = sc[src][tid] + (tid >= st ? sc[src][tid - st] : 0);
        __syncthreads(); src = 1 - src;
    }
    u32 inc = sc[src][tid], exc = inc - part;
    if (exc < (u32)KEDGE && (u32)KEDGE <= inc) {
        u32 cum = exc;
        for (int j = 0; j < 4; ++j) {
            u32 c = bins[tid * 4 + j];
            if (cum + c >= (u32)KEDGE) {
                meta[sel * 8 + 0] = (u32)(tid * 4 + j);
                meta[sel * 8 + 1] = (u32)KEDGE - cum;
                break;
            }
            cum += c;
        }
    }
}

// histB: among edges with top-12 == p12, LDS hist of bits [19:8].
__global__ __launch_bounds__(1024) void histB_kernel(
    const float* __restrict__ boxes, const float* __restrict__ scales,
    const float* __restrict__ pdls, const float* __restrict__ pdts,
    const u32* __restrict__ meta, u32* __restrict__ gpart)
{
    __shared__ float sv[512]; __shared__ float red[512];
    __shared__ u32 lh[4096];
    const int sel = blockIdx.y, b = sel >> 1, t = sel & 1;
    const int tid = threadIdx.x;
    for (int i = tid; i < 4096; i += 1024) lh[i] = 0;
    const float tbv = compute_sv_tb(boxes, scales, pdls, pdts, b, t, sv, red);
    const u32 p12 = meta[sel * 8 + 0];
    const int e1 = min((int)(blockIdx.x + 1) * ECHUNK, NE);
    for (int e = blockIdx.x * ECHUNK + tid; e < e1; e += 1024) {
        u32 qb; QBITS(e, qb);
        if ((qb >> 20) == p12) atomicAdd(&lh[(qb >> 8) & 0xFFF], 1u);
    }
    __syncthreads();
    u32* G = gpart + ((size_t)sel * NCHUNK + blockIdx.x) * 4096;
    for (int i = tid; i < 4096; i += 1024) G[i] = lh[i];
}

// scanB: locate need1-th within p12 group -> prefix24, need2.
__global__ __launch_bounds__(1024) void scanB_kernel(
    const u32* __restrict__ gpart, u32* __restrict__ meta)
{
    const int sel = blockIdx.x, tid = threadIdx.x;
    const u32 TH = meta[sel * 8 + 1];
    __shared__ u32 bins[4096];
    __shared__ u32 sc[2][1024];
    for (int b = tid; b < 4096; b += 1024) {
        u32 s = 0;
        for (int c = 0; c < NCHUNK; ++c) s += gpart[((size_t)sel * NCHUNK + c) * 4096 + b];
        bins[b] = s;
    }
    __syncthreads();
    u32 part = 0;
#pragma unroll
    for (int j = 0; j < 4; ++j) part += bins[tid * 4 + j];
    sc[0][tid] = part;
    __syncthreads();
    int src = 0;
    for (int st = 1; st < 1024; st <<= 1) {
        sc[1 - src][tid] = sc[src][tid] + (tid >= st ? sc[src][tid - st] : 0);
        __syncthreads(); src = 1 - src;
    }
    u32 inc = sc[src][tid], exc = inc - part;
    if (exc < TH && TH <= inc) {
        u32 cum = exc;
        for (int j = 0; j < 4; ++j) {
            u32 c = bins[tid * 4 + j];
            if (cum + c >= TH) {
                meta[sel * 8 + 6] = (meta[sel * 8 + 0] << 12) | (u32)(tid * 4 + j);
                meta[sel * 8 + 7] = TH - cum;
                break;
            }
            cum += c;
        }
    }
}

// histC: among edges with top-24 == prefix24, LDS hist of low 8 bits.
__global__ __launch_bounds__(1024) void histC_kernel(
    const float* __restrict__ boxes, const float* __restrict__ scales,
    const float* __restrict__ pdls, const float* __restrict__ pdts,
    const u32* __restrict__ meta, u32* __restrict__ gpart)
{
    __shared__ float sv[512]; __shared__ float red[512];
    __shared__ u32 lh[256];
    const int sel = blockIdx.y, b = sel >> 1, t = sel & 1;
    const int tid = threadIdx.x;
    if (tid < 256) lh[tid] = 0;
    const float tbv = compute_sv_tb(boxes, scales, pdls, pdts, b, t, sv, red);
    const u32 p24 = meta[sel * 8 + 6];
    const int e1 = min((int)(blockIdx.x + 1) * ECHUNK, NE);
    for (int e = blockIdx.x * ECHUNK + tid; e < e1; e += 1024) {
        u32 qb; QBITS(e, qb);
        if ((qb >> 8) == p24) atomicAdd(&lh[qb & 0xFF], 1u);
    }
    __syncthreads();
    u32* G = gpart + ((size_t)sel * NCHUNK + blockIdx.x) * 256;
    if (tid < 256) G[tid] = lh[tid];
}

// scanC: exact q*, then binary-search the w*-tie q-interval [qlo,qhi].
__global__ __launch_bounds__(256) void scanC_kernel(
    const u32* __restrict__ gpart, u32* __restrict__ meta)
{
    const int sel = blockIdx.x, tid = threadIdx.x;
    const u32 TH = meta[sel * 8 + 7];
    __shared__ u32 bins[256];
    __shared__ u32 sc[2][256];
    __shared__ u32 s_qstar;
    u32 s = 0;
    for (int c = 0; c < NCHUNK; ++c) s += gpart[((size_t)sel * NCHUNK + c) * 256 + tid];
    bins[tid] = s;
    sc[0][tid] = s;
    __syncthreads();
    int src = 0;
    for (int st = 1; st < 256; st <<= 1) {
        sc[1 - src][tid] = sc[src][tid] + (tid >= st ? sc[src][tid - st] : 0);
        __syncthreads(); src = 1 - src;
    }
    u32 inc = sc[src][tid], exc = inc - bins[tid];
    if (exc < TH && TH <= inc)
        s_qstar = (meta[sel * 8 + 6] << 8) | (u32)tid;
    __syncthreads();
    if (tid == 0) {
        u32 prefix = s_qstar;
        float qstar = __uint_as_float(prefix);
        float wstar = (float)exp(-(double)qstar);
        u32 lo = 0, hi = prefix;              // smallest qb with exp(-q)==w*
        while (lo < hi) {
            u32 mid = (lo + hi) >> 1;
            float wm = (float)exp(-(double)__uint_as_float(mid));
            if (wm > wstar) lo = mid + 1; else hi = mid;
        }
        meta[sel * 8 + 2] = lo;
        lo = prefix; hi = 0x7F800000u;        // largest qb with exp(-q)==w*
        while (lo < hi) {
            u32 mid = (lo + hi + 1) >> 1;
            float wm = (float)exp(-(double)__uint_as_float(mid));
            if (wm < wstar) hi = mid - 1; else lo = mid;
        }
        meta[sel * 8 + 3] = lo;
        meta[sel * 8 + 4] = __float_as_uint(wstar);
    }
}

// ---------------------------------------------------------------------------
// emit: winners (qb<qlo) -> slots via per-sel counter; ties -> tiebuf.
// ---------------------------------------------------------------------------
__global__ __launch_bounds__(1024) void emit_kernel(
    const float* __restrict__ boxes, const float* __restrict__ scales,
    const float* __restrict__ pdls, const float* __restrict__ pdts,
    u32* __restrict__ meta, int* __restrict__ tiebuf, int* __restrict__ tiecnt,
    int* __restrict__ es, int* __restrict__ ed, float* __restrict__ ewt,
    int* __restrict__ indeg, float* __restrict__ degw)
{
    __shared__ float sv[512]; __shared__ float red[512];
    const int sel = blockIdx.y, b = sel >> 1, t = sel & 1;
    const float tbv = compute_sv_tb(boxes, scales, pdls, pdts, b, t, sv, red);
    const u32 qlo = meta[sel * 8 + 2], qhi = meta[sel * 8 + 3];
    const int base = t * 16384 + b * 4096;
    const int e1 = min((int)(blockIdx.x + 1) * ECHUNK, NE);
    for (int e = blockIdx.x * ECHUNK + threadIdx.x; e < e1; e += 1024) {
        u32 qb; QBITS(e, qb);
        if (qb < qlo) {
            int i = e / 511; int jj = e - i * 511; int j = jj + (jj >= i ? 1 : 0);
            float wval = (float)exp(-(double)__uint_as_float(qb));
            int slot = (int)atomicAdd(&meta[sel * 8 + 5], 1u);
            es[base + slot] = b * 512 + i;
            ed[base + slot] = b * 512 + j;
            ewt[base + slot] = wval;
            atomicAdd(&indeg[t * 2048 + b * 512 + j], 1);
            atomicAdd(&degw[t * 2048 + b * 512 + j], wval);
        } else if (qb <= qhi) {
            int p = atomicAdd(&tiecnt[sel], 1);
            if (p < TIECAP) tiebuf[sel * TIECAP + p] = e;
        }
    }
}

// ---------------------------------------------------------------------------
// tie resolution (index-ascending, r = K - emitted) + indeg scan + dis.
// ---------------------------------------------------------------------------
__global__ __launch_bounds__(1024) void tie_scan_kernel(
    u32* __restrict__ meta, const int* __restrict__ tiebuf, const int* __restrict__ tiecnt,
    int* __restrict__ es, int* __restrict__ ed, float* __restrict__ ewt,
    int* __restrict__ indeg, float* __restrict__ degw,
    int* __restrict__ offs, float* __restrict__ dis)
{
    __shared__ int bufA[2048], bufB[2048];
    const int t = blockIdx.x, tid = threadIdx.x;
    for (int b = 0; b < 4; ++b) {
        int sel = b * 2 + t;
        int m = min(tiecnt[sel], TIECAP);
        int r = KEDGE - (int)meta[sel * 8 + 5];
        float wt = __uint_as_float(meta[sel * 8 + 4]);
        int base = t * 16384 + b * 4096;
        for (int k = tid; k < m; k += 1024) {
            int e = tiebuf[sel * TIECAP + k];
            int rank = 0;
            for (int l = 0; l < m; ++l) rank += (tiebuf[sel * TIECAP + l] < e) ? 1 : 0;
            if (rank < r) {
                int i = e / 511; int jj = e - i * 511; int j = jj + (jj >= i ? 1 : 0);
                int slot = (int)atomicAdd(&meta[sel * 8 + 5], 1u);
                es[base + slot] = b * 512 + i;
                ed[base + slot] = b * 512 + j;
                ewt[base + slot] = wt;
                atomicAdd(&indeg[t * 2048 + b * 512 + j], 1);
                atomicAdd(&degw[t * 2048 + b * 512 + j], wt);
            }
        }
    }
    __threadfence();
    __syncthreads();
    bufA[tid] = indeg[t * 2048 + tid];
    bufA[tid + 1024] = indeg[t * 2048 + tid + 1024];
    __syncthreads();
    int* src = bufA; int* dst = bufB;
    for (int st = 1; st < 2048; st <<= 1) {
        dst[tid] = src[tid] + (tid >= st ? src[tid - st] : 0);
        int k1 = tid + 1024;
        dst[k1] = src[k1] + (k1 >= st ? src[k1 - st] : 0);
        __syncthreads();
        int* tmp = src; src = dst; dst = tmp;
    }
    offs[t * 2048 + tid] = (tid == 0) ? 0 : src[tid - 1];
    offs[t * 2048 + tid + 1024] = src[tid + 1023];
    dis[t * 2048 + tid] = 1.0f / sqrtf(1.0f + degw[t * 2048 + tid]);
    dis[t * 2048 + tid + 1024] = 1.0f / sqrtf(1.0f + degw[t * 2048 + tid + 1024]);
}

// CSR fill
__global__ void fill_kernel(const int* __restrict__ ed, const int* __restrict__ offs,
                            int* __restrict__ fill, int* __restrict__ csr) {
    int idx = blockIdx.x * 256 + threadIdx.x;
    if (idx >= 32768) return;
    int t = idx >> 14, e = idx & 16383;
    int d = ed[t * 16384 + e] & 2047;
    int pos = offs[t * 2048 + d] + atomicAdd(&fill[t * 2048 + d], 1);
    csr[t * 16384 + pos] = e;
}

// E7: GCN aggregate -> feats f16
__global__ __launch_bounds__(256) void gcn_agg_kernel(
    const float* __restrict__ xw_row, const float* __restrict__ xw_col,
    const float* __restrict__ b_row, const float* __restrict__ b_col,
    const int* __restrict__ es, const float* __restrict__ ew,
    const int* __restrict__ csr, const int* __restrict__ offs,
    const int* __restrict__ indeg, const float* __restrict__ dis,
    _Float16* __restrict__ feat_row, _Float16* __restrict__ feat_col)
{
    int d = blockIdx.x; int t = blockIdx.y;
    const float* xw = t ? xw_col : xw_row;
    const float* bg = t ? b_col : b_row;
    _Float16* out = t ? feat_col : feat_row;
    int f0 = threadIdx.x, f1 = threadIdx.x + 256;
    float dd = dis[t * 2048 + d];
    float a0 = dd * dd * xw[(size_t)d * 512 + f0];
    float a1 = dd * dd * xw[(size_t)d * 512 + f1];
    int st = offs[t * 2048 + d], cnt = indeg[t * 2048 + d];
    for (int k = 0; k < cnt; ++k) {
        int e = csr[t * 16384 + st + k];
        int s = es[t * 16384 + e];
        float w = ew[t * 16384 + e];
        float coef = dis[t * 2048 + s] * w * dd;
        a0 += coef * xw[(size_t)s * 512 + f0];
        a1 += coef * xw[(size_t)s * 512 + f1];
    }
    a0 += bg[f0]; a1 += bg[f1];
    out[(size_t)d * 512 + f0] = (_Float16)fmaxf(a0, 0.f);
    out[(size_t)d * 512 + f1] = (_Float16)fmaxf(a1, 0.f);
}

// ---------------------------------------------------------------------------
extern "C" void kernel_launch(void* const* d_in, const int* in_sizes, int n_in,
                              void* d_out, int out_size, void* d_ws, size_t ws_size,
                              hipStream_t stream)
{
    const float* x      = (const float*)d_in[0];
    const float* boxes  = (const float*)d_in[1];
    const float* scales = (const float*)d_in[2];
    const float* pdls   = (const float*)d_in[3];
    const float* pdts   = (const float*)d_in[4];
    const float* W_dec  = (const float*)d_in[5];
    const float* b_dec  = (const float*)d_in[6];
    const float* W_box  = (const float*)d_in[7];
    const float* b_box  = (const float*)d_in[8];
    const float* W_cnn  = (const float*)d_in[9];
    const float* b_cnn  = (const float*)d_in[10];
    const float* W_grow = (const float*)d_in[11];
    const float* b_grow = (const float*)d_in[12];
    const float* W_gcol = (const float*)d_in[13];
    const float* b_gcol = (const float*)d_in[14];
    const float* W_rcls = (const float*)d_in[15];
    const float* b_rcls = (const float*)d_in[16];
    const float* W_ccls = (const float*)d_in[17];
    const float* b_ccls = (const float*)d_in[18];

    char* ws = (char*)d_ws;
    size_t off = 0;
    auto alloc = [&](size_t bytes) -> void* {
        void* p = ws + off;
        off = (off + bytes + 255) & ~(size_t)255;
        return p;
    };
    _Float16* xf16   = (_Float16*)alloc((size_t)4 * 2304 * 1024 * 2);  // NHWC in
    _Float16* wf16   = (_Float16*)alloc((size_t)256 * 9216 * 2);       // [o][tap][ch]
    _Float16* dec    = (_Float16*)alloc((size_t)4 * 2304 * 256 * 2);   // NHWC
    _Float16* cnn    = (_Float16*)alloc((size_t)2048 * 1024 * 2);
    _Float16* fusion = (_Float16*)alloc((size_t)2048 * 768 * 2);
    _Float16* WcT    = (_Float16*)alloc((size_t)512 * 1024 * 2);
    _Float16* WgrT   = (_Float16*)alloc((size_t)512 * 768 * 2);
    _Float16* WgcT   = (_Float16*)alloc((size_t)512 * 768 * 2);
    _Float16* WrT    = (_Float16*)alloc((size_t)228 * 512 * 2);
    _Float16* WccT   = (_Float16*)alloc((size_t)116 * 512 * 2);
    float* xw        = (float*)alloc((size_t)2097152 * 4);             // xw_row|xw_col
    _Float16* feats  = (_Float16*)alloc((size_t)2 * 2048 * 512 * 2);   // row|col
    int*  es     = (int*)  alloc((size_t)2 * 16384 * 4);
    int*  ed     = (int*)  alloc((size_t)2 * 16384 * 4);
    float* ewt   = (float*)alloc((size_t)2 * 16384 * 4);
    int*  offsA  = (int*)  alloc((size_t)4096 * 4);
    float* dis   = (float*)alloc((size_t)4096 * 4);
    int*  csr    = (int*)  alloc((size_t)2 * 16384 * 4);
    int*  tiebuf = (int*)  alloc((size_t)8 * TIECAP * 4);
    u32*  gpartA = (u32*)  alloc((size_t)8 * NCHUNK * 4096 * 4);   // fully overwritten
    u32*  gpartB = (u32*)  alloc((size_t)8 * NCHUNK * 4096 * 4);
    u32*  gpartC = (u32*)  alloc((size_t)8 * NCHUNK * 256 * 4);
    // ---- zero zone (one hipMemsetAsync) ----
    size_t z0 = off;
    u32*  meta   = (u32*)  alloc((size_t)8 * 8 * 4);
    int*  tiecnt = (int*)  alloc((size_t)8 * 4);
    int*  indeg  = (int*)  alloc((size_t)4096 * 4);
    float* degw  = (float*)alloc((size_t)4096 * 4);
    int*  fillA  = (int*)  alloc((size_t)4096 * 4);
    size_t z1 = off;

    float* out = (float*)d_out;

    hipMemsetAsync(ws + z0, 0, z1 - z0, stream);

    cvt_x_kernel<<<dim3(16, 48, 4), 256, 0, stream>>>(x, xf16);
    cvt_w_kernel<<<256, 256, 0, stream>>>(W_dec, wf16);
    conv_f16_kernel<<<dim3(12, 8, 4), 256, 0, stream>>>(xf16, wf16, b_dec, dec);
    roi_kernel<<<2048, 256, 0, stream>>>(dec, boxes, cnn);
    box_kernel<<<2048, 256, 0, stream>>>(boxes, W_box, b_box, fusion);
    // weight transposes (f16 [N][K])
    cvt_t_kernel<<<dim3(16, 32), 256, 0, stream>>>(W_cnn, WcT, 1024, 512);
    cvt_t_kernel<<<dim3(16, 24), 256, 0, stream>>>(W_grow, WgrT, 768, 512);
    cvt_t_kernel<<<dim3(16, 24), 256, 0, stream>>>(W_gcol, WgcT, 768, 512);
    cvt_t_kernel<<<dim3(8, 16), 256, 0, stream>>>(W_rcls, WrT, 512, 228);
    cvt_t_kernel<<<dim3(4, 16), 256, 0, stream>>>(W_ccls, WccT, 512, 116);
    // fusion[:,256:768] = relu(cnn @ W_cnn + b)
    gemm16_kernel<1, _Float16><<<dim3(8, 32), 256, 0, stream>>>(cnn, WcT, b_cnn, fusion + 256, 2048, 512, 1024, 768);
    // edge pipeline: 12+12+8 LDS-privatized radix select + emit + CSR
    histA_kernel<<<dim3(NCHUNK, 8), 1024, 0, stream>>>(boxes, scales, pdls, pdts, gpartA);
    scanA_kernel<<<8, 1024, 0, stream>>>(gpartA, meta);
    histB_kernel<<<dim3(NCHUNK, 8), 1024, 0, stream>>>(boxes, scales, pdls, pdts, meta, gpartB);
    scanB_kernel<<<8, 1024, 0, stream>>>(gpartB, meta);
    histC_kernel<<<dim3(NCHUNK, 8), 1024, 0, stream>>>(boxes, scales, pdls, pdts, meta, gpartC);
    scanC_kernel<<<8, 256, 0, stream>>>(gpartC, meta);
    emit_kernel<<<dim3(NCHUNK, 8), 1024, 0, stream>>>(boxes, scales, pdls, pdts, meta,
                                                      tiebuf, tiecnt, es, ed, ewt, indeg, degw);
    tie_scan_kernel<<<2, 1024, 0, stream>>>(meta, tiebuf, tiecnt, es, ed, ewt,
                                            indeg, degw, offsA, dis);
    fill_kernel<<<128, 256, 0, stream>>>(ed, offsA, fillA, csr);
    // xw = fusion @ W_g{row,col} (bias applied in aggregation)
    gemm16_kernel<0, float><<<dim3(8, 32), 256, 0, stream>>>(fusion, WgrT, nullptr, xw, 2048, 512, 768, 512);
    gemm16_kernel<0, float><<<dim3(8, 32), 256, 0, stream>>>(fusion, WgcT, nullptr, xw + 1048576, 2048, 512, 768, 512);
    gcn_agg_kernel<<<dim3(2048, 2), 256, 0, stream>>>(xw, xw + 1048576, b_grow, b_gcol,
                                                      es, ewt, csr, offsA, indeg, dis,
                                                      feats, feats + (size_t)2048 * 512);
    // classifier heads (leaky 0.01) -> fp32 out
    gemm16_kernel<2, float><<<dim3(4, 32), 256, 0, stream>>>(feats, WrT, b_rcls, out, 2048, 228, 512, 228);
    gemm16_kernel<2, float><<<dim3(2, 32), 256, 0, stream>>>(feats + (size_t)2048 * 512, WccT, b_ccls,
                                                             out + (size_t)2048 * 228, 2048, 116, 512, 116);
}

// Round 10
// 474.420 us; speedup vs baseline: 8.2480x; 1.0928x over previous
//
#include <hip/hip_runtime.h>
#include <cstdint>
#include <math.h>

typedef unsigned int u32;
typedef unsigned long long u64;
typedef unsigned short ushort;

typedef __attribute__((ext_vector_type(8))) _Float16 f16x8;
typedef __attribute__((ext_vector_type(4))) _Float16 f16x4;
typedef __attribute__((ext_vector_type(4))) float f32x4;

#define NB    4
#define BnN   2048
#define NE    261632      // 512*511 ordered pairs per batch
#define NCHUNK 16
#define ECHUNK 16352      // NE/16
#define KEDGE 4096
#define TIECAP 2048
#define PSLICE 2359296    // 4*2304*256 elements per K-slice partial

// meta[sel*8+i]: 0:p12  1:need1  2:qlo  3:qhi  4:wstar  5:emitcnt  6:prefix24  7:need2
// ---------------------------------------------------------------------------
// convert input: NCHW fp32 -> NHWC f16.  grid (16 chgrp, 48 y, 4 b), block 256
// ---------------------------------------------------------------------------
__global__ __launch_bounds__(256) void cvt_x_kernel(
    const float* __restrict__ in, _Float16* __restrict__ xf)
{
    __shared__ _Float16 sh[64][49];
    int cg = blockIdx.x, y = blockIdx.y, b = blockIdx.z;
    int tid = threadIdx.x;
    for (int i = tid; i < 64 * 48; i += 256) {
        int cl = i / 48, x = i - cl * 48;
        sh[cl][x] = (_Float16)in[(((size_t)b * 1024 + cg * 64 + cl) * 48 + y) * 48 + x];
    }
    __syncthreads();
    for (int i = tid; i < 64 * 48; i += 256) {
        int x = i / 64, cl = i - x * 64;
        xf[((size_t)(b * 48 + y) * 48 + x) * 1024 + cg * 64 + cl] = sh[cl][x];
    }
}

// convert weights: [o][ch][3][3] fp32 -> [o][tap][ch] f16. grid 256, block 256
__global__ __launch_bounds__(256) void cvt_w_kernel(
    const float* __restrict__ W, _Float16* __restrict__ wf)
{
    __shared__ _Float16 sh[9216];
    int o = blockIdx.x, tid = threadIdx.x;
    for (int g = tid; g < 9216; g += 256)
        sh[g] = (_Float16)W[(size_t)o * 9216 + g];     // g = ch*9+tap
    __syncthreads();
    for (int g = tid; g < 9216; g += 256) {
        int tap = g >> 10, ch = g & 1023;
        wf[(size_t)o * 9216 + g] = sh[ch * 9 + tap];
    }
}

// transpose-convert: in fp32 [K][N] -> out f16 [N][K]. grid (ceil(N/32), ceil(K/32))
__global__ __launch_bounds__(256) void cvt_t_kernel(
    const float* __restrict__ in, _Float16* __restrict__ out, int K, int N)
{
    __shared__ _Float16 sh[32][33];
    int n0 = blockIdx.x * 32, k0 = blockIdx.y * 32;
    int tx = threadIdx.x & 31, ty = threadIdx.x >> 5;
#pragma unroll
    for (int i = 0; i < 4; ++i) {
        int k = k0 + ty + i * 8, n = n0 + tx;
        sh[ty + i * 8][tx] = (k < K && n < N) ? (_Float16)in[(size_t)k * N + n] : (_Float16)0.f;
    }
    __syncthreads();
#pragma unroll
    for (int i = 0; i < 4; ++i) {
        int n = n0 + ty + i * 8, k = k0 + tx;
        if (n < N && k < K) out[(size_t)n * K + k] = sh[tx][ty + i * 8];
    }
}

// ---------------------------------------------------------------------------
// conv 3x3 SAME 1024->256, split-K(2) partials. Implicit-GEMM MFMA f16.
// Block 256 thr (4 waves): 32 och x 4 rows, wave = 1 row.
// grid (12 ygroup, 8 og, 8 = b*2+kslice). Each block: K = 512 ch.
// ---------------------------------------------------------------------------
__global__ __launch_bounds__(256) void conv_part_kernel(
    const _Float16* __restrict__ xf, const _Float16* __restrict__ wf,
    float* __restrict__ pbuf)
{
    __shared__ _Float16 wS[9][4][32][8];   // 18.4 KB  [tap][q][och][8ch]
    __shared__ _Float16 xS[6][4][50][8];   // 19.2 KB  [row][q][col][8ch]
    const int y0 = blockIdx.x * 4;
    const int og = blockIdx.y;
    const int bz = blockIdx.z;
    const int b  = bz >> 1, kb = bz & 1;
    const int tid = threadIdx.x;
    const int wv = tid >> 6;
    const int ln = tid & 63;
    const int n  = ln & 15;
    const int q  = ln >> 4;

    f32x4 acc[2][3];
#pragma unroll
    for (int mt = 0; mt < 2; ++mt)
#pragma unroll
        for (int nt = 0; nt < 3; ++nt) acc[mt][nt] = (f32x4){0.f, 0.f, 0.f, 0.f};

    const int c0 = kb * 512;
    for (int cc = c0; cc < c0 + 512; cc += 32) {
#pragma unroll
        for (int it = 0; it < 5; ++it) {
            int g = it * 256 + tid;
            if (g < 1152) {
                int tap = g >> 7, r = g & 127, qq = r >> 5, oc = r & 31;
                *(uint4*)&wS[tap][qq][oc][0] =
                    *(const uint4*)(wf + ((size_t)(og * 32 + oc) * 9 + tap) * 1024 + cc + qq * 8);
            }
        }
#pragma unroll
        for (int it = 0; it < 5; ++it) {
            int g = it * 256 + tid;
            if (g < 1200) {
                int row = g / 200, r2 = g - row * 200;
                int qq = r2 / 50, c = r2 - qq * 50;
                int gy = y0 + row - 1, gx = c - 1;
                uint4 v = make_uint4(0u, 0u, 0u, 0u);
                if ((unsigned)gy < 48u && (unsigned)gx < 48u)
                    v = *(const uint4*)(xf + ((size_t)(b * 48 + gy) * 48 + gx) * 1024 + cc + qq * 8);
                *(uint4*)&xS[row][qq][c][0] = v;
            }
        }
        __syncthreads();

#pragma unroll
        for (int tap = 0; tap < 9; ++tap) {
            const int dy = tap / 3, dx = tap % 3;
            f16x8 a0 = *(const f16x8*)&wS[tap][q][n][0];
            f16x8 a1 = *(const f16x8*)&wS[tap][q][16 + n][0];
#pragma unroll
            for (int nt = 0; nt < 3; ++nt) {
                f16x8 bb = *(const f16x8*)&xS[wv + dy][q][nt * 16 + n + dx][0];
                acc[0][nt] = __builtin_amdgcn_mfma_f32_16x16x32_f16(a0, bb, acc[0][nt], 0, 0, 0);
                acc[1][nt] = __builtin_amdgcn_mfma_f32_16x16x32_f16(a1, bb, acc[1][nt], 0, 0, 0);
            }
        }
        __syncthreads();
    }

    const int y = y0 + wv;
#pragma unroll
    for (int mt = 0; mt < 2; ++mt) {
#pragma unroll
        for (int nt = 0; nt < 3; ++nt) {
            int x = nt * 16 + n;
            *(f32x4*)(pbuf + (size_t)kb * PSLICE +
                      ((size_t)(b * 48 + y) * 48 + x) * 256 + og * 32 + mt * 16 + q * 4) = acc[mt][nt];
        }
    }
}

// sum partials + bias + relu -> dec NHWC f16. grid 2304 x 256.
__global__ __launch_bounds__(256) void conv_sum_kernel(
    const float* __restrict__ pbuf, const float* __restrict__ bd,
    _Float16* __restrict__ dec)
{
    size_t idx = (size_t)blockIdx.x * 256 + threadIdx.x;   // 589824 threads
    size_t e = idx * 4;
    int och = (int)(e & 255);
    f32x4 s0 = *(const f32x4*)(pbuf + e);
    f32x4 s1 = *(const f32x4*)(pbuf + (size_t)PSLICE + e);
    float4 b4 = *(const float4*)(bd + och);
    f16x4 v;
    v.x = (_Float16)fmaxf(s0[0] + s1[0] + b4.x, 0.f);
    v.y = (_Float16)fmaxf(s0[1] + s1[1] + b4.y, 0.f);
    v.z = (_Float16)fmaxf(s0[2] + s1[2] + b4.z, 0.f);
    v.w = (_Float16)fmaxf(s0[3] + s1[3] + b4.w, 0.f);
    *(f16x4*)(dec + e) = v;
}

// ---------------------------------------------------------------------------
// ROI align 2x2 on NHWC f16 dec
// ---------------------------------------------------------------------------
__global__ __launch_bounds__(256) void roi_kernel(
    const _Float16* __restrict__ dec, const float* __restrict__ boxes,
    _Float16* __restrict__ cnn)
{
    int n = blockIdx.x; int c = threadIdx.x;
    int b = n >> 9;
    float x1 = boxes[n * 4 + 0], y1 = boxes[n * 4 + 1];
    float x2 = boxes[n * 4 + 2], y2 = boxes[n * 4 + 3];
    float bw = (x2 - x1) * 0.5f, bh = (y2 - y1) * 0.5f;
    float sxv[2] = { x1 + 0.5f * bw, x1 + 1.5f * bw };
    float syv[2] = { y1 + 0.5f * bh, y1 + 1.5f * bh };
    float px[4] = { sxv[0], sxv[1], sxv[0], sxv[1] };
    float py[4] = { syv[0], syv[0], syv[1], syv[1] };
    const _Float16* f = dec + (size_t)b * 2304 * 256;
    f16x4 o4;
    float res[4];
#pragma unroll
    for (int p = 0; p < 4; ++p) {
        float yy = fminf(fmaxf(py[p], 0.f), 47.f);
        float xx = fminf(fmaxf(px[p], 0.f), 47.f);
        int y0 = (int)floorf(yy), x0 = (int)floorf(xx);
        int y1i = min(y0 + 1, 47), x1i = min(x0 + 1, 47);
        float wy = yy - (float)y0, wx = xx - (float)x0;
        float f00 = (float)f[(size_t)(y0 * 48 + x0) * 256 + c];
        float f01 = (float)f[(size_t)(y0 * 48 + x1i) * 256 + c];
        float f10 = (float)f[(size_t)(y1i * 48 + x0) * 256 + c];
        float f11 = (float)f[(size_t)(y1i * 48 + x1i) * 256 + c];
        res[p] = f00 * (1.f - wy) * (1.f - wx) + f01 * (1.f - wy) * wx
               + f10 * wy * (1.f - wx) + f11 * wy * wx;
    }
    o4.x = (_Float16)res[0]; o4.y = (_Float16)res[1];
    o4.z = (_Float16)res[2]; o4.w = (_Float16)res[3];
    *(f16x4*)(cnn + (size_t)n * 1024 + c * 4) = o4;
}

// ---------------------------------------------------------------------------
// box head: fusion[:, 0:256] = relu(bf @ W_box + b_box)
// ---------------------------------------------------------------------------
__global__ __launch_bounds__(256) void box_kernel(
    const float* __restrict__ boxes, const float* __restrict__ Wb,
    const float* __restrict__ bb, _Float16* __restrict__ fusion)
{
    int nrow = blockIdx.x, c = threadIdx.x;
    float x1 = boxes[nrow * 4 + 0], y1 = boxes[nrow * 4 + 1];
    float x2 = boxes[nrow * 4 + 2], y2 = boxes[nrow * 4 + 3];
    float bf0 = ((x1 + x2) * 0.5f) / 48.f;
    float bf1 = ((y1 + y2) * 0.5f) / 48.f;
    float bf2 = (x2 - x1) / 48.f;
    float bf3 = (y2 - y1) / 48.f;
    float acc = bb[c];
    acc += bf0 * Wb[0 * 256 + c];
    acc += bf1 * Wb[1 * 256 + c];
    acc += bf2 * Wb[2 * 256 + c];
    acc += bf3 * Wb[3 * 256 + c];
    fusion[(size_t)nrow * 768 + c] = (_Float16)fmaxf(acc, 0.f);
}

// ---------------------------------------------------------------------------
// f16 MFMA GEMM: C = act(A @ Bt^T + bias). 64x64 tile, 4 waves 2x2.
// ---------------------------------------------------------------------------
template <int ACT, typename OUTT>
__global__ __launch_bounds__(256) void gemm16_kernel(
    const _Float16* __restrict__ A, const _Float16* __restrict__ Bt,
    const float* __restrict__ bias, OUTT* __restrict__ C,
    int M, int N, int K, int ldC)
{
    __shared__ _Float16 aS[64][4][8];
    __shared__ _Float16 bS[64][4][8];
    const int n0 = blockIdx.x * 64, m0 = blockIdx.y * 64;
    const int tid = threadIdx.x;
    const int wv = tid >> 6, ln = tid & 63;
    const int wm = wv & 1, wn = wv >> 1;
    const int lm = ln & 15, lq = ln >> 4;
    const int sr = tid >> 2, sq = tid & 3;

    f32x4 acc[2][2];
#pragma unroll
    for (int i = 0; i < 2; ++i)
#pragma unroll
        for (int j = 0; j < 2; ++j) acc[i][j] = (f32x4){0.f, 0.f, 0.f, 0.f};

    for (int cc = 0; cc < K; cc += 32) {
        *(uint4*)&aS[sr][sq][0] = *(const uint4*)(A + (size_t)(m0 + sr) * K + cc + sq * 8);
        uint4 bv = make_uint4(0u, 0u, 0u, 0u);
        if (n0 + sr < N)
            bv = *(const uint4*)(Bt + (size_t)(n0 + sr) * K + cc + sq * 8);
        *(uint4*)&bS[sr][sq][0] = bv;
        __syncthreads();
        f16x8 af[2], bf[2];
#pragma unroll
        for (int mt = 0; mt < 2; ++mt) af[mt] = *(const f16x8*)&aS[wm * 32 + mt * 16 + lm][lq][0];
#pragma unroll
        for (int nt = 0; nt < 2; ++nt) bf[nt] = *(const f16x8*)&bS[wn * 32 + nt * 16 + lm][lq][0];
#pragma unroll
        for (int mt = 0; mt < 2; ++mt)
#pragma unroll
            for (int nt = 0; nt < 2; ++nt)
                acc[mt][nt] = __builtin_amdgcn_mfma_f32_16x16x32_f16(af[mt], bf[nt], acc[mt][nt], 0, 0, 0);
        __syncthreads();
    }

#pragma unroll
    for (int mt = 0; mt < 2; ++mt) {
#pragma unroll
        for (int nt = 0; nt < 2; ++nt) {
            int col = n0 + wn * 32 + nt * 16 + lm;
            if (col >= N) continue;
            float bs = bias ? bias[col] : 0.f;
#pragma unroll
            for (int r = 0; r < 4; ++r) {
                int row = m0 + wm * 32 + mt * 16 + lq * 4 + r;
                float v = acc[mt][nt][r] + bs;
                if (ACT == 1) v = fmaxf(v, 0.f);
                if (ACT == 2) v = (v >= 0.f) ? v : 0.01f * v;
                C[(size_t)row * ldC + col] = (OUTT)v;
            }
        }
    }
}

// dual-B variant: grid.z selects (Bt, C). ACT=0, float out, no bias.
__global__ __launch_bounds__(256) void gemm16z_kernel(
    const _Float16* __restrict__ A,
    const _Float16* __restrict__ Bt0, const _Float16* __restrict__ Bt1,
    float* __restrict__ C0, float* __restrict__ C1,
    int M, int N, int K, int ldC)
{
    const _Float16* __restrict__ Bt = blockIdx.z ? Bt1 : Bt0;
    float* __restrict__ C = blockIdx.z ? C1 : C0;
    __shared__ _Float16 aS[64][4][8];
    __shared__ _Float16 bS[64][4][8];
    const int n0 = blockIdx.x * 64, m0 = blockIdx.y * 64;
    const int tid = threadIdx.x;
    const int wv = tid >> 6, ln = tid & 63;
    const int wm = wv & 1, wn = wv >> 1;
    const int lm = ln & 15, lq = ln >> 4;
    const int sr = tid >> 2, sq = tid & 3;

    f32x4 acc[2][2];
#pragma unroll
    for (int i = 0; i < 2; ++i)
#pragma unroll
        for (int j = 0; j < 2; ++j) acc[i][j] = (f32x4){0.f, 0.f, 0.f, 0.f};

    for (int cc = 0; cc < K; cc += 32) {
        *(uint4*)&aS[sr][sq][0] = *(const uint4*)(A + (size_t)(m0 + sr) * K + cc + sq * 8);
        uint4 bv = make_uint4(0u, 0u, 0u, 0u);
        if (n0 + sr < N)
            bv = *(const uint4*)(Bt + (size_t)(n0 + sr) * K + cc + sq * 8);
        *(uint4*)&bS[sr][sq][0] = bv;
        __syncthreads();
        f16x8 af[2], bf[2];
#pragma unroll
        for (int mt = 0; mt < 2; ++mt) af[mt] = *(const f16x8*)&aS[wm * 32 + mt * 16 + lm][lq][0];
#pragma unroll
        for (int nt = 0; nt < 2; ++nt) bf[nt] = *(const f16x8*)&bS[wn * 32 + nt * 16 + lm][lq][0];
#pragma unroll
        for (int mt = 0; mt < 2; ++mt)
#pragma unroll
            for (int nt = 0; nt < 2; ++nt)
                acc[mt][nt] = __builtin_amdgcn_mfma_f32_16x16x32_f16(af[mt], bf[nt], acc[mt][nt], 0, 0, 0);
        __syncthreads();
    }

#pragma unroll
    for (int mt = 0; mt < 2; ++mt) {
#pragma unroll
        for (int nt = 0; nt < 2; ++nt) {
            int col = n0 + wn * 32 + nt * 16 + lm;
            if (col >= N) continue;
#pragma unroll
            for (int r = 0; r < 4; ++r) {
                int row = m0 + wm * 32 + mt * 16 + lq * 4 + r;
                C[(size_t)row * ldC + col] = acc[mt][nt][r];
            }
        }
    }
}

// ---------------------------------------------------------------------------
// shared helper: per-sel centers sv[512] (LDS) + table extent tbv.
// ---------------------------------------------------------------------------
__device__ __forceinline__ float compute_sv_tb(
    const float* __restrict__ boxes, const float* __restrict__ scales,
    const float* __restrict__ pdls, const float* __restrict__ pdts,
    int b, int t, float* sv, float* red)
{
    int tid = threadIdx.x;
    float pdl = pdls[b], pdt = pdts[b], sc = scales[b];
    if (tid < 512) {
        const float* bx = boxes + (size_t)(b * 512 + tid) * 4;
        float o0 = (bx[0] - pdl) / sc;
        float o1 = (bx[1] - pdt) / sc;
        float o2 = (bx[2] - pdl) / sc;
        float o3 = (bx[3] - pdt) / sc;
        sv[tid]  = (t == 0) ? (o1 + o3) * 0.5f : (o0 + o2) * 0.5f;
        red[tid] = (t == 0) ? fmaxf(o1, o3)    : fmaxf(o0, o2);
    }
    __syncthreads();
    for (int s = 256; s > 0; s >>= 1) {
        if (tid < s) red[tid] = fmaxf(red[tid], red[tid + s]);
        __syncthreads();
    }
    float tbv = red[0];
    __syncthreads();
    return tbv;
}

#define QBITS(e, QB)                                                   \
    {                                                                  \
        int i_ = (e) / 511; int jj_ = (e) - i_ * 511;                  \
        int j_ = jj_ + (jj_ >= i_ ? 1 : 0);                            \
        float diff_ = sv[i_] - sv[j_];                                 \
        float u_ = (diff_ * 5.0f) / tbv;                               \
        float q_ = u_ * u_;                                            \
        QB = __float_as_uint(q_);                                      \
    }

// ---------------------------------------------------------------------------
// histA: LDS 4096-bin hist of top-12 q-bits, per-chunk partial.
// ---------------------------------------------------------------------------
__global__ __launch_bounds__(1024) void histA_kernel(
    const float* __restrict__ boxes, const float* __restrict__ scales,
    const float* __restrict__ pdls, const float* __restrict__ pdts,
    u32* __restrict__ gpart)
{
    __shared__ float sv[512]; __shared__ float red[512];
    __shared__ u32 lh[4096];
    const int sel = blockIdx.y, b = sel >> 1, t = sel & 1;
    const int tid = threadIdx.x;
    for (int i = tid; i < 4096; i += 1024) lh[i] = 0;
    const float tbv = compute_sv_tb(boxes, scales, pdls, pdts, b, t, sv, red);
    const int e1 = min((int)(blockIdx.x + 1) * ECHUNK, NE);
    for (int e = blockIdx.x * ECHUNK + tid; e < e1; e += 1024) {
        u32 qb; QBITS(e, qb);
        atomicAdd(&lh[qb >> 20], 1u);
    }
    __syncthreads();
    u32* G = gpart + ((size_t)sel * NCHUNK + blockIdx.x) * 4096;
    for (int i = tid; i < 4096; i += 1024) G[i] = lh[i];
}

// scanA: sum partials, block scan over 4096 bins, locate K-th -> p12, need1.
__global__ __launch_bounds__(1024) void scanA_kernel(
    const u32* __restrict__ gpart, u32* __restrict__ meta)
{
    const int sel = blockIdx.x, tid = threadIdx.x;
    __shared__ u32 bins[4096];
    __shared__ u32 sc[2][1024];
    for (int b = tid; b < 4096; b += 1024) {
        u32 s = 0;
        for (int c = 0; c < NCHUNK; ++c) s += gpart[((size_t)sel * NCHUNK + c) * 4096 + b];
        bins[b] = s;
    }
    __syncthreads();
    u32 part = 0;
#pragma unroll
    for (int j = 0; j < 4; ++j) part += bins[tid * 4 + j];
    sc[0][tid] = part;
    __syncthreads();
    int src = 0;
    for (int st = 1; st < 1024; st <<= 1) {
        sc[1 - src][tid] = sc[src][tid] + (tid >= st ? sc[src][tid - st] : 0);
        __syncthreads(); src = 1 - src;
    }
    u32 inc = sc[src][tid], exc = inc - part;
    if (exc < (u32)KEDGE && (u32)KEDGE <= inc) {
        u32 cum = exc;
        for (int j = 0; j < 4; ++j) {
            u32 c = bins[tid * 4 + j];
            if (cum + c >= (u32)KEDGE) {
                meta[sel * 8 + 0] = (u32)(tid * 4 + j);
                meta[sel * 8 + 1] = (u32)KEDGE - cum;
                break;
            }
            cum += c;
        }
    }
}

// histB: among edges with top-12 == p12, LDS hist of bits [19:8].
__global__ __launch_bounds__(1024) void histB_kernel(
    const float* __restrict__ boxes, const float* __restrict__ scales,
    const float* __restrict__ pdls, const float* __restrict__ pdts,
    const u32* __restrict__ meta, u32* __restrict__ gpart)
{
    __shared__ float sv[512]; __shared__ float red[512];
    __shared__ u32 lh[4096];
    const int sel = blockIdx.y, b = sel >> 1, t = sel & 1;
    const int tid = threadIdx.x;
    for (int i = tid; i < 4096; i += 1024) lh[i] = 0;
    const float tbv = compute_sv_tb(boxes, scales, pdls, pdts, b, t, sv, red);
    const u32 p12 = meta[sel * 8 + 0];
    const int e1 = min((int)(blockIdx.x + 1) * ECHUNK, NE);
    for (int e = blockIdx.x * ECHUNK + tid; e < e1; e += 1024) {
        u32 qb; QBITS(e, qb);
        if ((qb >> 20) == p12) atomicAdd(&lh[(qb >> 8) & 0xFFF], 1u);
    }
    __syncthreads();
    u32* G = gpart + ((size_t)sel * NCHUNK + blockIdx.x) * 4096;
    for (int i = tid; i < 4096; i += 1024) G[i] = lh[i];
}

// scanB: locate need1-th within p12 group -> prefix24, need2.
__global__ __launch_bounds__(1024) void scanB_kernel(
    const u32* __restrict__ gpart, u32* __restrict__ meta)
{
    const int sel = blockIdx.x, tid = threadIdx.x;
    const u32 TH = meta[sel * 8 + 1];
    __shared__ u32 bins[4096];
    __shared__ u32 sc[2][1024];
    for (int b = tid; b < 4096; b += 1024) {
        u32 s = 0;
        for (int c = 0; c < NCHUNK; ++c) s += gpart[((size_t)sel * NCHUNK + c) * 4096 + b];
        bins[b] = s;
    }
    __syncthreads();
    u32 part = 0;
#pragma unroll
    for (int j = 0; j < 4; ++j) part += bins[tid * 4 + j];
    sc[0][tid] = part;
    __syncthreads();
    int src = 0;
    for (int st = 1; st < 1024; st <<= 1) {
        sc[1 - src][tid] = sc[src][tid] + (tid >= st ? sc[src][tid - st] : 0);
        __syncthreads(); src = 1 - src;
    }
    u32 inc = sc[src][tid], exc = inc - part;
    if (exc < TH && TH <= inc) {
        u32 cum = exc;
        for (int j = 0; j < 4; ++j) {
            u32 c = bins[tid * 4 + j];
            if (cum + c >= TH) {
                meta[sel * 8 + 6] = (meta[sel * 8 + 0] << 12) | (u32)(tid * 4 + j);
                meta[sel * 8 + 7] = TH - cum;
                break;
            }
            cum += c;
        }
    }
}

// histC: among edges with top-24 == prefix24, LDS hist of low 8 bits.
__global__ __launch_bounds__(1024) void histC_kernel(
    const float* __restrict__ boxes, const float* __restrict__ scales,
    const float* __restrict__ pdls, const float* __restrict__ pdts,
    const u32* __restrict__ meta, u32* __restrict__ gpart)
{
    __shared__ float sv[512]; __shared__ float red[512];
    __shared__ u32 lh[256];
    const int sel = blockIdx.y, b = sel >> 1, t = sel & 1;
    const int tid = threadIdx.x;
    if (tid < 256) lh[tid] = 0;
    const float tbv = compute_sv_tb(boxes, scales, pdls, pdts, b, t, sv, red);
    const u32 p24 = meta[sel * 8 + 6];
    const int e1 = min((int)(blockIdx.x + 1) * ECHUNK, NE);
    for (int e = blockIdx.x * ECHUNK + tid; e < e1; e += 1024) {
        u32 qb; QBITS(e, qb);
        if ((qb >> 8) == p24) atomicAdd(&lh[qb & 0xFF], 1u);
    }
    __syncthreads();
    u32* G = gpart + ((size_t)sel * NCHUNK + blockIdx.x) * 256;
    if (tid < 256) G[tid] = lh[tid];
}

// scanC: exact q*, then binary-search the w*-tie q-interval [qlo,qhi].
__global__ __launch_bounds__(256) void scanC_kernel(
    const u32* __restrict__ gpart, u32* __restrict__ meta)
{
    const int sel = blockIdx.x, tid = threadIdx.x;
    const u32 TH = meta[sel * 8 + 7];
    __shared__ u32 bins[256];
    __shared__ u32 sc[2][256];
    __shared__ u32 s_qstar;
    u32 s = 0;
    for (int c = 0; c < NCHUNK; ++c) s += gpart[((size_t)sel * NCHUNK + c) * 256 + tid];
    bins[tid] = s;
    sc[0][tid] = s;
    __syncthreads();
    int src = 0;
    for (int st = 1; st < 256; st <<= 1) {
        sc[1 - src][tid] = sc[src][tid] + (tid >= st ? sc[src][tid - st] : 0);
        __syncthreads(); src = 1 - src;
    }
    u32 inc = sc[src][tid], exc = inc - bins[tid];
    if (exc < TH && TH <= inc)
        s_qstar = (meta[sel * 8 + 6] << 8) | (u32)tid;
    __syncthreads();
    if (tid == 0) {
        u32 prefix = s_qstar;
        float qstar = __uint_as_float(prefix);
        float wstar = (float)exp(-(double)qstar);
        u32 lo = 0, hi = prefix;              // smallest qb with exp(-q)==w*
        while (lo < hi) {
            u32 mid = (lo + hi) >> 1;
            float wm = (float)exp(-(double)__uint_as_float(mid));
            if (wm > wstar) lo = mid + 1; else hi = mid;
        }
        meta[sel * 8 + 2] = lo;
        lo = prefix; hi = 0x7F800000u;        // largest qb with exp(-q)==w*
        while (lo < hi) {
            u32 mid = (lo + hi + 1) >> 1;
            float wm = (float)exp(-(double)__uint_as_float(mid));
            if (wm < wstar) hi = mid - 1; else lo = mid;
        }
        meta[sel * 8 + 3] = lo;
        meta[sel * 8 + 4] = __float_as_uint(wstar);
    }
}

// ---------------------------------------------------------------------------
// emit: winners (qb<qlo) -> slots via per-sel counter; ties -> tiebuf.
// ---------------------------------------------------------------------------
__global__ __launch_bounds__(1024) void emit_kernel(
    const float* __restrict__ boxes, const float* __restrict__ scales,
    const float* __restrict__ pdls, const float* __restrict__ pdts,
    u32* __restrict__ meta, int* __restrict__ tiebuf, int* __restrict__ tiecnt,
    int* __restrict__ es, int* __restrict__ ed, float* __restrict__ ewt,
    int* __restrict__ indeg, float* __restrict__ degw)
{
    __shared__ float sv[512]; __shared__ float red[512];
    const int sel = blockIdx.y, b = sel >> 1, t = sel & 1;
    const float tbv = compute_sv_tb(boxes, scales, pdls, pdts, b, t, sv, red);
    const u32 qlo = meta[sel * 8 + 2], qhi = meta[sel * 8 + 3];
    const int base = t * 16384 + b * 4096;
    const int e1 = min((int)(blockIdx.x + 1) * ECHUNK, NE);
    for (int e = blockIdx.x * ECHUNK + threadIdx.x; e < e1; e += 1024) {
        u32 qb; QBITS(e, qb);
        if (qb < qlo) {
            int i = e / 511; int jj = e - i * 511; int j = jj + (jj >= i ? 1 : 0);
            float wval = (float)exp(-(double)__uint_as_float(qb));
            int slot = (int)atomicAdd(&meta[sel * 8 + 5], 1u);
            es[base + slot] = b * 512 + i;
            ed[base + slot] = b * 512 + j;
            ewt[base + slot] = wval;
            atomicAdd(&indeg[t * 2048 + b * 512 + j], 1);
            atomicAdd(&degw[t * 2048 + b * 512 + j], wval);
        } else if (qb <= qhi) {
            int p = atomicAdd(&tiecnt[sel], 1);
            if (p < TIECAP) tiebuf[sel * TIECAP + p] = e;
        }
    }
}

// ---------------------------------------------------------------------------
// tie resolution (index-ascending, r = K - emitted) + indeg scan + dis.
// ---------------------------------------------------------------------------
__global__ __launch_bounds__(1024) void tie_scan_kernel(
    u32* __restrict__ meta, const int* __restrict__ tiebuf, const int* __restrict__ tiecnt,
    int* __restrict__ es, int* __restrict__ ed, float* __restrict__ ewt,
    int* __restrict__ indeg, float* __restrict__ degw,
    int* __restrict__ offs, float* __restrict__ dis)
{
    __shared__ int bufA[2048], bufB[2048];
    const int t = blockIdx.x, tid = threadIdx.x;
    for (int b = 0; b < 4; ++b) {
        int sel = b * 2 + t;
        int m = min(tiecnt[sel], TIECAP);
        int r = KEDGE - (int)meta[sel * 8 + 5];
        float wt = __uint_as_float(meta[sel * 8 + 4]);
        int base = t * 16384 + b * 4096;
        for (int k = tid; k < m; k += 1024) {
            int e = tiebuf[sel * TIECAP + k];
            int rank = 0;
            for (int l = 0; l < m; ++l) rank += (tiebuf[sel * TIECAP + l] < e) ? 1 : 0;
            if (rank < r) {
                int i = e / 511; int jj = e - i * 511; int j = jj + (jj >= i ? 1 : 0);
                int slot = (int)atomicAdd(&meta[sel * 8 + 5], 1u);
                es[base + slot] = b * 512 + i;
                ed[base + slot] = b * 512 + j;
                ewt[base + slot] = wt;
                atomicAdd(&indeg[t * 2048 + b * 512 + j], 1);
                atomicAdd(&degw[t * 2048 + b * 512 + j], wt);
            }
        }
    }
    __threadfence();
    __syncthreads();
    bufA[tid] = indeg[t * 2048 + tid];
    bufA[tid + 1024] = indeg[t * 2048 + tid + 1024];
    __syncthreads();
    int* src = bufA; int* dst = bufB;
    for (int st = 1; st < 2048; st <<= 1) {
        dst[tid] = src[tid] + (tid >= st ? src[tid - st] : 0);
        int k1 = tid + 1024;
        dst[k1] = src[k1] + (k1 >= st ? src[k1 - st] : 0);
        __syncthreads();
        int* tmp = src; src = dst; dst = tmp;
    }
    offs[t * 2048 + tid] = (tid == 0) ? 0 : src[tid - 1];
    offs[t * 2048 + tid + 1024] = src[tid + 1023];
    dis[t * 2048 + tid] = 1.0f / sqrtf(1.0f + degw[t * 2048 + tid]);
    dis[t * 2048 + tid + 1024] = 1.0f / sqrtf(1.0f + degw[t * 2048 + tid + 1024]);
}

// CSR fill
__global__ void fill_kernel(const int* __restrict__ ed, const int* __restrict__ offs,
                            int* __restrict__ fill, int* __restrict__ csr) {
    int idx = blockIdx.x * 256 + threadIdx.x;
    if (idx >= 32768) return;
    int t = idx >> 14, e = idx & 16383;
    int d = ed[t * 16384 + e] & 2047;
    int pos = offs[t * 2048 + d] + atomicAdd(&fill[t * 2048 + d], 1);
    csr[t * 16384 + pos] = e;
}

// E7: GCN aggregate -> feats f16
__global__ __launch_bounds__(256) void gcn_agg_kernel(
    const float* __restrict__ xw_row, const float* __restrict__ xw_col,
    const float* __restrict__ b_row, const float* __restrict__ b_col,
    const int* __restrict__ es, const float* __restrict__ ew,
    const int* __restrict__ csr, const int* __restrict__ offs,
    const int* __restrict__ indeg, const float* __restrict__ dis,
    _Float16* __restrict__ feat_row, _Float16* __restrict__ feat_col)
{
    int d = blockIdx.x; int t = blockIdx.y;
    const float* xw = t ? xw_col : xw_row;
    const float* bg = t ? b_col : b_row;
    _Float16* out = t ? feat_col : feat_row;
    int f0 = threadIdx.x, f1 = threadIdx.x + 256;
    float dd = dis[t * 2048 + d];
    float a0 = dd * dd * xw[(size_t)d * 512 + f0];
    float a1 = dd * dd * xw[(size_t)d * 512 + f1];
    int st = offs[t * 2048 + d], cnt = indeg[t * 2048 + d];
    for (int k = 0; k < cnt; ++k) {
        int e = csr[t * 16384 + st + k];
        int s = es[t * 16384 + e];
        float w = ew[t * 16384 + e];
        float coef = dis[t * 2048 + s] * w * dd;
        a0 += coef * xw[(size_t)s * 512 + f0];
        a1 += coef * xw[(size_t)s * 512 + f1];
    }
    a0 += bg[f0]; a1 += bg[f1];
    out[(size_t)d * 512 + f0] = (_Float16)fmaxf(a0, 0.f);
    out[(size_t)d * 512 + f1] = (_Float16)fmaxf(a1, 0.f);
}

// ---------------------------------------------------------------------------
extern "C" void kernel_launch(void* const* d_in, const int* in_sizes, int n_in,
                              void* d_out, int out_size, void* d_ws, size_t ws_size,
                              hipStream_t stream)
{
    const float* x      = (const float*)d_in[0];
    const float* boxes  = (const float*)d_in[1];
    const float* scales = (const float*)d_in[2];
    const float* pdls   = (const float*)d_in[3];
    const float* pdts   = (const float*)d_in[4];
    const float* W_dec  = (const float*)d_in[5];
    const float* b_dec  = (const float*)d_in[6];
    const float* W_box  = (const float*)d_in[7];
    const float* b_box  = (const float*)d_in[8];
    const float* W_cnn  = (const float*)d_in[9];
    const float* b_cnn  = (const float*)d_in[10];
    const float* W_grow = (const float*)d_in[11];
    const float* b_grow = (const float*)d_in[12];
    const float* W_gcol = (const float*)d_in[13];
    const float* b_gcol = (const float*)d_in[14];
    const float* W_rcls = (const float*)d_in[15];
    const float* b_rcls = (const float*)d_in[16];
    const float* W_ccls = (const float*)d_in[17];
    const float* b_ccls = (const float*)d_in[18];

    char* ws = (char*)d_ws;
    size_t off = 0;
    auto alloc = [&](size_t bytes) -> void* {
        void* p = ws + off;
        off = (off + bytes + 255) & ~(size_t)255;
        return p;
    };
    _Float16* xf16   = (_Float16*)alloc((size_t)4 * 2304 * 1024 * 2);  // NHWC in
    _Float16* wf16   = (_Float16*)alloc((size_t)256 * 9216 * 2);       // [o][tap][ch]
    _Float16* dec    = (_Float16*)alloc((size_t)4 * 2304 * 256 * 2);   // NHWC
    float*    pbuf   = (float*)   alloc((size_t)2 * PSLICE * 4);       // split-K partials
    _Float16* cnn    = (_Float16*)alloc((size_t)2048 * 1024 * 2);
    _Float16* fusion = (_Float16*)alloc((size_t)2048 * 768 * 2);
    _Float16* WcT    = (_Float16*)alloc((size_t)512 * 1024 * 2);
    _Float16* WgrT   = (_Float16*)alloc((size_t)512 * 768 * 2);
    _Float16* WgcT   = (_Float16*)alloc((size_t)512 * 768 * 2);
    _Float16* WrT    = (_Float16*)alloc((size_t)228 * 512 * 2);
    _Float16* WccT   = (_Float16*)alloc((size_t)116 * 512 * 2);
    float* xw        = (float*)alloc((size_t)2097152 * 4);             // xw_row|xw_col
    _Float16* feats  = (_Float16*)alloc((size_t)2 * 2048 * 512 * 2);   // row|col
    int*  es     = (int*)  alloc((size_t)2 * 16384 * 4);
    int*  ed     = (int*)  alloc((size_t)2 * 16384 * 4);
    float* ewt   = (float*)alloc((size_t)2 * 16384 * 4);
    int*  offsA  = (int*)  alloc((size_t)4096 * 4);
    float* dis   = (float*)alloc((size_t)4096 * 4);
    int*  csr    = (int*)  alloc((size_t)2 * 16384 * 4);
    int*  tiebuf = (int*)  alloc((size_t)8 * TIECAP * 4);
    u32*  gpartA = (u32*)  alloc((size_t)8 * NCHUNK * 4096 * 4);   // fully overwritten
    u32*  gpartB = (u32*)  alloc((size_t)8 * NCHUNK * 4096 * 4);
    u32*  gpartC = (u32*)  alloc((size_t)8 * NCHUNK * 256 * 4);
    // ---- zero zone (one hipMemsetAsync) ----
    size_t z0 = off;
    u32*  meta   = (u32*)  alloc((size_t)8 * 8 * 4);
    int*  tiecnt = (int*)  alloc((size_t)8 * 4);
    int*  indeg  = (int*)  alloc((size_t)4096 * 4);
    float* degw  = (float*)alloc((size_t)4096 * 4);
    int*  fillA  = (int*)  alloc((size_t)4096 * 4);
    size_t z1 = off;

    float* out = (float*)d_out;

    hipMemsetAsync(ws + z0, 0, z1 - z0, stream);

    cvt_x_kernel<<<dim3(16, 48, 4), 256, 0, stream>>>(x, xf16);
    cvt_w_kernel<<<256, 256, 0, stream>>>(W_dec, wf16);
    conv_part_kernel<<<dim3(12, 8, 8), 256, 0, stream>>>(xf16, wf16, pbuf);
    conv_sum_kernel<<<2304, 256, 0, stream>>>(pbuf, b_dec, dec);
    roi_kernel<<<2048, 256, 0, stream>>>(dec, boxes, cnn);
    box_kernel<<<2048, 256, 0, stream>>>(boxes, W_box, b_box, fusion);
    // weight transposes (f16 [N][K])
    cvt_t_kernel<<<dim3(16, 32), 256, 0, stream>>>(W_cnn, WcT, 1024, 512);
    cvt_t_kernel<<<dim3(16, 24), 256, 0, stream>>>(W_grow, WgrT, 768, 512);
    cvt_t_kernel<<<dim3(16, 24), 256, 0, stream>>>(W_gcol, WgcT, 768, 512);
    cvt_t_kernel<<<dim3(8, 16), 256, 0, stream>>>(W_rcls, WrT, 512, 228);
    cvt_t_kernel<<<dim3(4, 16), 256, 0, stream>>>(W_ccls, WccT, 512, 116);
    // fusion[:,256:768] = relu(cnn @ W_cnn + b)
    gemm16_kernel<1, _Float16><<<dim3(8, 32), 256, 0, stream>>>(cnn, WcT, b_cnn, fusion + 256, 2048, 512, 1024, 768);
    // edge pipeline: 12+12+8 LDS-privatized radix select + emit + CSR
    histA_kernel<<<dim3(NCHUNK, 8), 1024, 0, stream>>>(boxes, scales, pdls, pdts, gpartA);
    scanA_kernel<<<8, 1024, 0, stream>>>(gpartA, meta);
    histB_kernel<<<dim3(NCHUNK, 8), 1024, 0, stream>>>(boxes, scales, pdls, pdts, meta, gpartB);
    scanB_kernel<<<8, 1024, 0, stream>>>(gpartB, meta);
    histC_kernel<<<dim3(NCHUNK, 8), 1024, 0, stream>>>(boxes, scales, pdls, pdts, meta, gpartC);
    scanC_kernel<<<8, 256, 0, stream>>>(gpartC, meta);
    emit_kernel<<<dim3(NCHUNK, 8), 1024, 0, stream>>>(boxes, scales, pdls, pdts, meta,
                                                      tiebuf, tiecnt, es, ed, ewt, indeg, degw);
    tie_scan_kernel<<<2, 1024, 0, stream>>>(meta, tiebuf, tiecnt, es, ed, ewt,
                                            indeg, degw, offsA, dis);
    fill_kernel<<<128, 256, 0, stream>>>(ed, offsA, fillA, csr);
    // xw = fusion @ W_g{row,col} (bias applied in aggregation) — one dual launch
    gemm16z_kernel<<<dim3(8, 32, 2), 256, 0, stream>>>(fusion, WgrT, WgcT, xw, xw + 1048576,
                                                       2048, 512, 768, 512);
    gcn_agg_kernel<<<dim3(2048, 2), 256, 0, stream>>>(xw, xw + 1048576, b_grow, b_gcol,
                                                      es, ewt, csr, offsA, indeg, dis,
                                                      feats, feats + (size_t)2048 * 512);
    // classifier heads (leaky 0.01) -> fp32 out
    gemm16_kernel<2, float><<<dim3(4, 32), 256, 0, stream>>>(feats, WrT, b_rcls, out, 2048, 228, 512, 228);
    gemm16_kernel<2, float><<<dim3(2, 32), 256, 0, stream>>>(feats + (size_t)2048 * 512, WccT, b_ccls,
                                                             out + (size_t)2048 * 228, 2048, 116, 512, 116);
}

// Round 11
// 389.750 us; speedup vs baseline: 10.0397x; 1.2172x over previous
//
#include <hip/hip_runtime.h>
#include <cstdint>
#include <math.h>

typedef unsigned int u32;
typedef unsigned long long u64;
typedef unsigned short ushort;

typedef __attribute__((ext_vector_type(8))) _Float16 f16x8;
typedef __attribute__((ext_vector_type(4))) _Float16 f16x4;
typedef __attribute__((ext_vector_type(4))) float f32x4;

#define NB    4
#define BnN   2048
#define NE    261632      // 512*511 ordered pairs per batch
#define NCHUNK 16
#define ECHUNK 16352      // NE/16
#define KEDGE 4096
#define TIECAP 2048
#define PSLICE 2359296    // 4*2304*256 elements per K-slice partial
#define MS    64          // meta stride (u32) per sel -> 256B, own cache lines
#define TS    64          // tiecnt stride (int) per sel

// meta[sel*MS+i]: 0:p12  1:need1  2:qlo  3:qhi  4:wstar  5:emitcnt  6:prefix24  7:need2
// ---------------------------------------------------------------------------
// convert input: NCHW fp32 -> NHWC f16.  grid (16 chgrp, 48 y, 4 b), block 256
// ---------------------------------------------------------------------------
__global__ __launch_bounds__(256) void cvt_x_kernel(
    const float* __restrict__ in, _Float16* __restrict__ xf)
{
    __shared__ _Float16 sh[64][49];
    int cg = blockIdx.x, y = blockIdx.y, b = blockIdx.z;
    int tid = threadIdx.x;
    for (int i = tid; i < 64 * 48; i += 256) {
        int cl = i / 48, x = i - cl * 48;
        sh[cl][x] = (_Float16)in[(((size_t)b * 1024 + cg * 64 + cl) * 48 + y) * 48 + x];
    }
    __syncthreads();
    for (int i = tid; i < 64 * 48; i += 256) {
        int x = i / 64, cl = i - x * 64;
        xf[((size_t)(b * 48 + y) * 48 + x) * 1024 + cg * 64 + cl] = sh[cl][x];
    }
}

// convert weights: [o][ch][3][3] fp32 -> [o][tap][ch] f16. grid 256, block 256
__global__ __launch_bounds__(256) void cvt_w_kernel(
    const float* __restrict__ W, _Float16* __restrict__ wf)
{
    __shared__ _Float16 sh[9216];
    int o = blockIdx.x, tid = threadIdx.x;
    for (int g = tid; g < 9216; g += 256)
        sh[g] = (_Float16)W[(size_t)o * 9216 + g];     // g = ch*9+tap
    __syncthreads();
    for (int g = tid; g < 9216; g += 256) {
        int tap = g >> 10, ch = g & 1023;
        wf[(size_t)o * 9216 + g] = sh[ch * 9 + tap];
    }
}

// transpose-convert: in fp32 [K][N] -> out f16 [N][K]. grid (ceil(N/32), ceil(K/32))
__global__ __launch_bounds__(256) void cvt_t_kernel(
    const float* __restrict__ in, _Float16* __restrict__ out, int K, int N)
{
    __shared__ _Float16 sh[32][33];
    int n0 = blockIdx.x * 32, k0 = blockIdx.y * 32;
    int tx = threadIdx.x & 31, ty = threadIdx.x >> 5;
#pragma unroll
    for (int i = 0; i < 4; ++i) {
        int k = k0 + ty + i * 8, n = n0 + tx;
        sh[ty + i * 8][tx] = (k < K && n < N) ? (_Float16)in[(size_t)k * N + n] : (_Float16)0.f;
    }
    __syncthreads();
#pragma unroll
    for (int i = 0; i < 4; ++i) {
        int n = n0 + ty + i * 8, k = k0 + tx;
        if (n < N && k < K) out[(size_t)n * K + k] = sh[tx][ty + i * 8];
    }
}

// ---------------------------------------------------------------------------
// conv 3x3 SAME 1024->256, split-K(2) partials. Implicit-GEMM MFMA f16.
// ---------------------------------------------------------------------------
__global__ __launch_bounds__(256) void conv_part_kernel(
    const _Float16* __restrict__ xf, const _Float16* __restrict__ wf,
    float* __restrict__ pbuf)
{
    __shared__ _Float16 wS[9][4][32][8];   // 18.4 KB  [tap][q][och][8ch]
    __shared__ _Float16 xS[6][4][50][8];   // 19.2 KB  [row][q][col][8ch]
    const int y0 = blockIdx.x * 4;
    const int og = blockIdx.y;
    const int bz = blockIdx.z;
    const int b  = bz >> 1, kb = bz & 1;
    const int tid = threadIdx.x;
    const int wv = tid >> 6;
    const int ln = tid & 63;
    const int n  = ln & 15;
    const int q  = ln >> 4;

    f32x4 acc[2][3];
#pragma unroll
    for (int mt = 0; mt < 2; ++mt)
#pragma unroll
        for (int nt = 0; nt < 3; ++nt) acc[mt][nt] = (f32x4){0.f, 0.f, 0.f, 0.f};

    const int c0 = kb * 512;
    for (int cc = c0; cc < c0 + 512; cc += 32) {
#pragma unroll
        for (int it = 0; it < 5; ++it) {
            int g = it * 256 + tid;
            if (g < 1152) {
                int tap = g >> 7, r = g & 127, qq = r >> 5, oc = r & 31;
                *(uint4*)&wS[tap][qq][oc][0] =
                    *(const uint4*)(wf + ((size_t)(og * 32 + oc) * 9 + tap) * 1024 + cc + qq * 8);
            }
        }
#pragma unroll
        for (int it = 0; it < 5; ++it) {
            int g = it * 256 + tid;
            if (g < 1200) {
                int row = g / 200, r2 = g - row * 200;
                int qq = r2 / 50, c = r2 - qq * 50;
                int gy = y0 + row - 1, gx = c - 1;
                uint4 v = make_uint4(0u, 0u, 0u, 0u);
                if ((unsigned)gy < 48u && (unsigned)gx < 48u)
                    v = *(const uint4*)(xf + ((size_t)(b * 48 + gy) * 48 + gx) * 1024 + cc + qq * 8);
                *(uint4*)&xS[row][qq][c][0] = v;
            }
        }
        __syncthreads();

#pragma unroll
        for (int tap = 0; tap < 9; ++tap) {
            const int dy = tap / 3, dx = tap % 3;
            f16x8 a0 = *(const f16x8*)&wS[tap][q][n][0];
            f16x8 a1 = *(const f16x8*)&wS[tap][q][16 + n][0];
#pragma unroll
            for (int nt = 0; nt < 3; ++nt) {
                f16x8 bb = *(const f16x8*)&xS[wv + dy][q][nt * 16 + n + dx][0];
                acc[0][nt] = __builtin_amdgcn_mfma_f32_16x16x32_f16(a0, bb, acc[0][nt], 0, 0, 0);
                acc[1][nt] = __builtin_amdgcn_mfma_f32_16x16x32_f16(a1, bb, acc[1][nt], 0, 0, 0);
            }
        }
        __syncthreads();
    }

    const int y = y0 + wv;
#pragma unroll
    for (int mt = 0; mt < 2; ++mt) {
#pragma unroll
        for (int nt = 0; nt < 3; ++nt) {
            int x = nt * 16 + n;
            *(f32x4*)(pbuf + (size_t)kb * PSLICE +
                      ((size_t)(b * 48 + y) * 48 + x) * 256 + og * 32 + mt * 16 + q * 4) = acc[mt][nt];
        }
    }
}

// sum partials + bias + relu -> dec NHWC f16. grid 2304 x 256.
__global__ __launch_bounds__(256) void conv_sum_kernel(
    const float* __restrict__ pbuf, const float* __restrict__ bd,
    _Float16* __restrict__ dec)
{
    size_t idx = (size_t)blockIdx.x * 256 + threadIdx.x;   // 589824 threads
    size_t e = idx * 4;
    int och = (int)(e & 255);
    f32x4 s0 = *(const f32x4*)(pbuf + e);
    f32x4 s1 = *(const f32x4*)(pbuf + (size_t)PSLICE + e);
    float4 b4 = *(const float4*)(bd + och);
    f16x4 v;
    v.x = (_Float16)fmaxf(s0[0] + s1[0] + b4.x, 0.f);
    v.y = (_Float16)fmaxf(s0[1] + s1[1] + b4.y, 0.f);
    v.z = (_Float16)fmaxf(s0[2] + s1[2] + b4.z, 0.f);
    v.w = (_Float16)fmaxf(s0[3] + s1[3] + b4.w, 0.f);
    *(f16x4*)(dec + e) = v;
}

// ---------------------------------------------------------------------------
// ROI align 2x2 on NHWC f16 dec
// ---------------------------------------------------------------------------
__global__ __launch_bounds__(256) void roi_kernel(
    const _Float16* __restrict__ dec, const float* __restrict__ boxes,
    _Float16* __restrict__ cnn)
{
    int n = blockIdx.x; int c = threadIdx.x;
    int b = n >> 9;
    float x1 = boxes[n * 4 + 0], y1 = boxes[n * 4 + 1];
    float x2 = boxes[n * 4 + 2], y2 = boxes[n * 4 + 3];
    float bw = (x2 - x1) * 0.5f, bh = (y2 - y1) * 0.5f;
    float sxv[2] = { x1 + 0.5f * bw, x1 + 1.5f * bw };
    float syv[2] = { y1 + 0.5f * bh, y1 + 1.5f * bh };
    float px[4] = { sxv[0], sxv[1], sxv[0], sxv[1] };
    float py[4] = { syv[0], syv[0], syv[1], syv[1] };
    const _Float16* f = dec + (size_t)b * 2304 * 256;
    f16x4 o4;
    float res[4];
#pragma unroll
    for (int p = 0; p < 4; ++p) {
        float yy = fminf(fmaxf(py[p], 0.f), 47.f);
        float xx = fminf(fmaxf(px[p], 0.f), 47.f);
        int y0 = (int)floorf(yy), x0 = (int)floorf(xx);
        int y1i = min(y0 + 1, 47), x1i = min(x0 + 1, 47);
        float wy = yy - (float)y0, wx = xx - (float)x0;
        float f00 = (float)f[(size_t)(y0 * 48 + x0) * 256 + c];
        float f01 = (float)f[(size_t)(y0 * 48 + x1i) * 256 + c];
        float f10 = (float)f[(size_t)(y1i * 48 + x0) * 256 + c];
        float f11 = (float)f[(size_t)(y1i * 48 + x1i) * 256 + c];
        res[p] = f00 * (1.f - wy) * (1.f - wx) + f01 * (1.f - wy) * wx
               + f10 * wy * (1.f - wx) + f11 * wy * wx;
    }
    o4.x = (_Float16)res[0]; o4.y = (_Float16)res[1];
    o4.z = (_Float16)res[2]; o4.w = (_Float16)res[3];
    *(f16x4*)(cnn + (size_t)n * 1024 + c * 4) = o4;
}

// ---------------------------------------------------------------------------
// box head: fusion[:, 0:256] = relu(bf @ W_box + b_box)
// ---------------------------------------------------------------------------
__global__ __launch_bounds__(256) void box_kernel(
    const float* __restrict__ boxes, const float* __restrict__ Wb,
    const float* __restrict__ bb, _Float16* __restrict__ fusion)
{
    int nrow = blockIdx.x, c = threadIdx.x;
    float x1 = boxes[nrow * 4 + 0], y1 = boxes[nrow * 4 + 1];
    float x2 = boxes[nrow * 4 + 2], y2 = boxes[nrow * 4 + 3];
    float bf0 = ((x1 + x2) * 0.5f) / 48.f;
    float bf1 = ((y1 + y2) * 0.5f) / 48.f;
    float bf2 = (x2 - x1) / 48.f;
    float bf3 = (y2 - y1) / 48.f;
    float acc = bb[c];
    acc += bf0 * Wb[0 * 256 + c];
    acc += bf1 * Wb[1 * 256 + c];
    acc += bf2 * Wb[2 * 256 + c];
    acc += bf3 * Wb[3 * 256 + c];
    fusion[(size_t)nrow * 768 + c] = (_Float16)fmaxf(acc, 0.f);
}

// ---------------------------------------------------------------------------
// f16 MFMA GEMM: C = act(A @ Bt^T + bias). 64x64 tile, 4 waves 2x2.
// ---------------------------------------------------------------------------
template <int ACT, typename OUTT>
__global__ __launch_bounds__(256) void gemm16_kernel(
    const _Float16* __restrict__ A, const _Float16* __restrict__ Bt,
    const float* __restrict__ bias, OUTT* __restrict__ C,
    int M, int N, int K, int ldC)
{
    __shared__ _Float16 aS[64][4][8];
    __shared__ _Float16 bS[64][4][8];
    const int n0 = blockIdx.x * 64, m0 = blockIdx.y * 64;
    const int tid = threadIdx.x;
    const int wv = tid >> 6, ln = tid & 63;
    const int wm = wv & 1, wn = wv >> 1;
    const int lm = ln & 15, lq = ln >> 4;
    const int sr = tid >> 2, sq = tid & 3;

    f32x4 acc[2][2];
#pragma unroll
    for (int i = 0; i < 2; ++i)
#pragma unroll
        for (int j = 0; j < 2; ++j) acc[i][j] = (f32x4){0.f, 0.f, 0.f, 0.f};

    for (int cc = 0; cc < K; cc += 32) {
        *(uint4*)&aS[sr][sq][0] = *(const uint4*)(A + (size_t)(m0 + sr) * K + cc + sq * 8);
        uint4 bv = make_uint4(0u, 0u, 0u, 0u);
        if (n0 + sr < N)
            bv = *(const uint4*)(Bt + (size_t)(n0 + sr) * K + cc + sq * 8);
        *(uint4*)&bS[sr][sq][0] = bv;
        __syncthreads();
        f16x8 af[2], bf[2];
#pragma unroll
        for (int mt = 0; mt < 2; ++mt) af[mt] = *(const f16x8*)&aS[wm * 32 + mt * 16 + lm][lq][0];
#pragma unroll
        for (int nt = 0; nt < 2; ++nt) bf[nt] = *(const f16x8*)&bS[wn * 32 + nt * 16 + lm][lq][0];
#pragma unroll
        for (int mt = 0; mt < 2; ++mt)
#pragma unroll
            for (int nt = 0; nt < 2; ++nt)
                acc[mt][nt] = __builtin_amdgcn_mfma_f32_16x16x32_f16(af[mt], bf[nt], acc[mt][nt], 0, 0, 0);
        __syncthreads();
    }

#pragma unroll
    for (int mt = 0; mt < 2; ++mt) {
#pragma unroll
        for (int nt = 0; nt < 2; ++nt) {
            int col = n0 + wn * 32 + nt * 16 + lm;
            if (col >= N) continue;
            float bs = bias ? bias[col] : 0.f;
#pragma unroll
            for (int r = 0; r < 4; ++r) {
                int row = m0 + wm * 32 + mt * 16 + lq * 4 + r;
                float v = acc[mt][nt][r] + bs;
                if (ACT == 1) v = fmaxf(v, 0.f);
                if (ACT == 2) v = (v >= 0.f) ? v : 0.01f * v;
                C[(size_t)row * ldC + col] = (OUTT)v;
            }
        }
    }
}

// dual-B variant: grid.z selects (Bt, C). ACT=0, float out, no bias.
__global__ __launch_bounds__(256) void gemm16z_kernel(
    const _Float16* __restrict__ A,
    const _Float16* __restrict__ Bt0, const _Float16* __restrict__ Bt1,
    float* __restrict__ C0, float* __restrict__ C1,
    int M, int N, int K, int ldC)
{
    const _Float16* __restrict__ Bt = blockIdx.z ? Bt1 : Bt0;
    float* __restrict__ C = blockIdx.z ? C1 : C0;
    __shared__ _Float16 aS[64][4][8];
    __shared__ _Float16 bS[64][4][8];
    const int n0 = blockIdx.x * 64, m0 = blockIdx.y * 64;
    const int tid = threadIdx.x;
    const int wv = tid >> 6, ln = tid & 63;
    const int wm = wv & 1, wn = wv >> 1;
    const int lm = ln & 15, lq = ln >> 4;
    const int sr = tid >> 2, sq = tid & 3;

    f32x4 acc[2][2];
#pragma unroll
    for (int i = 0; i < 2; ++i)
#pragma unroll
        for (int j = 0; j < 2; ++j) acc[i][j] = (f32x4){0.f, 0.f, 0.f, 0.f};

    for (int cc = 0; cc < K; cc += 32) {
        *(uint4*)&aS[sr][sq][0] = *(const uint4*)(A + (size_t)(m0 + sr) * K + cc + sq * 8);
        uint4 bv = make_uint4(0u, 0u, 0u, 0u);
        if (n0 + sr < N)
            bv = *(const uint4*)(Bt + (size_t)(n0 + sr) * K + cc + sq * 8);
        *(uint4*)&bS[sr][sq][0] = bv;
        __syncthreads();
        f16x8 af[2], bf[2];
#pragma unroll
        for (int mt = 0; mt < 2; ++mt) af[mt] = *(const f16x8*)&aS[wm * 32 + mt * 16 + lm][lq][0];
#pragma unroll
        for (int nt = 0; nt < 2; ++nt) bf[nt] = *(const f16x8*)&bS[wn * 32 + nt * 16 + lm][lq][0];
#pragma unroll
        for (int mt = 0; mt < 2; ++mt)
#pragma unroll
            for (int nt = 0; nt < 2; ++nt)
                acc[mt][nt] = __builtin_amdgcn_mfma_f32_16x16x32_f16(af[mt], bf[nt], acc[mt][nt], 0, 0, 0);
        __syncthreads();
    }

#pragma unroll
    for (int mt = 0; mt < 2; ++mt) {
#pragma unroll
        for (int nt = 0; nt < 2; ++nt) {
            int col = n0 + wn * 32 + nt * 16 + lm;
            if (col >= N) continue;
#pragma unroll
            for (int r = 0; r < 4; ++r) {
                int row = m0 + wm * 32 + mt * 16 + lq * 4 + r;
                C[(size_t)row * ldC + col] = acc[mt][nt][r];
            }
        }
    }
}

// ---------------------------------------------------------------------------
// shared helper: per-sel centers sv[512] (LDS) + table extent tbv.
// ---------------------------------------------------------------------------
__device__ __forceinline__ float compute_sv_tb(
    const float* __restrict__ boxes, const float* __restrict__ scales,
    const float* __restrict__ pdls, const float* __restrict__ pdts,
    int b, int t, float* sv, float* red)
{
    int tid = threadIdx.x;
    float pdl = pdls[b], pdt = pdts[b], sc = scales[b];
    if (tid < 512) {
        const float* bx = boxes + (size_t)(b * 512 + tid) * 4;
        float o0 = (bx[0] - pdl) / sc;
        float o1 = (bx[1] - pdt) / sc;
        float o2 = (bx[2] - pdl) / sc;
        float o3 = (bx[3] - pdt) / sc;
        sv[tid]  = (t == 0) ? (o1 + o3) * 0.5f : (o0 + o2) * 0.5f;
        red[tid] = (t == 0) ? fmaxf(o1, o3)    : fmaxf(o0, o2);
    }
    __syncthreads();
    for (int s = 256; s > 0; s >>= 1) {
        if (tid < s) red[tid] = fmaxf(red[tid], red[tid + s]);
        __syncthreads();
    }
    float tbv = red[0];
    __syncthreads();
    return tbv;
}

#define QBITS(e, QB)                                                   \
    {                                                                  \
        int i_ = (e) / 511; int jj_ = (e) - i_ * 511;                  \
        int j_ = jj_ + (jj_ >= i_ ? 1 : 0);                            \
        float diff_ = sv[i_] - sv[j_];                                 \
        float u_ = (diff_ * 5.0f) / tbv;                               \
        float q_ = u_ * u_;                                            \
        QB = __float_as_uint(q_);                                      \
    }

// ---------------------------------------------------------------------------
// histA: LDS 4096-bin hist of top-12 q-bits, per-chunk partial.
// ---------------------------------------------------------------------------
__global__ __launch_bounds__(1024) void histA_kernel(
    const float* __restrict__ boxes, const float* __restrict__ scales,
    const float* __restrict__ pdls, const float* __restrict__ pdts,
    u32* __restrict__ gpart)
{
    __shared__ float sv[512]; __shared__ float red[512];
    __shared__ u32 lh[4096];
    const int sel = blockIdx.y, b = sel >> 1, t = sel & 1;
    const int tid = threadIdx.x;
    for (int i = tid; i < 4096; i += 1024) lh[i] = 0;
    const float tbv = compute_sv_tb(boxes, scales, pdls, pdts, b, t, sv, red);
    const int e1 = min((int)(blockIdx.x + 1) * ECHUNK, NE);
    for (int e = blockIdx.x * ECHUNK + tid; e < e1; e += 1024) {
        u32 qb; QBITS(e, qb);
        atomicAdd(&lh[qb >> 20], 1u);
    }
    __syncthreads();
    u32* G = gpart + ((size_t)sel * NCHUNK + blockIdx.x) * 4096;
    for (int i = tid; i < 4096; i += 1024) G[i] = lh[i];
}

// scanA: sum partials, block scan over 4096 bins, locate K-th -> p12, need1.
__global__ __launch_bounds__(1024) void scanA_kernel(
    const u32* __restrict__ gpart, u32* __restrict__ meta)
{
    const int sel = blockIdx.x, tid = threadIdx.x;
    __shared__ u32 bins[4096];
    __shared__ u32 sc[2][1024];
    for (int b = tid; b < 4096; b += 1024) {
        u32 s = 0;
        for (int c = 0; c < NCHUNK; ++c) s += gpart[((size_t)sel * NCHUNK + c) * 4096 + b];
        bins[b] = s;
    }
    __syncthreads();
    u32 part = 0;
#pragma unroll
    for (int j = 0; j < 4; ++j) part += bins[tid * 4 + j];
    sc[0][tid] = part;
    __syncthreads();
    int src = 0;
    for (int st = 1; st < 1024; st <<= 1) {
        sc[1 - src][tid] = sc[src][tid] + (tid >= st ? sc[src][tid - st] : 0);
        __syncthreads(); src = 1 - src;
    }
    u32 inc = sc[src][tid], exc = inc - part;
    if (exc < (u32)KEDGE && (u32)KEDGE <= inc) {
        u32 cum = exc;
        for (int j = 0; j < 4; ++j) {
            u32 c = bins[tid * 4 + j];
            if (cum + c >= (u32)KEDGE) {
                meta[sel * MS + 0] = (u32)(tid * 4 + j);
                meta[sel * MS + 1] = (u32)KEDGE - cum;
                break;
            }
            cum += c;
        }
    }
}

// histB: among edges with top-12 == p12, LDS hist of bits [19:8].
__global__ __launch_bounds__(1024) void histB_kernel(
    const float* __restrict__ boxes, const float* __restrict__ scales,
    const float* __restrict__ pdls, const float* __restrict__ pdts,
    const u32* __restrict__ meta, u32* __restrict__ gpart)
{
    __shared__ float sv[512]; __shared__ float red[512];
    __shared__ u32 lh[4096];
    const int sel = blockIdx.y, b = sel >> 1, t = sel & 1;
    const int tid = threadIdx.x;
    for (int i = tid; i < 4096; i += 1024) lh[i] = 0;
    const float tbv = compute_sv_tb(boxes, scales, pdls, pdts, b, t, sv, red);
    const u32 p12 = meta[sel * MS + 0];
    const int e1 = min((int)(blockIdx.x + 1) * ECHUNK, NE);
    for (int e = blockIdx.x * ECHUNK + tid; e < e1; e += 1024) {
        u32 qb; QBITS(e, qb);
        if ((qb >> 20) == p12) atomicAdd(&lh[(qb >> 8) & 0xFFF], 1u);
    }
    __syncthreads();
    u32* G = gpart + ((size_t)sel * NCHUNK + blockIdx.x) * 4096;
    for (int i = tid; i < 4096; i += 1024) G[i] = lh[i];
}

// scanB: locate need1-th within p12 group -> prefix24, need2.
__global__ __launch_bounds__(1024) void scanB_kernel(
    const u32* __restrict__ gpart, u32* __restrict__ meta)
{
    const int sel = blockIdx.x, tid = threadIdx.x;
    const u32 TH = meta[sel * MS + 1];
    __shared__ u32 bins[4096];
    __shared__ u32 sc[2][1024];
    for (int b = tid; b < 4096; b += 1024) {
        u32 s = 0;
        for (int c = 0; c < NCHUNK; ++c) s += gpart[((size_t)sel * NCHUNK + c) * 4096 + b];
        bins[b] = s;
    }
    __syncthreads();
    u32 part = 0;
#pragma unroll
    for (int j = 0; j < 4; ++j) part += bins[tid * 4 + j];
    sc[0][tid] = part;
    __syncthreads();
    int src = 0;
    for (int st = 1; st < 1024; st <<= 1) {
        sc[1 - src][tid] = sc[src][tid] + (tid >= st ? sc[src][tid - st] : 0);
        __syncthreads(); src = 1 - src;
    }
    u32 inc = sc[src][tid], exc = inc - part;
    if (exc < TH && TH <= inc) {
        u32 cum = exc;
        for (int j = 0; j < 4; ++j) {
            u32 c = bins[tid * 4 + j];
            if (cum + c >= TH) {
                meta[sel * MS + 6] = (meta[sel * MS + 0] << 12) | (u32)(tid * 4 + j);
                meta[sel * MS + 7] = TH - cum;
                break;
            }
            cum += c;
        }
    }
}

// histC: among edges with top-24 == prefix24, LDS hist of low 8 bits.
__global__ __launch_bounds__(1024) void histC_kernel(
    const float* __restrict__ boxes, const float* __restrict__ scales,
    const float* __restrict__ pdls, const float* __restrict__ pdts,
    const u32* __restrict__ meta, u32* __restrict__ gpart)
{
    __shared__ float sv[512]; __shared__ float red[512];
    __shared__ u32 lh[256];
    const int sel = blockIdx.y, b = sel >> 1, t = sel & 1;
    const int tid = threadIdx.x;
    if (tid < 256) lh[tid] = 0;
    const float tbv = compute_sv_tb(boxes, scales, pdls, pdts, b, t, sv, red);
    const u32 p24 = meta[sel * MS + 6];
    const int e1 = min((int)(blockIdx.x + 1) * ECHUNK, NE);
    for (int e = blockIdx.x * ECHUNK + tid; e < e1; e += 1024) {
        u32 qb; QBITS(e, qb);
        if ((qb >> 8) == p24) atomicAdd(&lh[qb & 0xFF], 1u);
    }
    __syncthreads();
    u32* G = gpart + ((size_t)sel * NCHUNK + blockIdx.x) * 256;
    if (tid < 256) G[tid] = lh[tid];
}

// scanC: exact q*, then binary-search the w*-tie q-interval [qlo,qhi].
__global__ __launch_bounds__(256) void scanC_kernel(
    const u32* __restrict__ gpart, u32* __restrict__ meta)
{
    const int sel = blockIdx.x, tid = threadIdx.x;
    const u32 TH = meta[sel * MS + 7];
    __shared__ u32 bins[256];
    __shared__ u32 sc[2][256];
    __shared__ u32 s_qstar;
    u32 s = 0;
    for (int c = 0; c < NCHUNK; ++c) s += gpart[((size_t)sel * NCHUNK + c) * 256 + tid];
    bins[tid] = s;
    sc[0][tid] = s;
    __syncthreads();
    int src = 0;
    for (int st = 1; st < 256; st <<= 1) {
        sc[1 - src][tid] = sc[src][tid] + (tid >= st ? sc[src][tid - st] : 0);
        __syncthreads(); src = 1 - src;
    }
    u32 inc = sc[src][tid], exc = inc - bins[tid];
    if (exc < TH && TH <= inc)
        s_qstar = (meta[sel * MS + 6] << 8) | (u32)tid;
    __syncthreads();
    if (tid == 0) {
        u32 prefix = s_qstar;
        float qstar = __uint_as_float(prefix);
        float wstar = (float)exp(-(double)qstar);
        u32 lo = 0, hi = prefix;              // smallest qb with exp(-q)==w*
        while (lo < hi) {
            u32 mid = (lo + hi) >> 1;
            float wm = (float)exp(-(double)__uint_as_float(mid));
            if (wm > wstar) lo = mid + 1; else hi = mid;
        }
        meta[sel * MS + 2] = lo;
        lo = prefix; hi = 0x7F800000u;        // largest qb with exp(-q)==w*
        while (lo < hi) {
            u32 mid = (lo + hi + 1) >> 1;
            float wm = (float)exp(-(double)__uint_as_float(mid));
            if (wm < wstar) hi = mid - 1; else lo = mid;
        }
        meta[sel * MS + 3] = lo;
        meta[sel * MS + 4] = __float_as_uint(wstar);
    }
}

// ---------------------------------------------------------------------------
// emit: two-pass block-aggregated slot reservation (ONE global RMW per block
// per counter instead of ~4096 same-address RMWs per sel -> no cross-XCD
// cache-line ping-pong). Winners (qb<qlo) -> es/ed/ewt; ties -> tiebuf.
// ---------------------------------------------------------------------------
__global__ __launch_bounds__(1024) void emit_kernel(
    const float* __restrict__ boxes, const float* __restrict__ scales,
    const float* __restrict__ pdls, const float* __restrict__ pdts,
    u32* __restrict__ meta, int* __restrict__ tiebuf, int* __restrict__ tiecnt,
    int* __restrict__ es, int* __restrict__ ed, float* __restrict__ ewt,
    int* __restrict__ indeg, float* __restrict__ degw)
{
    __shared__ float sv[512]; __shared__ float red[512];
    __shared__ int s_wcnt, s_tcnt, s_wbase, s_tbase;
    const int sel = blockIdx.y, b = sel >> 1, t = sel & 1;
    const int tid = threadIdx.x;
    const float tbv = compute_sv_tb(boxes, scales, pdls, pdts, b, t, sv, red);
    const u32 qlo = meta[sel * MS + 2], qhi = meta[sel * MS + 3];
    const int base = t * 16384 + b * 4096;
    const int e0 = blockIdx.x * ECHUNK + tid;
    const int e1 = min((int)(blockIdx.x + 1) * ECHUNK, NE);
    if (tid == 0) { s_wcnt = 0; s_tcnt = 0; }
    __syncthreads();
    // pass 1: count winners / ties in this block
    int myw = 0, myt = 0;
    for (int e = e0; e < e1; e += 1024) {
        u32 qb; QBITS(e, qb);
        if (qb < qlo) ++myw;
        else if (qb <= qhi) ++myt;
    }
    if (myw) atomicAdd(&s_wcnt, myw);
    if (myt) atomicAdd(&s_tcnt, myt);
    __syncthreads();
    if (tid == 0) {
        s_wbase = (s_wcnt > 0) ? (int)atomicAdd(&meta[sel * MS + 5], (u32)s_wcnt) : 0;
        s_tbase = (s_tcnt > 0) ? atomicAdd(&tiecnt[sel * TS], s_tcnt) : 0;
        s_wcnt = 0; s_tcnt = 0;
    }
    __syncthreads();
    // pass 2: place
    for (int e = e0; e < e1; e += 1024) {
        u32 qb; QBITS(e, qb);
        if (qb < qlo) {
            int i = e / 511; int jj = e - i * 511; int j = jj + (jj >= i ? 1 : 0);
            float wval = (float)exp(-(double)__uint_as_float(qb));
            int slot = s_wbase + atomicAdd(&s_wcnt, 1);
            es[base + slot] = b * 512 + i;
            ed[base + slot] = b * 512 + j;
            ewt[base + slot] = wval;
            atomicAdd(&indeg[t * 2048 + b * 512 + j], 1);
            atomicAdd(&degw[t * 2048 + b * 512 + j], wval);
        } else if (qb <= qhi) {
            int p = s_tbase + atomicAdd(&s_tcnt, 1);
            if (p < TIECAP) tiebuf[sel * TIECAP + p] = e;
        }
    }
}

// ---------------------------------------------------------------------------
// tie resolution (index-ascending, r = K - emitted) + indeg scan + dis.
// ---------------------------------------------------------------------------
__global__ __launch_bounds__(1024) void tie_scan_kernel(
    u32* __restrict__ meta, const int* __restrict__ tiebuf, const int* __restrict__ tiecnt,
    int* __restrict__ es, int* __restrict__ ed, float* __restrict__ ewt,
    int* __restrict__ indeg, float* __restrict__ degw,
    int* __restrict__ offs, float* __restrict__ dis)
{
    __shared__ int bufA[2048], bufB[2048];
    const int t = blockIdx.x, tid = threadIdx.x;
    for (int b = 0; b < 4; ++b) {
        int sel = b * 2 + t;
        int m = min(tiecnt[sel * TS], TIECAP);
        int r = KEDGE - (int)meta[sel * MS + 5];
        float wt = __uint_as_float(meta[sel * MS + 4]);
        int base = t * 16384 + b * 4096;
        for (int k = tid; k < m; k += 1024) {
            int e = tiebuf[sel * TIECAP + k];
            int rank = 0;
            for (int l = 0; l < m; ++l) rank += (tiebuf[sel * TIECAP + l] < e) ? 1 : 0;
            if (rank < r) {
                int i = e / 511; int jj = e - i * 511; int j = jj + (jj >= i ? 1 : 0);
                int slot = (int)atomicAdd(&meta[sel * MS + 5], 1u);
                es[base + slot] = b * 512 + i;
                ed[base + slot] = b * 512 + j;
                ewt[base + slot] = wt;
                atomicAdd(&indeg[t * 2048 + b * 512 + j], 1);
                atomicAdd(&degw[t * 2048 + b * 512 + j], wt);
            }
        }
    }
    __threadfence();
    __syncthreads();
    bufA[tid] = indeg[t * 2048 + tid];
    bufA[tid + 1024] = indeg[t * 2048 + tid + 1024];
    __syncthreads();
    int* src = bufA; int* dst = bufB;
    for (int st = 1; st < 2048; st <<= 1) {
        dst[tid] = src[tid] + (tid >= st ? src[tid - st] : 0);
        int k1 = tid + 1024;
        dst[k1] = src[k1] + (k1 >= st ? src[k1 - st] : 0);
        __syncthreads();
        int* tmp = src; src = dst; dst = tmp;
    }
    offs[t * 2048 + tid] = (tid == 0) ? 0 : src[tid - 1];
    offs[t * 2048 + tid + 1024] = src[tid + 1023];
    dis[t * 2048 + tid] = 1.0f / sqrtf(1.0f + degw[t * 2048 + tid]);
    dis[t * 2048 + tid + 1024] = 1.0f / sqrtf(1.0f + degw[t * 2048 + tid + 1024]);
}

// CSR fill
__global__ void fill_kernel(const int* __restrict__ ed, const int* __restrict__ offs,
                            int* __restrict__ fill, int* __restrict__ csr) {
    int idx = blockIdx.x * 256 + threadIdx.x;
    if (idx >= 32768) return;
    int t = idx >> 14, e = idx & 16383;
    int d = ed[t * 16384 + e] & 2047;
    int pos = offs[t * 2048 + d] + atomicAdd(&fill[t * 2048 + d], 1);
    csr[t * 16384 + pos] = e;
}

// E7: GCN aggregate -> feats f16
__global__ __launch_bounds__(256) void gcn_agg_kernel(
    const float* __restrict__ xw_row, const float* __restrict__ xw_col,
    const float* __restrict__ b_row, const float* __restrict__ b_col,
    const int* __restrict__ es, const float* __restrict__ ew,
    const int* __restrict__ csr, const int* __restrict__ offs,
    const int* __restrict__ indeg, const float* __restrict__ dis,
    _Float16* __restrict__ feat_row, _Float16* __restrict__ feat_col)
{
    int d = blockIdx.x; int t = blockIdx.y;
    const float* xw = t ? xw_col : xw_row;
    const float* bg = t ? b_col : b_row;
    _Float16* out = t ? feat_col : feat_row;
    int f0 = threadIdx.x, f1 = threadIdx.x + 256;
    float dd = dis[t * 2048 + d];
    float a0 = dd * dd * xw[(size_t)d * 512 + f0];
    float a1 = dd * dd * xw[(size_t)d * 512 + f1];
    int st = offs[t * 2048 + d], cnt = indeg[t * 2048 + d];
    for (int k = 0; k < cnt; ++k) {
        int e = csr[t * 16384 + st + k];
        int s = es[t * 16384 + e];
        float w = ew[t * 16384 + e];
        float coef = dis[t * 2048 + s] * w * dd;
        a0 += coef * xw[(size_t)s * 512 + f0];
        a1 += coef * xw[(size_t)s * 512 + f1];
    }
    a0 += bg[f0]; a1 += bg[f1];
    out[(size_t)d * 512 + f0] = (_Float16)fmaxf(a0, 0.f);
    out[(size_t)d * 512 + f1] = (_Float16)fmaxf(a1, 0.f);
}

// ---------------------------------------------------------------------------
extern "C" void kernel_launch(void* const* d_in, const int* in_sizes, int n_in,
                              void* d_out, int out_size, void* d_ws, size_t ws_size,
                              hipStream_t stream)
{
    const float* x      = (const float*)d_in[0];
    const float* boxes  = (const float*)d_in[1];
    const float* scales = (const float*)d_in[2];
    const float* pdls   = (const float*)d_in[3];
    const float* pdts   = (const float*)d_in[4];
    const float* W_dec  = (const float*)d_in[5];
    const float* b_dec  = (const float*)d_in[6];
    const float* W_box  = (const float*)d_in[7];
    const float* b_box  = (const float*)d_in[8];
    const float* W_cnn  = (const float*)d_in[9];
    const float* b_cnn  = (const float*)d_in[10];
    const float* W_grow = (const float*)d_in[11];
    const float* b_grow = (const float*)d_in[12];
    const float* W_gcol = (const float*)d_in[13];
    const float* b_gcol = (const float*)d_in[14];
    const float* W_rcls = (const float*)d_in[15];
    const float* b_rcls = (const float*)d_in[16];
    const float* W_ccls = (const float*)d_in[17];
    const float* b_ccls = (const float*)d_in[18];

    char* ws = (char*)d_ws;
    size_t off = 0;
    auto alloc = [&](size_t bytes) -> void* {
        void* p = ws + off;
        off = (off + bytes + 255) & ~(size_t)255;
        return p;
    };
    _Float16* xf16   = (_Float16*)alloc((size_t)4 * 2304 * 1024 * 2);  // NHWC in
    _Float16* wf16   = (_Float16*)alloc((size_t)256 * 9216 * 2);       // [o][tap][ch]
    _Float16* dec    = (_Float16*)alloc((size_t)4 * 2304 * 256 * 2);   // NHWC
    float*    pbuf   = (float*)   alloc((size_t)2 * PSLICE * 4);       // split-K partials
    _Float16* cnn    = (_Float16*)alloc((size_t)2048 * 1024 * 2);
    _Float16* fusion = (_Float16*)alloc((size_t)2048 * 768 * 2);
    _Float16* WcT    = (_Float16*)alloc((size_t)512 * 1024 * 2);
    _Float16* WgrT   = (_Float16*)alloc((size_t)512 * 768 * 2);
    _Float16* WgcT   = (_Float16*)alloc((size_t)512 * 768 * 2);
    _Float16* WrT    = (_Float16*)alloc((size_t)228 * 512 * 2);
    _Float16* WccT   = (_Float16*)alloc((size_t)116 * 512 * 2);
    float* xw        = (float*)alloc((size_t)2097152 * 4);             // xw_row|xw_col
    _Float16* feats  = (_Float16*)alloc((size_t)2 * 2048 * 512 * 2);   // row|col
    int*  es     = (int*)  alloc((size_t)2 * 16384 * 4);
    int*  ed     = (int*)  alloc((size_t)2 * 16384 * 4);
    float* ewt   = (float*)alloc((size_t)2 * 16384 * 4);
    int*  offsA  = (int*)  alloc((size_t)4096 * 4);
    float* dis   = (float*)alloc((size_t)4096 * 4);
    int*  csr    = (int*)  alloc((size_t)2 * 16384 * 4);
    int*  tiebuf = (int*)  alloc((size_t)8 * TIECAP * 4);
    u32*  gpartA = (u32*)  alloc((size_t)8 * NCHUNK * 4096 * 4);   // fully overwritten
    u32*  gpartB = (u32*)  alloc((size_t)8 * NCHUNK * 4096 * 4);
    u32*  gpartC = (u32*)  alloc((size_t)8 * NCHUNK * 256 * 4);
    // ---- zero zone (one hipMemsetAsync) ----
    size_t z0 = off;
    u32*  meta   = (u32*)  alloc((size_t)8 * MS * 4);
    int*  tiecnt = (int*)  alloc((size_t)8 * TS * 4);
    int*  indeg  = (int*)  alloc((size_t)4096 * 4);
    float* degw  = (float*)alloc((size_t)4096 * 4);
    int*  fillA  = (int*)  alloc((size_t)4096 * 4);
    size_t z1 = off;

    float* out = (float*)d_out;

    hipMemsetAsync(ws + z0, 0, z1 - z0, stream);

    cvt_x_kernel<<<dim3(16, 48, 4), 256, 0, stream>>>(x, xf16);
    cvt_w_kernel<<<256, 256, 0, stream>>>(W_dec, wf16);
    conv_part_kernel<<<dim3(12, 8, 8), 256, 0, stream>>>(xf16, wf16, pbuf);
    conv_sum_kernel<<<2304, 256, 0, stream>>>(pbuf, b_dec, dec);
    roi_kernel<<<2048, 256, 0, stream>>>(dec, boxes, cnn);
    box_kernel<<<2048, 256, 0, stream>>>(boxes, W_box, b_box, fusion);
    // weight transposes (f16 [N][K])
    cvt_t_kernel<<<dim3(16, 32), 256, 0, stream>>>(W_cnn, WcT, 1024, 512);
    cvt_t_kernel<<<dim3(16, 24), 256, 0, stream>>>(W_grow, WgrT, 768, 512);
    cvt_t_kernel<<<dim3(16, 24), 256, 0, stream>>>(W_gcol, WgcT, 768, 512);
    cvt_t_kernel<<<dim3(8, 16), 256, 0, stream>>>(W_rcls, WrT, 512, 228);
    cvt_t_kernel<<<dim3(4, 16), 256, 0, stream>>>(W_ccls, WccT, 512, 116);
    // fusion[:,256:768] = relu(cnn @ W_cnn + b)
    gemm16_kernel<1, _Float16><<<dim3(8, 32), 256, 0, stream>>>(cnn, WcT, b_cnn, fusion + 256, 2048, 512, 1024, 768);
    // edge pipeline: 12+12+8 LDS-privatized radix select + emit + CSR
    histA_kernel<<<dim3(NCHUNK, 8), 1024, 0, stream>>>(boxes, scales, pdls, pdts, gpartA);
    scanA_kernel<<<8, 1024, 0, stream>>>(gpartA, meta);
    histB_kernel<<<dim3(NCHUNK, 8), 1024, 0, stream>>>(boxes, scales, pdls, pdts, meta, gpartB);
    scanB_kernel<<<8, 1024, 0, stream>>>(gpartB, meta);
    histC_kernel<<<dim3(NCHUNK, 8), 1024, 0, stream>>>(boxes, scales, pdls, pdts, meta, gpartC);
    scanC_kernel<<<8, 256, 0, stream>>>(gpartC, meta);
    emit_kernel<<<dim3(NCHUNK, 8), 1024, 0, stream>>>(boxes, scales, pdls, pdts, meta,
                                                      tiebuf, tiecnt, es, ed, ewt, indeg, degw);
    tie_scan_kernel<<<2, 1024, 0, stream>>>(meta, tiebuf, tiecnt, es, ed, ewt,
                                            indeg, degw, offsA, dis);
    fill_kernel<<<128, 256, 0, stream>>>(ed, offsA, fillA, csr);
    // xw = fusion @ W_g{row,col} (bias applied in aggregation) — one dual launch
    gemm16z_kernel<<<dim3(8, 32, 2), 256, 0, stream>>>(fusion, WgrT, WgcT, xw, xw + 1048576,
                                                       2048, 512, 768, 512);
    gcn_agg_kernel<<<dim3(2048, 2), 256, 0, stream>>>(xw, xw + 1048576, b_grow, b_gcol,
                                                      es, ewt, csr, offsA, indeg, dis,
                                                      feats, feats + (size_t)2048 * 512);
    // classifier heads (leaky 0.01) -> fp32 out
    gemm16_kernel<2, float><<<dim3(4, 32), 256, 0, stream>>>(feats, WrT, b_rcls, out, 2048, 228, 512, 228);
    gemm16_kernel<2, float><<<dim3(2, 32), 256, 0, stream>>>(feats + (size_t)2048 * 512, WccT, b_ccls,
                                                             out + (size_t)2048 * 228, 2048, 116, 512, 116);
}

// Round 12
// 385.494 us; speedup vs baseline: 10.1506x; 1.0110x over previous
//
#include <hip/hip_runtime.h>
#include <cstdint>
#include <math.h>

typedef unsigned int u32;
typedef unsigned long long u64;
typedef unsigned short ushort;

typedef __attribute__((ext_vector_type(8))) _Float16 f16x8;
typedef __attribute__((ext_vector_type(4))) _Float16 f16x4;
typedef __attribute__((ext_vector_type(4))) float f32x4;

#define NB    4
#define BnN   2048
#define NE    261632      // 512*511 ordered pairs per batch
#define NCHUNK 16
#define ECHUNK 16352      // NE/16
#define KEDGE 4096
#define TIECAP 2048
#define PSLICE 2359296    // 4*2304*256 elements per K-slice partial
#define MS    64          // meta stride (u32) per sel -> 256B, own cache lines
#define TS    64          // tiecnt stride (int) per sel

// meta[sel*MS+i]: 0:p12  1:need1  2:qlo  3:qhi  4:wstar  5:emitcnt  6:prefix24  7:need2
// ---------------------------------------------------------------------------
// convert input: NCHW fp32 -> NHWC f16.  grid (16 chgrp, 48 y, 4 b), block 256
// ---------------------------------------------------------------------------
__global__ __launch_bounds__(256) void cvt_x_kernel(
    const float* __restrict__ in, _Float16* __restrict__ xf)
{
    __shared__ _Float16 sh[64][49];
    int cg = blockIdx.x, y = blockIdx.y, b = blockIdx.z;
    int tid = threadIdx.x;
    for (int i = tid; i < 64 * 48; i += 256) {
        int cl = i / 48, x = i - cl * 48;
        sh[cl][x] = (_Float16)in[(((size_t)b * 1024 + cg * 64 + cl) * 48 + y) * 48 + x];
    }
    __syncthreads();
    for (int i = tid; i < 64 * 48; i += 256) {
        int x = i / 64, cl = i - x * 64;
        xf[((size_t)(b * 48 + y) * 48 + x) * 1024 + cg * 64 + cl] = sh[cl][x];
    }
}

// convert weights: [o][ch][3][3] fp32 -> [o][tap][ch] f16. grid 256, block 256
__global__ __launch_bounds__(256) void cvt_w_kernel(
    const float* __restrict__ W, _Float16* __restrict__ wf)
{
    __shared__ _Float16 sh[9216];
    int o = blockIdx.x, tid = threadIdx.x;
    for (int g = tid; g < 9216; g += 256)
        sh[g] = (_Float16)W[(size_t)o * 9216 + g];     // g = ch*9+tap
    __syncthreads();
    for (int g = tid; g < 9216; g += 256) {
        int tap = g >> 10, ch = g & 1023;
        wf[(size_t)o * 9216 + g] = sh[ch * 9 + tap];
    }
}

// transpose-convert: in fp32 [K][N] -> out f16 [N][K]. grid (ceil(N/32), ceil(K/32))
__global__ __launch_bounds__(256) void cvt_t_kernel(
    const float* __restrict__ in, _Float16* __restrict__ out, int K, int N)
{
    __shared__ _Float16 sh[32][33];
    int n0 = blockIdx.x * 32, k0 = blockIdx.y * 32;
    int tx = threadIdx.x & 31, ty = threadIdx.x >> 5;
#pragma unroll
    for (int i = 0; i < 4; ++i) {
        int k = k0 + ty + i * 8, n = n0 + tx;
        sh[ty + i * 8][tx] = (k < K && n < N) ? (_Float16)in[(size_t)k * N + n] : (_Float16)0.f;
    }
    __syncthreads();
#pragma unroll
    for (int i = 0; i < 4; ++i) {
        int n = n0 + ty + i * 8, k = k0 + tx;
        if (n < N && k < K) out[(size_t)n * K + k] = sh[tx][ty + i * 8];
    }
}

// ---------------------------------------------------------------------------
// conv 3x3 SAME 1024->256, split-K(4) partials. Implicit-GEMM MFMA f16.
// Block 256 thr (4 waves). Wave tile: 64 och x 2 rows x 48 px
// (4 mt x 2 rr x 3 nt = 24 MFMA per 10 ds_read_b128 -> 38.4 FLOP/LDS-byte,
// 2x the old 32x48 tile -> LDS-BW time halves).
// grid (6 ygroup[8 rows], 4 og[64 och], 16 = b*4+kslice). K = 256 ch/block.
// ---------------------------------------------------------------------------
__global__ __launch_bounds__(256) void conv_part_kernel(
    const _Float16* __restrict__ xf, const _Float16* __restrict__ wf,
    float* __restrict__ pbuf)
{
    __shared__ _Float16 wS[9][4][64][8];   // 36.9 KB  [tap][q][och64][8ch]
    __shared__ _Float16 xS[10][4][50][8];  // 32.0 KB  [row10][q][col][8ch]
    const int y0 = blockIdx.x * 8;
    const int og = blockIdx.y;
    const int bz = blockIdx.z;
    const int b  = bz >> 2, ks = bz & 3;
    const int tid = threadIdx.x;
    const int wv = tid >> 6;
    const int ln = tid & 63;
    const int n  = ln & 15;
    const int q  = ln >> 4;

    f32x4 acc[4][2][3];
#pragma unroll
    for (int mt = 0; mt < 4; ++mt)
#pragma unroll
        for (int rr = 0; rr < 2; ++rr)
#pragma unroll
            for (int nt = 0; nt < 3; ++nt) acc[mt][rr][nt] = (f32x4){0.f, 0.f, 0.f, 0.f};

    const int c0 = ks * 256;
    for (int cc = c0; cc < c0 + 256; cc += 32) {
        // stage weights: 2304 x 16B (9 exact rounds)
#pragma unroll
        for (int it = 0; it < 9; ++it) {
            int g = it * 256 + tid;
            int tap = g >> 8, r = g & 255, qq = r >> 6, oc = r & 63;
            *(uint4*)&wS[tap][qq][oc][0] =
                *(const uint4*)(wf + ((size_t)(og * 64 + oc) * 9 + tap) * 1024 + cc + qq * 8);
        }
        // stage input rows y0-1 .. y0+8 (10), cols -1..48 : 2000 x 16B
#pragma unroll
        for (int it = 0; it < 8; ++it) {
            int g = it * 256 + tid;
            if (g < 2000) {
                int row = g / 200, r2 = g - row * 200;
                int qq = r2 / 50, c = r2 - qq * 50;
                int gy = y0 + row - 1, gx = c - 1;
                uint4 v = make_uint4(0u, 0u, 0u, 0u);
                if ((unsigned)gy < 48u && (unsigned)gx < 48u)
                    v = *(const uint4*)(xf + ((size_t)(b * 48 + gy) * 48 + gx) * 1024 + cc + qq * 8);
                *(uint4*)&xS[row][qq][c][0] = v;
            }
        }
        __syncthreads();

#pragma unroll
        for (int tap = 0; tap < 9; ++tap) {
            const int dy = tap / 3, dx = tap % 3;
            f16x8 a[4];
#pragma unroll
            for (int mt = 0; mt < 4; ++mt)
                a[mt] = *(const f16x8*)&wS[tap][q][mt * 16 + n][0];
#pragma unroll
            for (int rr = 0; rr < 2; ++rr) {
                const int row = 2 * wv + rr + dy;
#pragma unroll
                for (int nt = 0; nt < 3; ++nt) {
                    f16x8 bb = *(const f16x8*)&xS[row][q][nt * 16 + n + dx][0];
#pragma unroll
                    for (int mt = 0; mt < 4; ++mt)
                        acc[mt][rr][nt] = __builtin_amdgcn_mfma_f32_16x16x32_f16(a[mt], bb, acc[mt][rr][nt], 0, 0, 0);
                }
            }
        }
        __syncthreads();
    }

    // epilogue: px = nt*16+n, och = og*64 + mt*16 + q*4 + reg, y = y0+2wv+rr
#pragma unroll
    for (int rr = 0; rr < 2; ++rr) {
        const int y = y0 + 2 * wv + rr;
#pragma unroll
        for (int mt = 0; mt < 4; ++mt) {
#pragma unroll
            for (int nt = 0; nt < 3; ++nt) {
                int x = nt * 16 + n;
                *(f32x4*)(pbuf + (size_t)ks * PSLICE +
                          ((size_t)(b * 48 + y) * 48 + x) * 256 + og * 64 + mt * 16 + q * 4) = acc[mt][rr][nt];
            }
        }
    }
}

// sum 4 partials + bias + relu -> dec NHWC f16. grid 2304 x 256.
__global__ __launch_bounds__(256) void conv_sum_kernel(
    const float* __restrict__ pbuf, const float* __restrict__ bd,
    _Float16* __restrict__ dec)
{
    size_t idx = (size_t)blockIdx.x * 256 + threadIdx.x;   // 589824 threads
    size_t e = idx * 4;
    int och = (int)(e & 255);
    f32x4 s0 = *(const f32x4*)(pbuf + e);
    f32x4 s1 = *(const f32x4*)(pbuf + (size_t)PSLICE + e);
    f32x4 s2 = *(const f32x4*)(pbuf + (size_t)2 * PSLICE + e);
    f32x4 s3 = *(const f32x4*)(pbuf + (size_t)3 * PSLICE + e);
    float4 b4 = *(const float4*)(bd + och);
    f16x4 v;
    v.x = (_Float16)fmaxf(s0[0] + s1[0] + s2[0] + s3[0] + b4.x, 0.f);
    v.y = (_Float16)fmaxf(s0[1] + s1[1] + s2[1] + s3[1] + b4.y, 0.f);
    v.z = (_Float16)fmaxf(s0[2] + s1[2] + s2[2] + s3[2] + b4.z, 0.f);
    v.w = (_Float16)fmaxf(s0[3] + s1[3] + s2[3] + s3[3] + b4.w, 0.f);
    *(f16x4*)(dec + e) = v;
}

// ---------------------------------------------------------------------------
// ROI align 2x2 on NHWC f16 dec
// ---------------------------------------------------------------------------
__global__ __launch_bounds__(256) void roi_kernel(
    const _Float16* __restrict__ dec, const float* __restrict__ boxes,
    _Float16* __restrict__ cnn)
{
    int n = blockIdx.x; int c = threadIdx.x;
    int b = n >> 9;
    float x1 = boxes[n * 4 + 0], y1 = boxes[n * 4 + 1];
    float x2 = boxes[n * 4 + 2], y2 = boxes[n * 4 + 3];
    float bw = (x2 - x1) * 0.5f, bh = (y2 - y1) * 0.5f;
    float sxv[2] = { x1 + 0.5f * bw, x1 + 1.5f * bw };
    float syv[2] = { y1 + 0.5f * bh, y1 + 1.5f * bh };
    float px[4] = { sxv[0], sxv[1], sxv[0], sxv[1] };
    float py[4] = { syv[0], syv[0], syv[1], syv[1] };
    const _Float16* f = dec + (size_t)b * 2304 * 256;
    f16x4 o4;
    float res[4];
#pragma unroll
    for (int p = 0; p < 4; ++p) {
        float yy = fminf(fmaxf(py[p], 0.f), 47.f);
        float xx = fminf(fmaxf(px[p], 0.f), 47.f);
        int y0 = (int)floorf(yy), x0 = (int)floorf(xx);
        int y1i = min(y0 + 1, 47), x1i = min(x0 + 1, 47);
        float wy = yy - (float)y0, wx = xx - (float)x0;
        float f00 = (float)f[(size_t)(y0 * 48 + x0) * 256 + c];
        float f01 = (float)f[(size_t)(y0 * 48 + x1i) * 256 + c];
        float f10 = (float)f[(size_t)(y1i * 48 + x0) * 256 + c];
        float f11 = (float)f[(size_t)(y1i * 48 + x1i) * 256 + c];
        res[p] = f00 * (1.f - wy) * (1.f - wx) + f01 * (1.f - wy) * wx
               + f10 * wy * (1.f - wx) + f11 * wy * wx;
    }
    o4.x = (_Float16)res[0]; o4.y = (_Float16)res[1];
    o4.z = (_Float16)res[2]; o4.w = (_Float16)res[3];
    *(f16x4*)(cnn + (size_t)n * 1024 + c * 4) = o4;
}

// ---------------------------------------------------------------------------
// box head: fusion[:, 0:256] = relu(bf @ W_box + b_box)
// ---------------------------------------------------------------------------
__global__ __launch_bounds__(256) void box_kernel(
    const float* __restrict__ boxes, const float* __restrict__ Wb,
    const float* __restrict__ bb, _Float16* __restrict__ fusion)
{
    int nrow = blockIdx.x, c = threadIdx.x;
    float x1 = boxes[nrow * 4 + 0], y1 = boxes[nrow * 4 + 1];
    float x2 = boxes[nrow * 4 + 2], y2 = boxes[nrow * 4 + 3];
    float bf0 = ((x1 + x2) * 0.5f) / 48.f;
    float bf1 = ((y1 + y2) * 0.5f) / 48.f;
    float bf2 = (x2 - x1) / 48.f;
    float bf3 = (y2 - y1) / 48.f;
    float acc = bb[c];
    acc += bf0 * Wb[0 * 256 + c];
    acc += bf1 * Wb[1 * 256 + c];
    acc += bf2 * Wb[2 * 256 + c];
    acc += bf3 * Wb[3 * 256 + c];
    fusion[(size_t)nrow * 768 + c] = (_Float16)fmaxf(acc, 0.f);
}

// ---------------------------------------------------------------------------
// f16 MFMA GEMM: C = act(A @ Bt^T + bias). 64x64 tile, 4 waves 2x2.
// ---------------------------------------------------------------------------
template <int ACT, typename OUTT>
__global__ __launch_bounds__(256) void gemm16_kernel(
    const _Float16* __restrict__ A, const _Float16* __restrict__ Bt,
    const float* __restrict__ bias, OUTT* __restrict__ C,
    int M, int N, int K, int ldC)
{
    __shared__ _Float16 aS[64][4][8];
    __shared__ _Float16 bS[64][4][8];
    const int n0 = blockIdx.x * 64, m0 = blockIdx.y * 64;
    const int tid = threadIdx.x;
    const int wv = tid >> 6, ln = tid & 63;
    const int wm = wv & 1, wn = wv >> 1;
    const int lm = ln & 15, lq = ln >> 4;
    const int sr = tid >> 2, sq = tid & 3;

    f32x4 acc[2][2];
#pragma unroll
    for (int i = 0; i < 2; ++i)
#pragma unroll
        for (int j = 0; j < 2; ++j) acc[i][j] = (f32x4){0.f, 0.f, 0.f, 0.f};

    for (int cc = 0; cc < K; cc += 32) {
        *(uint4*)&aS[sr][sq][0] = *(const uint4*)(A + (size_t)(m0 + sr) * K + cc + sq * 8);
        uint4 bv = make_uint4(0u, 0u, 0u, 0u);
        if (n0 + sr < N)
            bv = *(const uint4*)(Bt + (size_t)(n0 + sr) * K + cc + sq * 8);
        *(uint4*)&bS[sr][sq][0] = bv;
        __syncthreads();
        f16x8 af[2], bf[2];
#pragma unroll
        for (int mt = 0; mt < 2; ++mt) af[mt] = *(const f16x8*)&aS[wm * 32 + mt * 16 + lm][lq][0];
#pragma unroll
        for (int nt = 0; nt < 2; ++nt) bf[nt] = *(const f16x8*)&bS[wn * 32 + nt * 16 + lm][lq][0];
#pragma unroll
        for (int mt = 0; mt < 2; ++mt)
#pragma unroll
            for (int nt = 0; nt < 2; ++nt)
                acc[mt][nt] = __builtin_amdgcn_mfma_f32_16x16x32_f16(af[mt], bf[nt], acc[mt][nt], 0, 0, 0);
        __syncthreads();
    }

#pragma unroll
    for (int mt = 0; mt < 2; ++mt) {
#pragma unroll
        for (int nt = 0; nt < 2; ++nt) {
            int col = n0 + wn * 32 + nt * 16 + lm;
            if (col >= N) continue;
            float bs = bias ? bias[col] : 0.f;
#pragma unroll
            for (int r = 0; r < 4; ++r) {
                int row = m0 + wm * 32 + mt * 16 + lq * 4 + r;
                float v = acc[mt][nt][r] + bs;
                if (ACT == 1) v = fmaxf(v, 0.f);
                if (ACT == 2) v = (v >= 0.f) ? v : 0.01f * v;
                C[(size_t)row * ldC + col] = (OUTT)v;
            }
        }
    }
}

// dual-B variant: grid.z selects (Bt, C). ACT=0, float out, no bias.
__global__ __launch_bounds__(256) void gemm16z_kernel(
    const _Float16* __restrict__ A,
    const _Float16* __restrict__ Bt0, const _Float16* __restrict__ Bt1,
    float* __restrict__ C0, float* __restrict__ C1,
    int M, int N, int K, int ldC)
{
    const _Float16* __restrict__ Bt = blockIdx.z ? Bt1 : Bt0;
    float* __restrict__ C = blockIdx.z ? C1 : C0;
    __shared__ _Float16 aS[64][4][8];
    __shared__ _Float16 bS[64][4][8];
    const int n0 = blockIdx.x * 64, m0 = blockIdx.y * 64;
    const int tid = threadIdx.x;
    const int wv = tid >> 6, ln = tid & 63;
    const int wm = wv & 1, wn = wv >> 1;
    const int lm = ln & 15, lq = ln >> 4;
    const int sr = tid >> 2, sq = tid & 3;

    f32x4 acc[2][2];
#pragma unroll
    for (int i = 0; i < 2; ++i)
#pragma unroll
        for (int j = 0; j < 2; ++j) acc[i][j] = (f32x4){0.f, 0.f, 0.f, 0.f};

    for (int cc = 0; cc < K; cc += 32) {
        *(uint4*)&aS[sr][sq][0] = *(const uint4*)(A + (size_t)(m0 + sr) * K + cc + sq * 8);
        uint4 bv = make_uint4(0u, 0u, 0u, 0u);
        if (n0 + sr < N)
            bv = *(const uint4*)(Bt + (size_t)(n0 + sr) * K + cc + sq * 8);
        *(uint4*)&bS[sr][sq][0] = bv;
        __syncthreads();
        f16x8 af[2], bf[2];
#pragma unroll
        for (int mt = 0; mt < 2; ++mt) af[mt] = *(const f16x8*)&aS[wm * 32 + mt * 16 + lm][lq][0];
#pragma unroll
        for (int nt = 0; nt < 2; ++nt) bf[nt] = *(const f16x8*)&bS[wn * 32 + nt * 16 + lm][lq][0];
#pragma unroll
        for (int mt = 0; mt < 2; ++mt)
#pragma unroll
            for (int nt = 0; nt < 2; ++nt)
                acc[mt][nt] = __builtin_amdgcn_mfma_f32_16x16x32_f16(af[mt], bf[nt], acc[mt][nt], 0, 0, 0);
        __syncthreads();
    }

#pragma unroll
    for (int mt = 0; mt < 2; ++mt) {
#pragma unroll
        for (int nt = 0; nt < 2; ++nt) {
            int col = n0 + wn * 32 + nt * 16 + lm;
            if (col >= N) continue;
#pragma unroll
            for (int r = 0; r < 4; ++r) {
                int row = m0 + wm * 32 + mt * 16 + lq * 4 + r;
                C[(size_t)row * ldC + col] = acc[mt][nt][r];
            }
        }
    }
}

// ---------------------------------------------------------------------------
// shared helper: per-sel centers sv[512] (LDS) + table extent tbv.
// ---------------------------------------------------------------------------
__device__ __forceinline__ float compute_sv_tb(
    const float* __restrict__ boxes, const float* __restrict__ scales,
    const float* __restrict__ pdls, const float* __restrict__ pdts,
    int b, int t, float* sv, float* red)
{
    int tid = threadIdx.x;
    float pdl = pdls[b], pdt = pdts[b], sc = scales[b];
    if (tid < 512) {
        const float* bx = boxes + (size_t)(b * 512 + tid) * 4;
        float o0 = (bx[0] - pdl) / sc;
        float o1 = (bx[1] - pdt) / sc;
        float o2 = (bx[2] - pdl) / sc;
        float o3 = (bx[3] - pdt) / sc;
        sv[tid]  = (t == 0) ? (o1 + o3) * 0.5f : (o0 + o2) * 0.5f;
        red[tid] = (t == 0) ? fmaxf(o1, o3)    : fmaxf(o0, o2);
    }
    __syncthreads();
    for (int s = 256; s > 0; s >>= 1) {
        if (tid < s) red[tid] = fmaxf(red[tid], red[tid + s]);
        __syncthreads();
    }
    float tbv = red[0];
    __syncthreads();
    return tbv;
}

#define QBITS(e, QB)                                                   \
    {                                                                  \
        int i_ = (e) / 511; int jj_ = (e) - i_ * 511;                  \
        int j_ = jj_ + (jj_ >= i_ ? 1 : 0);                            \
        float diff_ = sv[i_] - sv[j_];                                 \
        float u_ = (diff_ * 5.0f) / tbv;                               \
        float q_ = u_ * u_;                                            \
        QB = __float_as_uint(q_);                                      \
    }

// ---------------------------------------------------------------------------
// histA: LDS 4096-bin hist of top-12 q-bits, per-chunk partial.
// ---------------------------------------------------------------------------
__global__ __launch_bounds__(1024) void histA_kernel(
    const float* __restrict__ boxes, const float* __restrict__ scales,
    const float* __restrict__ pdls, const float* __restrict__ pdts,
    u32* __restrict__ gpart)
{
    __shared__ float sv[512]; __shared__ float red[512];
    __shared__ u32 lh[4096];
    const int sel = blockIdx.y, b = sel >> 1, t = sel & 1;
    const int tid = threadIdx.x;
    for (int i = tid; i < 4096; i += 1024) lh[i] = 0;
    const float tbv = compute_sv_tb(boxes, scales, pdls, pdts, b, t, sv, red);
    const int e1 = min((int)(blockIdx.x + 1) * ECHUNK, NE);
    for (int e = blockIdx.x * ECHUNK + tid; e < e1; e += 1024) {
        u32 qb; QBITS(e, qb);
        atomicAdd(&lh[qb >> 20], 1u);
    }
    __syncthreads();
    u32* G = gpart + ((size_t)sel * NCHUNK + blockIdx.x) * 4096;
    for (int i = tid; i < 4096; i += 1024) G[i] = lh[i];
}

// scanA: sum partials, block scan over 4096 bins, locate K-th -> p12, need1.
__global__ __launch_bounds__(1024) void scanA_kernel(
    const u32* __restrict__ gpart, u32* __restrict__ meta)
{
    const int sel = blockIdx.x, tid = threadIdx.x;
    __shared__ u32 bins[4096];
    __shared__ u32 sc[2][1024];
    for (int b = tid; b < 4096; b += 1024) {
        u32 s = 0;
        for (int c = 0; c < NCHUNK; ++c) s += gpart[((size_t)sel * NCHUNK + c) * 4096 + b];
        bins[b] = s;
    }
    __syncthreads();
    u32 part = 0;
#pragma unroll
    for (int j = 0; j < 4; ++j) part += bins[tid * 4 + j];
    sc[0][tid] = part;
    __syncthreads();
    int src = 0;
    for (int st = 1; st < 1024; st <<= 1) {
        sc[1 - src][tid] = sc[src][tid] + (tid >= st ? sc[src][tid - st] : 0);
        __syncthreads(); src = 1 - src;
    }
    u32 inc = sc[src][tid], exc = inc - part;
    if (exc < (u32)KEDGE && (u32)KEDGE <= inc) {
        u32 cum = exc;
        for (int j = 0; j < 4; ++j) {
            u32 c = bins[tid * 4 + j];
            if (cum + c >= (u32)KEDGE) {
                meta[sel * MS + 0] = (u32)(tid * 4 + j);
                meta[sel * MS + 1] = (u32)KEDGE - cum;
                break;
            }
            cum += c;
        }
    }
}

// histB: among edges with top-12 == p12, LDS hist of bits [19:8].
__global__ __launch_bounds__(1024) void histB_kernel(
    const float* __restrict__ boxes, const float* __restrict__ scales,
    const float* __restrict__ pdls, const float* __restrict__ pdts,
    const u32* __restrict__ meta, u32* __restrict__ gpart)
{
    __shared__ float sv[512]; __shared__ float red[512];
    __shared__ u32 lh[4096];
    const int sel = blockIdx.y, b = sel >> 1, t = sel & 1;
    const int tid = threadIdx.x;
    for (int i = tid; i < 4096; i += 1024) lh[i] = 0;
    const float tbv = compute_sv_tb(boxes, scales, pdls, pdts, b, t, sv, red);
    const u32 p12 = meta[sel * MS + 0];
    const int e1 = min((int)(blockIdx.x + 1) * ECHUNK, NE);
    for (int e = blockIdx.x * ECHUNK + tid; e < e1; e += 1024) {
        u32 qb; QBITS(e, qb);
        if ((qb >> 20) == p12) atomicAdd(&lh[(qb >> 8) & 0xFFF], 1u);
    }
    __syncthreads();
    u32* G = gpart + ((size_t)sel * NCHUNK + blockIdx.x) * 4096;
    for (int i = tid; i < 4096; i += 1024) G[i] = lh[i];
}

// scanB: locate need1-th within p12 group -> prefix24, need2.
__global__ __launch_bounds__(1024) void scanB_kernel(
    const u32* __restrict__ gpart, u32* __restrict__ meta)
{
    const int sel = blockIdx.x, tid = threadIdx.x;
    const u32 TH = meta[sel * MS + 1];
    __shared__ u32 bins[4096];
    __shared__ u32 sc[2][1024];
    for (int b = tid; b < 4096; b += 1024) {
        u32 s = 0;
        for (int c = 0; c < NCHUNK; ++c) s += gpart[((size_t)sel * NCHUNK + c) * 4096 + b];
        bins[b] = s;
    }
    __syncthreads();
    u32 part = 0;
#pragma unroll
    for (int j = 0; j < 4; ++j) part += bins[tid * 4 + j];
    sc[0][tid] = part;
    __syncthreads();
    int src = 0;
    for (int st = 1; st < 1024; st <<= 1) {
        sc[1 - src][tid] = sc[src][tid] + (tid >= st ? sc[src][tid - st] : 0);
        __syncthreads(); src = 1 - src;
    }
    u32 inc = sc[src][tid], exc = inc - part;
    if (exc < TH && TH <= inc) {
        u32 cum = exc;
        for (int j = 0; j < 4; ++j) {
            u32 c = bins[tid * 4 + j];
            if (cum + c >= TH) {
                meta[sel * MS + 6] = (meta[sel * MS + 0] << 12) | (u32)(tid * 4 + j);
                meta[sel * MS + 7] = TH - cum;
                break;
            }
            cum += c;
        }
    }
}

// histC: among edges with top-24 == prefix24, LDS hist of low 8 bits.
__global__ __launch_bounds__(1024) void histC_kernel(
    const float* __restrict__ boxes, const float* __restrict__ scales,
    const float* __restrict__ pdls, const float* __restrict__ pdts,
    const u32* __restrict__ meta, u32* __restrict__ gpart)
{
    __shared__ float sv[512]; __shared__ float red[512];
    __shared__ u32 lh[256];
    const int sel = blockIdx.y, b = sel >> 1, t = sel & 1;
    const int tid = threadIdx.x;
    if (tid < 256) lh[tid] = 0;
    const float tbv = compute_sv_tb(boxes, scales, pdls, pdts, b, t, sv, red);
    const u32 p24 = meta[sel * MS + 6];
    const int e1 = min((int)(blockIdx.x + 1) * ECHUNK, NE);
    for (int e = blockIdx.x * ECHUNK + tid; e < e1; e += 1024) {
        u32 qb; QBITS(e, qb);
        if ((qb >> 8) == p24) atomicAdd(&lh[qb & 0xFF], 1u);
    }
    __syncthreads();
    u32* G = gpart + ((size_t)sel * NCHUNK + blockIdx.x) * 256;
    if (tid < 256) G[tid] = lh[tid];
}

// scanC: exact q*, then binary-search the w*-tie q-interval [qlo,qhi].
__global__ __launch_bounds__(256) void scanC_kernel(
    const u32* __restrict__ gpart, u32* __restrict__ meta)
{
    const int sel = blockIdx.x, tid = threadIdx.x;
    const u32 TH = meta[sel * MS + 7];
    __shared__ u32 bins[256];
    __shared__ u32 sc[2][256];
    __shared__ u32 s_qstar;
    u32 s = 0;
    for (int c = 0; c < NCHUNK; ++c) s += gpart[((size_t)sel * NCHUNK + c) * 256 + tid];
    bins[tid] = s;
    sc[0][tid] = s;
    __syncthreads();
    int src = 0;
    for (int st = 1; st < 256; st <<= 1) {
        sc[1 - src][tid] = sc[src][tid] + (tid >= st ? sc[src][tid - st] : 0);
        __syncthreads(); src = 1 - src;
    }
    u32 inc = sc[src][tid], exc = inc - bins[tid];
    if (exc < TH && TH <= inc)
        s_qstar = (meta[sel * MS + 6] << 8) | (u32)tid;
    __syncthreads();
    if (tid == 0) {
        u32 prefix = s_qstar;
        float qstar = __uint_as_float(prefix);
        float wstar = (float)exp(-(double)qstar);
        u32 lo = 0, hi = prefix;              // smallest qb with exp(-q)==w*
        while (lo < hi) {
            u32 mid = (lo + hi) >> 1;
            float wm = (float)exp(-(double)__uint_as_float(mid));
            if (wm > wstar) lo = mid + 1; else hi = mid;
        }
        meta[sel * MS + 2] = lo;
        lo = prefix; hi = 0x7F800000u;        // largest qb with exp(-q)==w*
        while (lo < hi) {
            u32 mid = (lo + hi + 1) >> 1;
            float wm = (float)exp(-(double)__uint_as_float(mid));
            if (wm < wstar) hi = mid - 1; else lo = mid;
        }
        meta[sel * MS + 3] = lo;
        meta[sel * MS + 4] = __float_as_uint(wstar);
    }
}

// ---------------------------------------------------------------------------
// emit: two-pass block-aggregated slot reservation. Winners -> es/ed/ewt;
// ties -> tiebuf.
// ---------------------------------------------------------------------------
__global__ __launch_bounds__(1024) void emit_kernel(
    const float* __restrict__ boxes, const float* __restrict__ scales,
    const float* __restrict__ pdls, const float* __restrict__ pdts,
    u32* __restrict__ meta, int* __restrict__ tiebuf, int* __restrict__ tiecnt,
    int* __restrict__ es, int* __restrict__ ed, float* __restrict__ ewt,
    int* __restrict__ indeg, float* __restrict__ degw)
{
    __shared__ float sv[512]; __shared__ float red[512];
    __shared__ int s_wcnt, s_tcnt, s_wbase, s_tbase;
    const int sel = blockIdx.y, b = sel >> 1, t = sel & 1;
    const int tid = threadIdx.x;
    const float tbv = compute_sv_tb(boxes, scales, pdls, pdts, b, t, sv, red);
    const u32 qlo = meta[sel * MS + 2], qhi = meta[sel * MS + 3];
    const int base = t * 16384 + b * 4096;
    const int e0 = blockIdx.x * ECHUNK + tid;
    const int e1 = min((int)(blockIdx.x + 1) * ECHUNK, NE);
    if (tid == 0) { s_wcnt = 0; s_tcnt = 0; }
    __syncthreads();
    int myw = 0, myt = 0;
    for (int e = e0; e < e1; e += 1024) {
        u32 qb; QBITS(e, qb);
        if (qb < qlo) ++myw;
        else if (qb <= qhi) ++myt;
    }
    if (myw) atomicAdd(&s_wcnt, myw);
    if (myt) atomicAdd(&s_tcnt, myt);
    __syncthreads();
    if (tid == 0) {
        s_wbase = (s_wcnt > 0) ? (int)atomicAdd(&meta[sel * MS + 5], (u32)s_wcnt) : 0;
        s_tbase = (s_tcnt > 0) ? atomicAdd(&tiecnt[sel * TS], s_tcnt) : 0;
        s_wcnt = 0; s_tcnt = 0;
    }
    __syncthreads();
    for (int e = e0; e < e1; e += 1024) {
        u32 qb; QBITS(e, qb);
        if (qb < qlo) {
            int i = e / 511; int jj = e - i * 511; int j = jj + (jj >= i ? 1 : 0);
            float wval = (float)exp(-(double)__uint_as_float(qb));
            int slot = s_wbase + atomicAdd(&s_wcnt, 1);
            es[base + slot] = b * 512 + i;
            ed[base + slot] = b * 512 + j;
            ewt[base + slot] = wval;
            atomicAdd(&indeg[t * 2048 + b * 512 + j], 1);
            atomicAdd(&degw[t * 2048 + b * 512 + j], wval);
        } else if (qb <= qhi) {
            int p = s_tbase + atomicAdd(&s_tcnt, 1);
            if (p < TIECAP) tiebuf[sel * TIECAP + p] = e;
        }
    }
}

// ---------------------------------------------------------------------------
// tie resolution (index-ascending, r = K - emitted) + indeg scan + dis.
// ---------------------------------------------------------------------------
__global__ __launch_bounds__(1024) void tie_scan_kernel(
    u32* __restrict__ meta, const int* __restrict__ tiebuf, const int* __restrict__ tiecnt,
    int* __restrict__ es, int* __restrict__ ed, float* __restrict__ ewt,
    int* __restrict__ indeg, float* __restrict__ degw,
    int* __restrict__ offs, float* __restrict__ dis)
{
    __shared__ int bufA[2048], bufB[2048];
    const int t = blockIdx.x, tid = threadIdx.x;
    for (int b = 0; b < 4; ++b) {
        int sel = b * 2 + t;
        int m = min(tiecnt[sel * TS], TIECAP);
        int r = KEDGE - (int)meta[sel * MS + 5];
        float wt = __uint_as_float(meta[sel * MS + 4]);
        int base = t * 16384 + b * 4096;
        for (int k = tid; k < m; k += 1024) {
            int e = tiebuf[sel * TIECAP + k];
            int rank = 0;
            for (int l = 0; l < m; ++l) rank += (tiebuf[sel * TIECAP + l] < e) ? 1 : 0;
            if (rank < r) {
                int i = e / 511; int jj = e - i * 511; int j = jj + (jj >= i ? 1 : 0);
                int slot = (int)atomicAdd(&meta[sel * MS + 5], 1u);
                es[base + slot] = b * 512 + i;
                ed[base + slot] = b * 512 + j;
                ewt[base + slot] = wt;
                atomicAdd(&indeg[t * 2048 + b * 512 + j], 1);
                atomicAdd(&degw[t * 2048 + b * 512 + j], wt);
            }
        }
    }
    __threadfence();
    __syncthreads();
    bufA[tid] = indeg[t * 2048 + tid];
    bufA[tid + 1024] = indeg[t * 2048 + tid + 1024];
    __syncthreads();
    int* src = bufA; int* dst = bufB;
    for (int st = 1; st < 2048; st <<= 1) {
        dst[tid] = src[tid] + (tid >= st ? src[tid - st] : 0);
        int k1 = tid + 1024;
        dst[k1] = src[k1] + (k1 >= st ? src[k1 - st] : 0);
        __syncthreads();
        int* tmp = src; src = dst; dst = tmp;
    }
    offs[t * 2048 + tid] = (tid == 0) ? 0 : src[tid - 1];
    offs[t * 2048 + tid + 1024] = src[tid + 1023];
    dis[t * 2048 + tid] = 1.0f / sqrtf(1.0f + degw[t * 2048 + tid]);
    dis[t * 2048 + tid + 1024] = 1.0f / sqrtf(1.0f + degw[t * 2048 + tid + 1024]);
}

// CSR fill
__global__ void fill_kernel(const int* __restrict__ ed, const int* __restrict__ offs,
                            int* __restrict__ fill, int* __restrict__ csr) {
    int idx = blockIdx.x * 256 + threadIdx.x;
    if (idx >= 32768) return;
    int t = idx >> 14, e = idx & 16383;
    int d = ed[t * 16384 + e] & 2047;
    int pos = offs[t * 2048 + d] + atomicAdd(&fill[t * 2048 + d], 1);
    csr[t * 16384 + pos] = e;
}

// E7: GCN aggregate -> feats f16
__global__ __launch_bounds__(256) void gcn_agg_kernel(
    const float* __restrict__ xw_row, const float* __restrict__ xw_col,
    const float* __restrict__ b_row, const float* __restrict__ b_col,
    const int* __restrict__ es, const float* __restrict__ ew,
    const int* __restrict__ csr, const int* __restrict__ offs,
    const int* __restrict__ indeg, const float* __restrict__ dis,
    _Float16* __restrict__ feat_row, _Float16* __restrict__ feat_col)
{
    int d = blockIdx.x; int t = blockIdx.y;
    const float* xw = t ? xw_col : xw_row;
    const float* bg = t ? b_col : b_row;
    _Float16* out = t ? feat_col : feat_row;
    int f0 = threadIdx.x, f1 = threadIdx.x + 256;
    float dd = dis[t * 2048 + d];
    float a0 = dd * dd * xw[(size_t)d * 512 + f0];
    float a1 = dd * dd * xw[(size_t)d * 512 + f1];
    int st = offs[t * 2048 + d], cnt = indeg[t * 2048 + d];
    for (int k = 0; k < cnt; ++k) {
        int e = csr[t * 16384 + st + k];
        int s = es[t * 16384 + e];
        float w = ew[t * 16384 + e];
        float coef = dis[t * 2048 + s] * w * dd;
        a0 += coef * xw[(size_t)s * 512 + f0];
        a1 += coef * xw[(size_t)s * 512 + f1];
    }
    a0 += bg[f0]; a1 += bg[f1];
    out[(size_t)d * 512 + f0] = (_Float16)fmaxf(a0, 0.f);
    out[(size_t)d * 512 + f1] = (_Float16)fmaxf(a1, 0.f);
}

// ---------------------------------------------------------------------------
extern "C" void kernel_launch(void* const* d_in, const int* in_sizes, int n_in,
                              void* d_out, int out_size, void* d_ws, size_t ws_size,
                              hipStream_t stream)
{
    const float* x      = (const float*)d_in[0];
    const float* boxes  = (const float*)d_in[1];
    const float* scales = (const float*)d_in[2];
    const float* pdls   = (const float*)d_in[3];
    const float* pdts   = (const float*)d_in[4];
    const float* W_dec  = (const float*)d_in[5];
    const float* b_dec  = (const float*)d_in[6];
    const float* W_box  = (const float*)d_in[7];
    const float* b_box  = (const float*)d_in[8];
    const float* W_cnn  = (const float*)d_in[9];
    const float* b_cnn  = (const float*)d_in[10];
    const float* W_grow = (const float*)d_in[11];
    const float* b_grow = (const float*)d_in[12];
    const float* W_gcol = (const float*)d_in[13];
    const float* b_gcol = (const float*)d_in[14];
    const float* W_rcls = (const float*)d_in[15];
    const float* b_rcls = (const float*)d_in[16];
    const float* W_ccls = (const float*)d_in[17];
    const float* b_ccls = (const float*)d_in[18];

    char* ws = (char*)d_ws;
    size_t off = 0;
    auto alloc = [&](size_t bytes) -> void* {
        void* p = ws + off;
        off = (off + bytes + 255) & ~(size_t)255;
        return p;
    };
    _Float16* xf16   = (_Float16*)alloc((size_t)4 * 2304 * 1024 * 2);  // NHWC in
    _Float16* wf16   = (_Float16*)alloc((size_t)256 * 9216 * 2);       // [o][tap][ch]
    _Float16* dec    = (_Float16*)alloc((size_t)4 * 2304 * 256 * 2);   // NHWC
    float*    pbuf   = (float*)   alloc((size_t)4 * PSLICE * 4);       // split-K(4) partials
    _Float16* cnn    = (_Float16*)alloc((size_t)2048 * 1024 * 2);
    _Float16* fusion = (_Float16*)alloc((size_t)2048 * 768 * 2);
    _Float16* WcT    = (_Float16*)alloc((size_t)512 * 1024 * 2);
    _Float16* WgrT   = (_Float16*)alloc((size_t)512 * 768 * 2);
    _Float16* WgcT   = (_Float16*)alloc((size_t)512 * 768 * 2);
    _Float16* WrT    = (_Float16*)alloc((size_t)228 * 512 * 2);
    _Float16* WccT   = (_Float16*)alloc((size_t)116 * 512 * 2);
    float* xw        = (float*)alloc((size_t)2097152 * 4);             // xw_row|xw_col
    _Float16* feats  = (_Float16*)alloc((size_t)2 * 2048 * 512 * 2);   // row|col
    int*  es     = (int*)  alloc((size_t)2 * 16384 * 4);
    int*  ed     = (int*)  alloc((size_t)2 * 16384 * 4);
    float* ewt   = (float*)alloc((size_t)2 * 16384 * 4);
    int*  offsA  = (int*)  alloc((size_t)4096 * 4);
    float* dis   = (float*)alloc((size_t)4096 * 4);
    int*  csr    = (int*)  alloc((size_t)2 * 16384 * 4);
    int*  tiebuf = (int*)  alloc((size_t)8 * TIECAP * 4);
    u32*  gpartA = (u32*)  alloc((size_t)8 * NCHUNK * 4096 * 4);   // fully overwritten
    u32*  gpartB = (u32*)  alloc((size_t)8 * NCHUNK * 4096 * 4);
    u32*  gpartC = (u32*)  alloc((size_t)8 * NCHUNK * 256 * 4);
    // ---- zero zone (one hipMemsetAsync) ----
    size_t z0 = off;
    u32*  meta   = (u32*)  alloc((size_t)8 * MS * 4);
    int*  tiecnt = (int*)  alloc((size_t)8 * TS * 4);
    int*  indeg  = (int*)  alloc((size_t)4096 * 4);
    float* degw  = (float*)alloc((size_t)4096 * 4);
    int*  fillA  = (int*)  alloc((size_t)4096 * 4);
    size_t z1 = off;

    float* out = (float*)d_out;

    hipMemsetAsync(ws + z0, 0, z1 - z0, stream);

    cvt_x_kernel<<<dim3(16, 48, 4), 256, 0, stream>>>(x, xf16);
    cvt_w_kernel<<<256, 256, 0, stream>>>(W_dec, wf16);
    conv_part_kernel<<<dim3(6, 4, 16), 256, 0, stream>>>(xf16, wf16, pbuf);
    conv_sum_kernel<<<2304, 256, 0, stream>>>(pbuf, b_dec, dec);
    roi_kernel<<<2048, 256, 0, stream>>>(dec, boxes, cnn);
    box_kernel<<<2048, 256, 0, stream>>>(boxes, W_box, b_box, fusion);
    // weight transposes (f16 [N][K])
    cvt_t_kernel<<<dim3(16, 32), 256, 0, stream>>>(W_cnn, WcT, 1024, 512);
    cvt_t_kernel<<<dim3(16, 24), 256, 0, stream>>>(W_grow, WgrT, 768, 512);
    cvt_t_kernel<<<dim3(16, 24), 256, 0, stream>>>(W_gcol, WgcT, 768, 512);
    cvt_t_kernel<<<dim3(8, 16), 256, 0, stream>>>(W_rcls, WrT, 512, 228);
    cvt_t_kernel<<<dim3(4, 16), 256, 0, stream>>>(W_ccls, WccT, 512, 116);
    // fusion[:,256:768] = relu(cnn @ W_cnn + b)
    gemm16_kernel<1, _Float16><<<dim3(8, 32), 256, 0, stream>>>(cnn, WcT, b_cnn, fusion + 256, 2048, 512, 1024, 768);
    // edge pipeline: 12+12+8 LDS-privatized radix select + emit + CSR
    histA_kernel<<<dim3(NCHUNK, 8), 1024, 0, stream>>>(boxes, scales, pdls, pdts, gpartA);
    scanA_kernel<<<8, 1024, 0, stream>>>(gpartA, meta);
    histB_kernel<<<dim3(NCHUNK, 8), 1024, 0, stream>>>(boxes, scales, pdls, pdts, meta, gpartB);
    scanB_kernel<<<8, 1024, 0, stream>>>(gpartB, meta);
    histC_kernel<<<dim3(NCHUNK, 8), 1024, 0, stream>>>(boxes, scales, pdls, pdts, meta, gpartC);
    scanC_kernel<<<8, 256, 0, stream>>>(gpartC, meta);
    emit_kernel<<<dim3(NCHUNK, 8), 1024, 0, stream>>>(boxes, scales, pdls, pdts, meta,
                                                      tiebuf, tiecnt, es, ed, ewt, indeg, degw);
    tie_scan_kernel<<<2, 1024, 0, stream>>>(meta, tiebuf, tiecnt, es, ed, ewt,
                                            indeg, degw, offsA, dis);
    fill_kernel<<<128, 256, 0, stream>>>(ed, offsA, fillA, csr);
    // xw = fusion @ W_g{row,col} (bias applied in aggregation) — one dual launch
    gemm16z_kernel<<<dim3(8, 32, 2), 256, 0, stream>>>(fusion, WgrT, WgcT, xw, xw + 1048576,
                                                       2048, 512, 768, 512);
    gcn_agg_kernel<<<dim3(2048, 2), 256, 0, stream>>>(xw, xw + 1048576, b_grow, b_gcol,
                                                      es, ewt, csr, offsA, indeg, dis,
                                                      feats, feats + (size_t)2048 * 512);
    // classifier heads (leaky 0.01) -> fp32 out
    gemm16_kernel<2, float><<<dim3(4, 32), 256, 0, stream>>>(feats, WrT, b_rcls, out, 2048, 228, 512, 228);
    gemm16_kernel<2, float><<<dim3(2, 32), 256, 0, stream>>>(feats + (size_t)2048 * 512, WccT, b_ccls,
                                                             out + (size_t)2048 * 228, 2048, 116, 512, 116);
}